// Round 7
// baseline (561.422 us; speedup 1.0000x reference)
//
#include <hip/hip_runtime.h>
#include <math.h>

#define NS_STEPS 30

typedef __attribute__((ext_vector_type(8))) _Float16 half8;
typedef __attribute__((ext_vector_type(4))) _Float16 half4v;
typedef __attribute__((ext_vector_type(8))) short short8;
typedef __attribute__((ext_vector_type(4))) float floatx4;

static __device__ inline unsigned short f2bf(float f) {
  union { float f; unsigned u; } v; v.f = f;
  unsigned r = v.u + 0x7fffu + ((v.u >> 16) & 1u);
  return (unsigned short)(r >> 16);
}
static __device__ inline float bf2f(unsigned short h) {
  union { unsigned u; float f; } v; v.u = ((unsigned)h) << 16;
  return v.f;
}

// ======================= encoder convs =======================
__global__ __launch_bounds__(256) void conv1_k(const float* __restrict__ x,
    const float* __restrict__ w, const float* __restrict__ bias,
    float* __restrict__ out) {
  __shared__ float ws[384];
  int tid = threadIdx.x;
  for (int i = tid; i < 384; i += 256) ws[i] = w[i];
  __syncthreads();
  int idx = blockIdx.x * 256 + tid;
  if (idx >= 196608) return;
  int b = idx / 768, r = idx % 768;
  int c = r / 24, h = r % 24;
  const float* xb = x + b * 104 + h * 4;
  const float* wc = ws + c * 12;
  float acc = bias[c];
  #pragma unroll
  for (int kh = 0; kh < 3; kh++) {
    #pragma unroll
    for (int kw = 0; kw < 4; kw++)
      acc += xb[kh * 4 + kw] * wc[kh * 4 + kw];
  }
  out[idx] = acc;
}

__global__ __launch_bounds__(256) void conv2_k(const float* __restrict__ in,
    const float* __restrict__ w, const float* __restrict__ bias,
    float* __restrict__ out) {
  __shared__ float ws[2560];
  int tid = threadIdx.x;
  for (int i = tid; i < 2560; i += 256) ws[i] = w[i];
  __syncthreads();
  int idx = blockIdx.x * 256 + tid;
  if (idx >= 81920) return;
  int b = idx / 320, r = idx % 320;
  int c = r / 20, h = r % 20;
  const float* ib = in + b * 768 + h;
  const float* wc = ws + c * 160;
  float acc = bias[c];
  for (int i = 0; i < 32; i++) {
    #pragma unroll
    for (int kh = 0; kh < 5; kh++)
      acc += ib[i * 24 + kh] * wc[i * 5 + kh];
  }
  out[idx] = acc;
}

__global__ __launch_bounds__(256) void conv3_k(const float* __restrict__ in,
    const float* __restrict__ w, const float* __restrict__ bias,
    float* __restrict__ out) {
  __shared__ float ws[896];
  int tid = threadIdx.x;
  for (int i = tid; i < 896; i += 256) ws[i] = w[i];
  __syncthreads();
  int idx = blockIdx.x * 256 + tid;
  if (idx >= 28672) return;
  int b = idx / 112, r = idx % 112;
  int c = r / 14, h = r % 14;
  const float* ib = in + b * 320 + h;
  const float* wc = ws + c * 112;
  float acc = bias[c];
  for (int i = 0; i < 16; i++) {
    #pragma unroll
    for (int kh = 0; kh < 7; kh++)
      acc += ib[i * 20 + kh] * wc[i * 7 + kh];
  }
  out[idx] = acc;
}

// ======================= decoder tconvs =======================
__global__ __launch_bounds__(256) void tconv1_k(const float* __restrict__ in,
    const float* __restrict__ w, const float* __restrict__ bias,
    float* __restrict__ out) {
  __shared__ float ws[896];
  int tid = threadIdx.x;
  for (int i = tid; i < 896; i += 256) ws[i] = w[i];
  __syncthreads();
  int idx = blockIdx.x * 256 + tid;
  if (idx >= 81920) return;
  int b = idx / 320, r = idx % 320;
  int c = r / 20, s = r % 20;
  float acc = bias[c];
  for (int o = 0; o < 8; o++) {
    #pragma unroll
    for (int kh = 0; kh < 7; kh++) {
      int hs = s - kh;
      if (hs >= 0 && hs < 14)
        acc += in[b * 112 + o * 14 + hs] * ws[o * 112 + c * 7 + kh];
    }
  }
  out[idx] = acc;
}

__global__ __launch_bounds__(256) void tconv2_k(const float* __restrict__ in,
    const float* __restrict__ w, const float* __restrict__ bias,
    float* __restrict__ out) {
  __shared__ float ws[2560];
  int tid = threadIdx.x;
  for (int i = tid; i < 2560; i += 256) ws[i] = w[i];
  __syncthreads();
  int idx = blockIdx.x * 256 + tid;
  if (idx >= 196608) return;
  int b = idx / 768, r = idx % 768;
  int c = r / 24, s = r % 24;
  float acc = bias[c];
  for (int o = 0; o < 16; o++) {
    #pragma unroll
    for (int kh = 0; kh < 5; kh++) {
      int hs = s - kh;
      if (hs >= 0 && hs < 20)
        acc += in[b * 320 + o * 20 + hs] * ws[o * 160 + c * 5 + kh];
    }
  }
  out[idx] = acc;
}

__global__ __launch_bounds__(256) void tconv3_k(const float* __restrict__ in,
    const float* __restrict__ w, const float* __restrict__ bias,
    float* __restrict__ out) {
  __shared__ float ws[384];
  int tid = threadIdx.x;
  for (int i = tid; i < 384; i += 256) ws[i] = w[i];
  __syncthreads();
  int idx = blockIdx.x * 256 + tid;
  if (idx >= 26624) return;
  int b = idx / 104, r = idx % 104;
  int sh = r / 4, sw = r % 4;
  float acc = bias[0];
  for (int o = 0; o < 32; o++) {
    #pragma unroll
    for (int kh = 0; kh < 3; kh++) {
      int hs = sh - kh;
      if (hs >= 0 && hs < 24)
        acc += in[b * 768 + o * 24 + hs] * ws[o * 12 + kh * 4 + sw];
    }
  }
  out[idx] = acc;
}

// ======================= batchnorm =======================
__global__ __launch_bounds__(256) void bn2d_k(float* __restrict__ x,
    const float* __restrict__ g, const float* __restrict__ be,
    int C, int HW) {
  __shared__ float rs[256], rs2[256];
  int c = blockIdx.x, tid = threadIdx.x;
  int total = 256 * HW;
  float s = 0.f, s2 = 0.f;
  for (int i = tid; i < total; i += 256) {
    int b = i / HW, j = i - b * HW;
    float v = x[(b * C + c) * HW + j];
    s += v; s2 += v * v;
  }
  rs[tid] = s; rs2[tid] = s2;
  __syncthreads();
  for (int off = 128; off > 0; off >>= 1) {
    if (tid < off) { rs[tid] += rs[tid + off]; rs2[tid] += rs2[tid + off]; }
    __syncthreads();
  }
  float m = rs[0] / (float)total;
  float var = rs2[0] / (float)total - m * m;
  float rstd = rsqrtf(var + 1e-5f) * g[c];
  float bb = be[c];
  for (int i = tid; i < total; i += 256) {
    int b = i / HW, j = i - b * HW;
    size_t idx = (size_t)(b * C + c) * HW + j;
    float v = (x[idx] - m) * rstd + bb;
    x[idx] = v > 0.f ? v : 0.f;
  }
}

__global__ __launch_bounds__(256) void bn1d_k(float* __restrict__ x,
    const float* __restrict__ g, const float* __restrict__ be, int N) {
  __shared__ float p1[8][32], p2[8][32];
  int t = threadIdx.x;
  int cl = t & 31, rg = t >> 5;
  int c = blockIdx.x * 32 + cl;
  float s = 0.f, s2 = 0.f;
  if (c < N) {
    for (int r = rg * 32; r < rg * 32 + 32; r++) {
      float v = x[r * N + c];
      s += v; s2 += v * v;
    }
  }
  p1[rg][cl] = s; p2[rg][cl] = s2;
  __syncthreads();
  float ts = 0.f, ts2 = 0.f;
  #pragma unroll
  for (int i = 0; i < 8; i++) { ts += p1[i][cl]; ts2 += p2[i][cl]; }
  float m = ts * (1.f / 256.f);
  float var = ts2 * (1.f / 256.f) - m * m;
  float rstd = rsqrtf(var + 1e-5f) * ((c < N) ? g[c] : 1.f);
  float bb = (c < N) ? be[c] : 0.f;
  if (c < N) {
    for (int r = rg * 32; r < rg * 32 + 32; r++) {
      float v = (x[r * N + c] - m) * rstd + bb;
      x[r * N + c] = v > 0.f ? v : 0.f;
    }
  }
}

// ============== one-shot fp32 GEMM (K<=112, N multiple of 64) ===============
__global__ __launch_bounds__(256) void gemm_os_k(const float* __restrict__ A,
    const float* __restrict__ W, const float* __restrict__ bias,
    float* __restrict__ C, int K, int N) {
  __shared__ float As[112 * 68];
  __shared__ float Bs[112 * 68];
  int tid = threadIdx.x;
  int nb = blockIdx.x, mb = blockIdx.y;
  int K16 = K >> 4;
  {
    int row = tid >> 2;
    const float* Ar = A + (size_t)(mb * 64 + row) * K;
    for (int i = 0; i < K16; i++) {
      int j = (tid & 3) + 4 * i;
      float4 v = *(const float4*)(Ar + j * 4);
      int k = j * 4;
      As[k * 68 + row] = v.x;
      As[(k + 1) * 68 + row] = v.y;
      As[(k + 2) * 68 + row] = v.z;
      As[(k + 3) * 68 + row] = v.w;
    }
  }
  {
    int n4 = (tid & 15) * 4;
    for (int i = 0; i < K16; i++) {
      int k = (tid >> 4) + 16 * i;
      float4 v = *(const float4*)(W + (size_t)k * N + nb * 64 + n4);
      *(float4*)(Bs + k * 68 + n4) = v;
    }
  }
  __syncthreads();
  int tm = tid >> 4, tn = tid & 15;
  int m0 = tm * 4, n0 = tn * 4;
  float acc[4][4] = {{0.f}};
  #pragma unroll 8
  for (int kk = 0; kk < K; kk++) {
    float4 a = *(const float4*)(As + kk * 68 + m0);
    float4 b = *(const float4*)(Bs + kk * 68 + n0);
    acc[0][0] += a.x*b.x; acc[0][1] += a.x*b.y; acc[0][2] += a.x*b.z; acc[0][3] += a.x*b.w;
    acc[1][0] += a.y*b.x; acc[1][1] += a.y*b.y; acc[1][2] += a.y*b.z; acc[1][3] += a.y*b.w;
    acc[2][0] += a.z*b.x; acc[2][1] += a.z*b.y; acc[2][2] += a.z*b.z; acc[2][3] += a.z*b.w;
    acc[3][0] += a.w*b.x; acc[3][1] += a.w*b.y; acc[3][2] += a.w*b.z; acc[3][3] += a.w*b.w;
  }
  #pragma unroll
  for (int i = 0; i < 4; i++) {
    int m = mb * 64 + m0 + i;
    #pragma unroll
    for (int j = 0; j < 4; j++) {
      int n = nb * 64 + n0 + j;
      C[(size_t)m * N + n] = acc[i][j] + bias[n];
    }
  }
}

// ============== K-split fp32 GEMM for d4: C(256,112) += A@W chunk ===========
__global__ __launch_bounds__(256) void gemm_ks_k(const float* __restrict__ A,
    const float* __restrict__ W, const float* __restrict__ bias,
    float* __restrict__ C) {
  __shared__ float As[64 * 68];
  __shared__ float Bs[64 * 68];
  int tid = threadIdx.x;
  int nb = blockIdx.x, mb = blockIdx.y, kc = blockIdx.z;
  int k0 = kc * 64;
  {
    int row = tid >> 2;
    const float* Ar = A + (size_t)(mb * 64 + row) * 1024 + k0;
    #pragma unroll
    for (int i = 0; i < 4; i++) {
      int j = (tid & 3) + 4 * i;
      float4 v = *(const float4*)(Ar + j * 4);
      int k = j * 4;
      As[k * 68 + row] = v.x;
      As[(k + 1) * 68 + row] = v.y;
      As[(k + 2) * 68 + row] = v.z;
      As[(k + 3) * 68 + row] = v.w;
    }
  }
  {
    int n4 = (tid & 15) * 4;
    int nbase = nb * 64 + n4;
    #pragma unroll
    for (int i = 0; i < 4; i++) {
      int k = (tid >> 4) + 16 * i;
      const float* Wr = W + (size_t)(k0 + k) * 112;
      float4 v;
      v.x = (nbase     < 112) ? Wr[nbase]     : 0.f;
      v.y = (nbase + 1 < 112) ? Wr[nbase + 1] : 0.f;
      v.z = (nbase + 2 < 112) ? Wr[nbase + 2] : 0.f;
      v.w = (nbase + 3 < 112) ? Wr[nbase + 3] : 0.f;
      *(float4*)(Bs + k * 68 + n4) = v;
    }
  }
  __syncthreads();
  int tm = tid >> 4, tn = tid & 15;
  int m0 = tm * 4, n0 = tn * 4;
  float acc[4][4] = {{0.f}};
  #pragma unroll 8
  for (int kk = 0; kk < 64; kk++) {
    float4 a = *(const float4*)(As + kk * 68 + m0);
    float4 b = *(const float4*)(Bs + kk * 68 + n0);
    acc[0][0] += a.x*b.x; acc[0][1] += a.x*b.y; acc[0][2] += a.x*b.z; acc[0][3] += a.x*b.w;
    acc[1][0] += a.y*b.x; acc[1][1] += a.y*b.y; acc[1][2] += a.y*b.z; acc[1][3] += a.y*b.w;
    acc[2][0] += a.z*b.x; acc[2][1] += a.z*b.y; acc[2][2] += a.z*b.z; acc[2][3] += a.z*b.w;
    acc[3][0] += a.w*b.x; acc[3][1] += a.w*b.y; acc[3][2] += a.w*b.z; acc[3][3] += a.w*b.w;
  }
  #pragma unroll
  for (int i = 0; i < 4; i++) {
    int m = mb * 64 + m0 + i;
    #pragma unroll
    for (int j = 0; j < 4; j++) {
      int n = nb * 64 + n0 + j;
      if (n < 112) {
        float v = acc[i][j] + (kc == 0 ? bias[n] : 0.f);
        atomicAdd(&C[m * 112 + n], v);
      }
    }
  }
}

// ======= A-fragment precompute: out1 f32 -> bf16 hi/lo, MFMA-frag layout =====
__global__ __launch_bounds__(256) void prep_a_k(const float* __restrict__ A,
    short* __restrict__ ahi, short* __restrict__ alo) {
  int gi = blockIdx.x * 256 + threadIdx.x;   // 0..32767
  int lane = gi & 63;
  int t = gi >> 6;
  int mt = t & 3; t >>= 2;
  int c = t & 31; int mb = t >> 5;
  int row = mb * 64 + mt * 16 + (lane & 15);
  int k0 = c * 32 + (lane >> 4) * 8;
  const float* src = A + (size_t)row * 1024 + k0;
  float4 v0 = *(const float4*)(src);
  float4 v1 = *(const float4*)(src + 4);
  float av[8] = {v0.x, v0.y, v0.z, v0.w, v1.x, v1.y, v1.z, v1.w};
  short8 h, lo;
  #pragma unroll
  for (int i = 0; i < 8; i++) {
    unsigned short hh = f2bf(av[i]);
    h[i] = (short)hh;
    lo[i] = (short)f2bf(av[i] - bf2f(hh));
  }
  *(short8*)(ahi + (size_t)gi * 8) = h;
  *(short8*)(alo + (size_t)gi * 8) = lo;
}

// ================= fused head GEMMs, compensated-bf16 MFMA ==================
// v6 (unchanged): grid (200,4), W dbuf in LDS, lgkmcnt-only barrier.
struct HeadArgs {
  const float* W[7];
  const float* b[7];
  float* dst[7];
  int off[8];
  int ldw[7];
  int op[7];
};

__global__ __launch_bounds__(256) void heads_mfma_k(const short* __restrict__ ahi,
                                                    const short* __restrict__ alo,
                                                    HeadArgs ha) {
  __shared__ __align__(16) short Wsh[2][2][2048];  // [buf][hi/lo][64col x 32k frag]
  int tid = threadIdx.x;
  int nb = blockIdx.x;          // 64-col tile, 0..199
  int mq = blockIdx.y;          // 64-row quarter, 0..3
  int gc = nb * 64;
  int r = 0;
  while (gc >= ha.off[r + 1]) r++;
  const float* Wp = ha.W[r];
  const float* bias = ha.b[r];
  float* dst = ha.dst[r];
  int ldw = ha.ldw[r];
  int op = ha.op[r];
  int nloc = gc - ha.off[r];

  int w = tid >> 6, l = tid & 63;
  int lane16 = l & 15, quad = l >> 4;

  int c64 = tid & 63, q4 = tid >> 6;
  const float* wcol = Wp + (size_t)(q4 * 8) * ldw + nloc + c64;
  int wg = ((c64 >> 4) * 64 + q4 * 16 + (c64 & 15)) * 8;  // shorts

  const short* agh = ahi + (size_t)mq * 65536 + w * 512 + l * 8;
  const short* agl = alo + (size_t)mq * 65536 + w * 512 + l * 8;

  const floatx4 zero4 = {0.f, 0.f, 0.f, 0.f};
  floatx4 acc[4] = {zero4, zero4, zero4, zero4};

  float wvN[8], wvF[8];
  short8 whiN, wloN;
  short8 aCh, aCl, aNh, aNl;

  {
    float wv0[8];
    #pragma unroll
    for (int j = 0; j < 8; j++) wv0[j] = wcol[(size_t)j * ldw];
    #pragma unroll
    for (int j = 0; j < 8; j++) wvN[j] = wcol[(size_t)(32 + j) * ldw];
    aCh = *(const short8*)(agh);
    aCl = *(const short8*)(agl);
    #pragma unroll
    for (int j = 0; j < 8; j++) wvF[j] = wcol[(size_t)(64 + j) * ldw];
    short8 t0h, t0l;
    #pragma unroll
    for (int j = 0; j < 8; j++) {
      unsigned short hh = f2bf(wv0[j]);
      t0h[j] = (short)hh;
      t0l[j] = (short)f2bf(wv0[j] - bf2f(hh));
    }
    *(short8*)(&Wsh[0][0][wg]) = t0h;
    *(short8*)(&Wsh[0][1][wg]) = t0l;
    #pragma unroll
    for (int j = 0; j < 8; j++) {
      unsigned short hh = f2bf(wvN[j]);
      whiN[j] = (short)hh;
      wloN[j] = (short)f2bf(wvN[j] - bf2f(hh));
    }
    #pragma unroll
    for (int j = 0; j < 8; j++) wvN[j] = wvF[j];
    asm volatile("s_waitcnt lgkmcnt(0)" ::: "memory");
    __builtin_amdgcn_s_barrier();
  }

  for (int ch = 0; ch < 32; ++ch) {
    int p = ch & 1;
    if (ch < 31) {
      *(short8*)(&Wsh[p ^ 1][0][wg]) = whiN;
      *(short8*)(&Wsh[p ^ 1][1][wg]) = wloN;
    }
    if (ch < 29) {
      #pragma unroll
      for (int j = 0; j < 8; j++)
        wvF[j] = wcol[(size_t)((ch + 3) * 32 + j) * ldw];
    }
    if (ch < 31) {
      aNh = *(const short8*)(agh + (size_t)(ch + 1) * 2048);
      aNl = *(const short8*)(agl + (size_t)(ch + 1) * 2048);
    }
    short8 bh0 = *(const short8*)(&Wsh[p][0][(0 * 64 + l) * 8]);
    short8 bl0 = *(const short8*)(&Wsh[p][1][(0 * 64 + l) * 8]);
    short8 bh1 = *(const short8*)(&Wsh[p][0][(1 * 64 + l) * 8]);
    short8 bl1 = *(const short8*)(&Wsh[p][1][(1 * 64 + l) * 8]);
    short8 bh2 = *(const short8*)(&Wsh[p][0][(2 * 64 + l) * 8]);
    short8 bl2 = *(const short8*)(&Wsh[p][1][(2 * 64 + l) * 8]);
    short8 bh3 = *(const short8*)(&Wsh[p][0][(3 * 64 + l) * 8]);
    short8 bl3 = *(const short8*)(&Wsh[p][1][(3 * 64 + l) * 8]);
    acc[0] = __builtin_amdgcn_mfma_f32_16x16x32_bf16(aCh, bh0, acc[0], 0, 0, 0);
    acc[0] = __builtin_amdgcn_mfma_f32_16x16x32_bf16(aCh, bl0, acc[0], 0, 0, 0);
    acc[0] = __builtin_amdgcn_mfma_f32_16x16x32_bf16(aCl, bh0, acc[0], 0, 0, 0);
    acc[1] = __builtin_amdgcn_mfma_f32_16x16x32_bf16(aCh, bh1, acc[1], 0, 0, 0);
    acc[1] = __builtin_amdgcn_mfma_f32_16x16x32_bf16(aCh, bl1, acc[1], 0, 0, 0);
    acc[1] = __builtin_amdgcn_mfma_f32_16x16x32_bf16(aCl, bh1, acc[1], 0, 0, 0);
    acc[2] = __builtin_amdgcn_mfma_f32_16x16x32_bf16(aCh, bh2, acc[2], 0, 0, 0);
    acc[2] = __builtin_amdgcn_mfma_f32_16x16x32_bf16(aCh, bl2, acc[2], 0, 0, 0);
    acc[2] = __builtin_amdgcn_mfma_f32_16x16x32_bf16(aCl, bh2, acc[2], 0, 0, 0);
    acc[3] = __builtin_amdgcn_mfma_f32_16x16x32_bf16(aCh, bh3, acc[3], 0, 0, 0);
    acc[3] = __builtin_amdgcn_mfma_f32_16x16x32_bf16(aCh, bl3, acc[3], 0, 0, 0);
    acc[3] = __builtin_amdgcn_mfma_f32_16x16x32_bf16(aCl, bh3, acc[3], 0, 0, 0);
    if (ch < 30) {
      #pragma unroll
      for (int j = 0; j < 8; j++) {
        unsigned short hh = f2bf(wvN[j]);
        whiN[j] = (short)hh;
        wloN[j] = (short)f2bf(wvN[j] - bf2f(hh));
      }
    }
    if (ch < 29) {
      #pragma unroll
      for (int j = 0; j < 8; j++) wvN[j] = wvF[j];
    }
    if (ch < 31) { aCh = aNh; aCl = aNl; }
    asm volatile("s_waitcnt lgkmcnt(0)" ::: "memory");
    __builtin_amdgcn_s_barrier();
  }

  #pragma unroll
  for (int nf = 0; nf < 4; nf++) {
    int n = nloc + nf * 16 + lane16;
    float bv = bias[n];
    #pragma unroll
    for (int i = 0; i < 4; i++) {
      int m = mq * 64 + w * 16 + quad * 4 + i;
      float v = acc[nf][i] + bv;
      if (op == 1) v = tanhf(v);
      dst[(size_t)m * ldw + n] = v;
    }
  }
}

// ============ Newton-Schulz: fully compensated f16 MFMA =====================
// v5 = v4 + __launch_bounds__(128, 1). R6's 108us regression was SCRATCH
// SPILL (WRITE_SIZE 8MB->99MB, VGPR pinned at 68 by the occupancy-driven
// allocator budget while ~120 regs were live). min-waves/EU=1 releases the
// VGPR budget; block is LDS-limited anyway, and ns is LDS-throughput-bound
// (R5 audit), not occupancy-bound. Algorithm unchanged from v4 (numerics
// already harness-verified identical in R6).
__global__ __launch_bounds__(128, 1) void ns_f16split_k(const float* __restrict__ q,
                                                        float* __restrict__ amat) {
  __align__(16) __shared__ _Float16 arena[12288];
  int tid = threadIdx.x;
  int wid = tid >> 6;
  int l = tid & 63;
  int lane16 = l & 15, quad = l >> 4;
  _Float16* Ah_cm = arena;          // [32][72]
  _Float16* Al_cm = arena + 2304;   // [32][72]
  _Float16* Mh_cm = arena + 4608;   // [32][40]
  _Float16* Ml_cm = arena + 5888;   // [32][40]
  _Float16* Ah_rm = arena + 7168;   // [64][40]
  _Float16* Al_rm = arena + 9728;   // [64][40]
  float* Afin = (float*)arena;      // [64][36]

  const float* g = q + (size_t)blockIdx.x * 2048;
  float* o = amat + (size_t)blockIdx.x * 2048;

  if (wid == 0) {
    float vals[32];
    float ss = 0.f;
    #pragma unroll
    for (int j = 0; j < 8; j++) {
      float4 v = *(const float4*)(g + l * 32 + j * 4);
      vals[4*j] = v.x; vals[4*j+1] = v.y; vals[4*j+2] = v.z; vals[4*j+3] = v.w;
      ss += v.x*v.x + v.y*v.y + v.z*v.z + v.w*v.w;
    }
    #pragma unroll
    for (int off = 32; off > 0; off >>= 1) ss += __shfl_xor(ss, off);
    float rn = rsqrtf(ss);
    #pragma unroll
    for (int i = 0; i < 32; i++) vals[i] *= rn;
    #pragma unroll
    for (int j = 0; j < 8; j++) {
      half4v ph, pl;
      #pragma unroll
      for (int rr = 0; rr < 4; rr++) {
        float v = vals[4*j + rr];
        _Float16 h = (_Float16)v;
        _Float16 lo = (_Float16)(v - (float)h);
        ph[rr] = h; pl[rr] = lo;
      }
      *(half4v*)(Ah_rm + l * 40 + j * 4) = ph;
      *(half4v*)(Al_rm + l * 40 + j * 4) = pl;
    }
    #pragma unroll
    for (int i = 0; i < 32; i++) {
      float v = vals[i];
      _Float16 h = (_Float16)v;
      Ah_cm[i * 72 + l] = h;
      Al_cm[i * 72 + l] = (_Float16)(v - (float)h);
    }
  }
  __syncthreads();

  const floatx4 zero4 = {0.f, 0.f, 0.f, 0.f};
  for (int s = 0; s < NS_STEPS; s++) {
    bool last = (s == NS_STEPS - 1);
    // ---- gram: wave computes tiles (ti=0..1, tj=wid) ----
    half8 fah[2][2], fal[2][2];
    #pragma unroll
    for (int ti = 0; ti < 2; ti++)
      #pragma unroll
      for (int c = 0; c < 2; c++) {
        fah[ti][c] = *(half8*)(Ah_cm + (ti * 16 + lane16) * 72 + c * 32 + quad * 8);
        fal[ti][c] = *(half8*)(Al_cm + (ti * 16 + lane16) * 72 + c * 32 + quad * 8);
      }
    // B-operand = this wave's column tile: wave-uniform register select
    half8 fgh[2], fgl[2];
    #pragma unroll
    for (int c = 0; c < 2; c++) {
      fgh[c] = (wid == 0) ? fah[0][c] : fah[1][c];
      fgl[c] = (wid == 0) ? fal[0][c] : fal[1][c];
    }
    floatx4 gf[2] = {zero4, zero4};
    #pragma unroll
    for (int ti = 0; ti < 2; ti++)
      #pragma unroll
      for (int c = 0; c < 2; c++) {
        gf[ti] = __builtin_amdgcn_mfma_f32_16x16x32_f16(
            fah[ti][c], fgh[c], gf[ti], 0, 0, 0);
        gf[ti] = __builtin_amdgcn_mfma_f32_16x16x32_f16(
            fah[ti][c], fgl[c], gf[ti], 0, 0, 0);
        gf[ti] = __builtin_amdgcn_mfma_f32_16x16x32_f16(
            fal[ti][c], fgh[c], gf[ti], 0, 0, 0);
      }
    #pragma unroll
    for (int ti = 0; ti < 2; ti++) {
      int col = wid * 16 + lane16;
      int row0 = ti * 16 + quad * 4;
      half4v ph, pl;
      #pragma unroll
      for (int rr = 0; rr < 4; rr++) {
        float m = ((row0 + rr) == col ? 1.5f : 0.f) - 0.5f * gf[ti][rr];
        _Float16 h = (_Float16)m;
        ph[rr] = h; pl[rr] = (_Float16)(m - (float)h);
      }
      *(half4v*)(Mh_cm + col * 40 + row0) = ph;
      *(half4v*)(Ml_cm + col * 40 + row0) = pl;
    }
    __syncthreads();
    // ---- update: wave computes tiles (ti=0..1, tj in {2*wid, 2*wid+1}) ----
    half8 fmh[2], fml[2], fbh[2], fbl[2];
    #pragma unroll
    for (int ti = 0; ti < 2; ti++) {
      fmh[ti] = *(half8*)(Mh_cm + (ti * 16 + lane16) * 40 + quad * 8);
      fml[ti] = *(half8*)(Ml_cm + (ti * 16 + lane16) * 40 + quad * 8);
    }
    #pragma unroll
    for (int jj = 0; jj < 2; jj++) {
      int tj = 2 * wid + jj;
      fbh[jj] = *(half8*)(Ah_rm + (tj * 16 + lane16) * 40 + quad * 8);
      fbl[jj] = *(half8*)(Al_rm + (tj * 16 + lane16) * 40 + quad * 8);
    }
    // pass A: rm layout (z on lanes, d on regs)
    floatx4 df[2][2];
    #pragma unroll
    for (int ti = 0; ti < 2; ti++)
      #pragma unroll
      for (int jj = 0; jj < 2; jj++) {
        df[ti][jj] = __builtin_amdgcn_mfma_f32_16x16x32_f16(
            fmh[ti], fbh[jj], zero4, 0, 0, 0);
        df[ti][jj] = __builtin_amdgcn_mfma_f32_16x16x32_f16(
            fmh[ti], fbl[jj], df[ti][jj], 0, 0, 0);
        df[ti][jj] = __builtin_amdgcn_mfma_f32_16x16x32_f16(
            fml[ti], fbh[jj], df[ti][jj], 0, 0, 0);
      }
    // pass B (operand-swapped, non-last only): cm layout (d on lanes, z on regs)
    floatx4 db[2][2];
    if (!last) {
      #pragma unroll
      for (int ti = 0; ti < 2; ti++)
        #pragma unroll
        for (int jj = 0; jj < 2; jj++) {
          db[ti][jj] = __builtin_amdgcn_mfma_f32_16x16x32_f16(
              fbh[jj], fmh[ti], zero4, 0, 0, 0);
          db[ti][jj] = __builtin_amdgcn_mfma_f32_16x16x32_f16(
              fbl[jj], fmh[ti], db[ti][jj], 0, 0, 0);
          db[ti][jj] = __builtin_amdgcn_mfma_f32_16x16x32_f16(
              fbh[jj], fml[ti], db[ti][jj], 0, 0, 0);
        }
    }
    __syncthreads();   // WAR: all reads of Ah_rm/M done before overwrite
    if (!last) {
      #pragma unroll
      for (int ti = 0; ti < 2; ti++)
        #pragma unroll
        for (int jj = 0; jj < 2; jj++) {
          int tj = 2 * wid + jj;
          // rm write from pass A
          {
            int z = tj * 16 + lane16;
            int d0 = ti * 16 + quad * 4;
            half4v ph, pl;
            #pragma unroll
            for (int rr = 0; rr < 4; rr++) {
              float v = df[ti][jj][rr];
              _Float16 h = (_Float16)v;
              ph[rr] = h; pl[rr] = (_Float16)(v - (float)h);
            }
            *(half4v*)(Ah_rm + z * 40 + d0) = ph;
            *(half4v*)(Al_rm + z * 40 + d0) = pl;
          }
          // cm write from pass B (bitwise-identical values, transposed layout)
          {
            int d = ti * 16 + lane16;
            int z0 = tj * 16 + quad * 4;
            half4v ph, pl;
            #pragma unroll
            for (int rr = 0; rr < 4; rr++) {
              float v = db[ti][jj][rr];
              _Float16 h = (_Float16)v;
              ph[rr] = h; pl[rr] = (_Float16)(v - (float)h);
            }
            *(half4v*)(Ah_cm + d * 72 + z0) = ph;
            *(half4v*)(Al_cm + d * 72 + z0) = pl;
          }
        }
    } else {
      #pragma unroll
      for (int ti = 0; ti < 2; ti++)
        #pragma unroll
        for (int jj = 0; jj < 2; jj++) {
          int tj = 2 * wid + jj;
          int z = tj * 16 + lane16;
          int d0 = ti * 16 + quad * 4;
          float4 v;
          v.x = df[ti][jj][0]; v.y = df[ti][jj][1];
          v.z = df[ti][jj][2]; v.w = df[ti][jj][3];
          *(float4*)(Afin + z * 36 + d0) = v;
        }
    }
    __syncthreads();
  }
  #pragma unroll
  for (int j = 0; j < 4; j++) {
    int f = j * 512 + tid * 4;
    int z = f >> 5, d = f & 31;
    float4 v = *(const float4*)(Afin + z * 36 + d);
    *(float4*)(o + f) = v;
  }
}

// ======================= Sylvester flow (K=4 steps) =======================
__global__ __launch_bounds__(64) void flow_k(const float* __restrict__ amat,
    const float* __restrict__ fd, const float* __restrict__ dg1,
    const float* __restrict__ dg2, const float* __restrict__ ab,
    const float* __restrict__ eps, float* __restrict__ dout) {
  __shared__ float Ps[32][64];
  __shared__ float wsh[32], tsh[32], ush[32];
  int b = blockIdx.x, l = threadIdx.x;
  float mv  = dout[26624 + b * 64 + l];
  float lvv = dout[43008 + b * 64 + l];
  float z0 = mv + eps[b * 64 + l] * expf(0.5f * lvv);
  dout[59648 + b * 64 + l] = z0;
  float zv = z0;
  float ldj = 0.f;
  float q[32];
  for (int k = 0; k < 4; k++) {
    const float4* qrow = (const float4*)(amat + (size_t)(b * 4 + k) * 2048 + l * 32);
    #pragma unroll
    for (int j = 0; j < 8; j++) {
      float4 v = qrow[j];
      q[4*j] = v.x; q[4*j+1] = v.y; q[4*j+2] = v.z; q[4*j+3] = v.w;
    }
    #pragma unroll
    for (int d = 0; d < 32; d++) Ps[d][l] = zv * q[d];
    __syncthreads();
    if (l < 32) {
      const float4* pr = (const float4*)Ps[l];
      float s = 0.f;
      #pragma unroll
      for (int j = 0; j < 16; j++) {
        float4 v = pr[j];
        s += v.x + v.y + v.z + v.w;
      }
      wsh[l] = s;
    }
    __syncthreads();
    if (l < 32) {
      int e = l;
      float acc = ab[b * 128 + e * 4 + k] + wsh[e] * dg2[b * 128 + e * 4 + k];
      for (int d = e + 1; d < 32; d++)
        acc += wsh[d] * fd[b * 4096 + d * 128 + e * 4 + k];
      float tt = tanhf(acc);
      tsh[e] = tt;
      float dd = (1.f - tt * tt) * (dg1[b*128 + e*4 + k] * dg2[b*128 + e*4 + k]) + 1.f;
      ldj += logf(fabsf(dd));
    }
    __syncthreads();
    if (l < 32) {
      int d = l;
      float acc = tsh[d] * dg1[b * 128 + d * 4 + k];
      for (int e = d + 1; e < 32; e++)
        acc += fd[b * 4096 + d * 128 + e * 4 + k] * tsh[e];
      ush[d] = acc;
    }
    __syncthreads();
    #pragma unroll
    for (int d = 0; d < 32; d++) zv += q[d] * ush[d];
    __syncthreads();
  }
  dout[76032 + b * 64 + l] = zv;
  for (int off = 16; off > 0; off >>= 1) ldj += __shfl_down(ldj, off, 32);
  if (l == 0) dout[59392 + b] = ldj;
}

// ======================= host launch =======================
extern "C" void kernel_launch(void* const* d_in, const int* in_sizes, int n_in,
                              void* d_out, int out_size, void* d_ws, size_t ws_size,
                              hipStream_t stream) {
  (void)in_sizes; (void)n_in; (void)out_size; (void)ws_size;
  const float* x     = (const float*)d_in[0];
  const float* eps   = (const float*)d_in[1];
  const float* cw1   = (const float*)d_in[2];
  const float* cb1   = (const float*)d_in[3];
  const float* g1    = (const float*)d_in[4];
  const float* be1   = (const float*)d_in[5];
  const float* cw2   = (const float*)d_in[6];
  const float* cb2   = (const float*)d_in[7];
  const float* g2    = (const float*)d_in[8];
  const float* be2   = (const float*)d_in[9];
  const float* cw3   = (const float*)d_in[10];
  const float* cb3   = (const float*)d_in[11];
  const float* g3    = (const float*)d_in[12];
  const float* be3   = (const float*)d_in[13];
  const float* d1_w  = (const float*)d_in[14];
  const float* d1_b  = (const float*)d_in[15];
  const float* bn1_g = (const float*)d_in[16];
  const float* bn1_b = (const float*)d_in[17];
  const float* mu_w  = (const float*)d_in[18];
  const float* mu_b  = (const float*)d_in[19];
  const float* lv_w  = (const float*)d_in[20];
  const float* lv_b  = (const float*)d_in[21];
  const float* ad_w  = (const float*)d_in[22];
  const float* ad_b  = (const float*)d_in[23];
  const float* adg1_w= (const float*)d_in[24];
  const float* adg1_b= (const float*)d_in[25];
  const float* adg2_w= (const float*)d_in[26];
  const float* adg2_b= (const float*)d_in[27];
  const float* aq_w  = (const float*)d_in[28];
  const float* aq_b  = (const float*)d_in[29];
  const float* ab_w  = (const float*)d_in[30];
  const float* ab_b  = (const float*)d_in[31];
  const float* d3_w  = (const float*)d_in[32];
  const float* d3_b  = (const float*)d_in[33];
  const float* bn3_g = (const float*)d_in[34];
  const float* bn3_b = (const float*)d_in[35];
  const float* d4_w  = (const float*)d_in[36];
  const float* d4_b  = (const float*)d_in[37];
  const float* bn4_g = (const float*)d_in[38];
  const float* bn4_b = (const float*)d_in[39];
  const float* tw1   = (const float*)d_in[40];
  const float* tb1   = (const float*)d_in[41];
  const float* tg1   = (const float*)d_in[42];
  const float* tbe1  = (const float*)d_in[43];
  const float* tw2   = (const float*)d_in[44];
  const float* tb2   = (const float*)d_in[45];
  const float* tg2   = (const float*)d_in[46];
  const float* tbe2  = (const float*)d_in[47];
  const float* tw3   = (const float*)d_in[48];
  const float* tb3   = (const float*)d_in[49];

  float* out = (float*)d_out;
  float* wsf = (float*)d_ws;
  float* h1   = wsf;                 // 196608  (later: abuf, t2)
  float* h2   = wsf + 196608;        // 81920   (later: abuf tail, t1)
  float* h3   = wsf + 278528;        // 28672   (later: dec2)
  float* out1 = wsf + 307200;        // 262144  (later: dec1)
  float* fd   = wsf + 569344;        // 1048576
  float* dg1  = wsf + 1617920;       // 32768
  float* dg2  = wsf + 1650688;       // 32768
  float* qb   = wsf + 1683456;       // 2097152
  float* ab   = wsf + 3780608;       // 32768
  float* amat = wsf + 3813376;       // 2097152
  float* dec1 = out1;
  float* dec2 = h3;
  float* t1   = h2;
  float* t2   = h1;

  // A-fragment buffer: 524288 shorts = 262144 floats, reuses dead h1+h2
  short* ahi = (short*)wsf;
  short* alo = ahi + 262144;

  float* mean_o = out + 26624;
  float* lv_o   = out + 43008;
  float* z_o    = out + 76032;

  // ---------------- encoder ----------------
  conv1_k<<<768, 256, 0, stream>>>(x, cw1, cb1, h1);
  bn2d_k<<<32, 256, 0, stream>>>(h1, g1, be1, 32, 24);
  conv2_k<<<320, 256, 0, stream>>>(h1, cw2, cb2, h2);
  bn2d_k<<<16, 256, 0, stream>>>(h2, g2, be2, 16, 20);
  conv3_k<<<112, 256, 0, stream>>>(h2, cw3, cb3, h3);
  bn2d_k<<<8, 256, 0, stream>>>(h3, g3, be3, 8, 14);

  gemm_os_k<<<dim3(16, 4), 256, 0, stream>>>(h3, d1_w, d1_b, out1, 112, 1024);
  bn1d_k<<<32, 256, 0, stream>>>(out1, bn1_g, bn1_b, 1024);

  // ---------------- fused heads (MFMA) ----------------
  prep_a_k<<<128, 256, 0, stream>>>(out1, ahi, alo);

  HeadArgs ha;
  ha.W[0] = mu_w;   ha.b[0] = mu_b;   ha.dst[0] = mean_o; ha.ldw[0] = 64;   ha.op[0] = 0;
  ha.W[1] = lv_w;   ha.b[1] = lv_b;   ha.dst[1] = lv_o;   ha.ldw[1] = 64;   ha.op[1] = 0;
  ha.W[2] = ad_w;   ha.b[2] = ad_b;   ha.dst[2] = fd;     ha.ldw[2] = 4096; ha.op[2] = 0;
  ha.W[3] = adg1_w; ha.b[3] = adg1_b; ha.dst[3] = dg1;    ha.ldw[3] = 128;  ha.op[3] = 1;
  ha.W[4] = adg2_w; ha.b[4] = adg2_b; ha.dst[4] = dg2;    ha.ldw[4] = 128;  ha.op[4] = 1;
  ha.W[5] = aq_w;   ha.b[5] = aq_b;   ha.dst[5] = qb;     ha.ldw[5] = 8192; ha.op[5] = 0;
  ha.W[6] = ab_w;   ha.b[6] = ab_b;   ha.dst[6] = ab;     ha.ldw[6] = 128;  ha.op[6] = 0;
  ha.off[0] = 0;    ha.off[1] = 64;   ha.off[2] = 128;  ha.off[3] = 4224;
  ha.off[4] = 4352; ha.off[5] = 4480; ha.off[6] = 12672; ha.off[7] = 12800;
  heads_mfma_k<<<dim3(200, 4), 256, 0, stream>>>(ahi, alo, ha);

  // ---------------- orthogonalization + flow ----------------
  ns_f16split_k<<<1024, 128, 0, stream>>>(qb, amat);
  flow_k<<<256, 64, 0, stream>>>(amat, fd, dg1, dg2, ab, eps, out);

  // ---------------- decoder ----------------
  gemm_os_k<<<dim3(16, 4), 256, 0, stream>>>(z_o, d3_w, d3_b, dec1, 64, 1024);
  bn1d_k<<<32, 256, 0, stream>>>(dec1, bn3_g, bn3_b, 1024);
  hipMemsetAsync(dec2, 0, 28672 * sizeof(float), stream);
  gemm_ks_k<<<dim3(2, 4, 16), 256, 0, stream>>>(dec1, d4_w, d4_b, dec2);
  bn1d_k<<<4, 256, 0, stream>>>(dec2, bn4_g, bn4_b, 112);

  tconv1_k<<<320, 256, 0, stream>>>(dec2, tw1, tb1, t1);
  bn2d_k<<<16, 256, 0, stream>>>(t1, tg1, tbe1, 16, 20);
  tconv2_k<<<768, 256, 0, stream>>>(t1, tw2, tb2, t2);
  bn2d_k<<<32, 256, 0, stream>>>(t2, tg2, tbe2, 32, 24);
  tconv3_k<<<104, 256, 0, stream>>>(t2, tw3, tb3, out);
}

// Round 8
// 560.769 us; speedup vs baseline: 1.0012x; 1.0012x over previous
//
#include <hip/hip_runtime.h>
#include <math.h>

#define NS_STEPS 30

typedef __attribute__((ext_vector_type(8))) _Float16 half8;
typedef __attribute__((ext_vector_type(4))) _Float16 half4v;
typedef __attribute__((ext_vector_type(8))) short short8;
typedef __attribute__((ext_vector_type(4))) float floatx4;

static __device__ inline unsigned short f2bf(float f) {
  union { float f; unsigned u; } v; v.f = f;
  unsigned r = v.u + 0x7fffu + ((v.u >> 16) & 1u);
  return (unsigned short)(r >> 16);
}
static __device__ inline float bf2f(unsigned short h) {
  union { unsigned u; float f; } v; v.u = ((unsigned)h) << 16;
  return v.f;
}

// ======================= encoder convs =======================
__global__ __launch_bounds__(256) void conv1_k(const float* __restrict__ x,
    const float* __restrict__ w, const float* __restrict__ bias,
    float* __restrict__ out) {
  __shared__ float ws[384];
  int tid = threadIdx.x;
  for (int i = tid; i < 384; i += 256) ws[i] = w[i];
  __syncthreads();
  int idx = blockIdx.x * 256 + tid;
  if (idx >= 196608) return;
  int b = idx / 768, r = idx % 768;
  int c = r / 24, h = r % 24;
  const float* xb = x + b * 104 + h * 4;
  const float* wc = ws + c * 12;
  float acc = bias[c];
  #pragma unroll
  for (int kh = 0; kh < 3; kh++) {
    #pragma unroll
    for (int kw = 0; kw < 4; kw++)
      acc += xb[kh * 4 + kw] * wc[kh * 4 + kw];
  }
  out[idx] = acc;
}

__global__ __launch_bounds__(256) void conv2_k(const float* __restrict__ in,
    const float* __restrict__ w, const float* __restrict__ bias,
    float* __restrict__ out) {
  __shared__ float ws[2560];
  int tid = threadIdx.x;
  for (int i = tid; i < 2560; i += 256) ws[i] = w[i];
  __syncthreads();
  int idx = blockIdx.x * 256 + tid;
  if (idx >= 81920) return;
  int b = idx / 320, r = idx % 320;
  int c = r / 20, h = r % 20;
  const float* ib = in + b * 768 + h;
  const float* wc = ws + c * 160;
  float acc = bias[c];
  for (int i = 0; i < 32; i++) {
    #pragma unroll
    for (int kh = 0; kh < 5; kh++)
      acc += ib[i * 24 + kh] * wc[i * 5 + kh];
  }
  out[idx] = acc;
}

__global__ __launch_bounds__(256) void conv3_k(const float* __restrict__ in,
    const float* __restrict__ w, const float* __restrict__ bias,
    float* __restrict__ out) {
  __shared__ float ws[896];
  int tid = threadIdx.x;
  for (int i = tid; i < 896; i += 256) ws[i] = w[i];
  __syncthreads();
  int idx = blockIdx.x * 256 + tid;
  if (idx >= 28672) return;
  int b = idx / 112, r = idx % 112;
  int c = r / 14, h = r % 14;
  const float* ib = in + b * 320 + h;
  const float* wc = ws + c * 112;
  float acc = bias[c];
  for (int i = 0; i < 16; i++) {
    #pragma unroll
    for (int kh = 0; kh < 7; kh++)
      acc += ib[i * 20 + kh] * wc[i * 7 + kh];
  }
  out[idx] = acc;
}

// ======================= decoder tconvs =======================
__global__ __launch_bounds__(256) void tconv1_k(const float* __restrict__ in,
    const float* __restrict__ w, const float* __restrict__ bias,
    float* __restrict__ out) {
  __shared__ float ws[896];
  int tid = threadIdx.x;
  for (int i = tid; i < 896; i += 256) ws[i] = w[i];
  __syncthreads();
  int idx = blockIdx.x * 256 + tid;
  if (idx >= 81920) return;
  int b = idx / 320, r = idx % 320;
  int c = r / 20, s = r % 20;
  float acc = bias[c];
  for (int o = 0; o < 8; o++) {
    #pragma unroll
    for (int kh = 0; kh < 7; kh++) {
      int hs = s - kh;
      if (hs >= 0 && hs < 14)
        acc += in[b * 112 + o * 14 + hs] * ws[o * 112 + c * 7 + kh];
    }
  }
  out[idx] = acc;
}

__global__ __launch_bounds__(256) void tconv2_k(const float* __restrict__ in,
    const float* __restrict__ w, const float* __restrict__ bias,
    float* __restrict__ out) {
  __shared__ float ws[2560];
  int tid = threadIdx.x;
  for (int i = tid; i < 2560; i += 256) ws[i] = w[i];
  __syncthreads();
  int idx = blockIdx.x * 256 + tid;
  if (idx >= 196608) return;
  int b = idx / 768, r = idx % 768;
  int c = r / 24, s = r % 24;
  float acc = bias[c];
  for (int o = 0; o < 16; o++) {
    #pragma unroll
    for (int kh = 0; kh < 5; kh++) {
      int hs = s - kh;
      if (hs >= 0 && hs < 20)
        acc += in[b * 320 + o * 20 + hs] * ws[o * 160 + c * 5 + kh];
    }
  }
  out[idx] = acc;
}

__global__ __launch_bounds__(256) void tconv3_k(const float* __restrict__ in,
    const float* __restrict__ w, const float* __restrict__ bias,
    float* __restrict__ out) {
  __shared__ float ws[384];
  int tid = threadIdx.x;
  for (int i = tid; i < 384; i += 256) ws[i] = w[i];
  __syncthreads();
  int idx = blockIdx.x * 256 + tid;
  if (idx >= 26624) return;
  int b = idx / 104, r = idx % 104;
  int sh = r / 4, sw = r % 4;
  float acc = bias[0];
  for (int o = 0; o < 32; o++) {
    #pragma unroll
    for (int kh = 0; kh < 3; kh++) {
      int hs = sh - kh;
      if (hs >= 0 && hs < 24)
        acc += in[b * 768 + o * 24 + hs] * ws[o * 12 + kh * 4 + sw];
    }
  }
  out[idx] = acc;
}

// ======================= batchnorm =======================
__global__ __launch_bounds__(256) void bn2d_k(float* __restrict__ x,
    const float* __restrict__ g, const float* __restrict__ be,
    int C, int HW) {
  __shared__ float rs[256], rs2[256];
  int c = blockIdx.x, tid = threadIdx.x;
  int total = 256 * HW;
  float s = 0.f, s2 = 0.f;
  for (int i = tid; i < total; i += 256) {
    int b = i / HW, j = i - b * HW;
    float v = x[(b * C + c) * HW + j];
    s += v; s2 += v * v;
  }
  rs[tid] = s; rs2[tid] = s2;
  __syncthreads();
  for (int off = 128; off > 0; off >>= 1) {
    if (tid < off) { rs[tid] += rs[tid + off]; rs2[tid] += rs2[tid + off]; }
    __syncthreads();
  }
  float m = rs[0] / (float)total;
  float var = rs2[0] / (float)total - m * m;
  float rstd = rsqrtf(var + 1e-5f) * g[c];
  float bb = be[c];
  for (int i = tid; i < total; i += 256) {
    int b = i / HW, j = i - b * HW;
    size_t idx = (size_t)(b * C + c) * HW + j;
    float v = (x[idx] - m) * rstd + bb;
    x[idx] = v > 0.f ? v : 0.f;
  }
}

__global__ __launch_bounds__(256) void bn1d_k(float* __restrict__ x,
    const float* __restrict__ g, const float* __restrict__ be, int N) {
  __shared__ float p1[8][32], p2[8][32];
  int t = threadIdx.x;
  int cl = t & 31, rg = t >> 5;
  int c = blockIdx.x * 32 + cl;
  float s = 0.f, s2 = 0.f;
  if (c < N) {
    for (int r = rg * 32; r < rg * 32 + 32; r++) {
      float v = x[r * N + c];
      s += v; s2 += v * v;
    }
  }
  p1[rg][cl] = s; p2[rg][cl] = s2;
  __syncthreads();
  float ts = 0.f, ts2 = 0.f;
  #pragma unroll
  for (int i = 0; i < 8; i++) { ts += p1[i][cl]; ts2 += p2[i][cl]; }
  float m = ts * (1.f / 256.f);
  float var = ts2 * (1.f / 256.f) - m * m;
  float rstd = rsqrtf(var + 1e-5f) * ((c < N) ? g[c] : 1.f);
  float bb = (c < N) ? be[c] : 0.f;
  if (c < N) {
    for (int r = rg * 32; r < rg * 32 + 32; r++) {
      float v = (x[r * N + c] - m) * rstd + bb;
      x[r * N + c] = v > 0.f ? v : 0.f;
    }
  }
}

// ============== one-shot fp32 GEMM (K<=112, N multiple of 64) ===============
__global__ __launch_bounds__(256) void gemm_os_k(const float* __restrict__ A,
    const float* __restrict__ W, const float* __restrict__ bias,
    float* __restrict__ C, int K, int N) {
  __shared__ float As[112 * 68];
  __shared__ float Bs[112 * 68];
  int tid = threadIdx.x;
  int nb = blockIdx.x, mb = blockIdx.y;
  int K16 = K >> 4;
  {
    int row = tid >> 2;
    const float* Ar = A + (size_t)(mb * 64 + row) * K;
    for (int i = 0; i < K16; i++) {
      int j = (tid & 3) + 4 * i;
      float4 v = *(const float4*)(Ar + j * 4);
      int k = j * 4;
      As[k * 68 + row] = v.x;
      As[(k + 1) * 68 + row] = v.y;
      As[(k + 2) * 68 + row] = v.z;
      As[(k + 3) * 68 + row] = v.w;
    }
  }
  {
    int n4 = (tid & 15) * 4;
    for (int i = 0; i < K16; i++) {
      int k = (tid >> 4) + 16 * i;
      float4 v = *(const float4*)(W + (size_t)k * N + nb * 64 + n4);
      *(float4*)(Bs + k * 68 + n4) = v;
    }
  }
  __syncthreads();
  int tm = tid >> 4, tn = tid & 15;
  int m0 = tm * 4, n0 = tn * 4;
  float acc[4][4] = {{0.f}};
  #pragma unroll 8
  for (int kk = 0; kk < K; kk++) {
    float4 a = *(const float4*)(As + kk * 68 + m0);
    float4 b = *(const float4*)(Bs + kk * 68 + n0);
    acc[0][0] += a.x*b.x; acc[0][1] += a.x*b.y; acc[0][2] += a.x*b.z; acc[0][3] += a.x*b.w;
    acc[1][0] += a.y*b.x; acc[1][1] += a.y*b.y; acc[1][2] += a.y*b.z; acc[1][3] += a.y*b.w;
    acc[2][0] += a.z*b.x; acc[2][1] += a.z*b.y; acc[2][2] += a.z*b.z; acc[2][3] += a.z*b.w;
    acc[3][0] += a.w*b.x; acc[3][1] += a.w*b.y; acc[3][2] += a.w*b.z; acc[3][3] += a.w*b.w;
  }
  #pragma unroll
  for (int i = 0; i < 4; i++) {
    int m = mb * 64 + m0 + i;
    #pragma unroll
    for (int j = 0; j < 4; j++) {
      int n = nb * 64 + n0 + j;
      C[(size_t)m * N + n] = acc[i][j] + bias[n];
    }
  }
}

// ============== K-split fp32 GEMM for d4: C(256,112) += A@W chunk ===========
__global__ __launch_bounds__(256) void gemm_ks_k(const float* __restrict__ A,
    const float* __restrict__ W, const float* __restrict__ bias,
    float* __restrict__ C) {
  __shared__ float As[64 * 68];
  __shared__ float Bs[64 * 68];
  int tid = threadIdx.x;
  int nb = blockIdx.x, mb = blockIdx.y, kc = blockIdx.z;
  int k0 = kc * 64;
  {
    int row = tid >> 2;
    const float* Ar = A + (size_t)(mb * 64 + row) * 1024 + k0;
    #pragma unroll
    for (int i = 0; i < 4; i++) {
      int j = (tid & 3) + 4 * i;
      float4 v = *(const float4*)(Ar + j * 4);
      int k = j * 4;
      As[k * 68 + row] = v.x;
      As[(k + 1) * 68 + row] = v.y;
      As[(k + 2) * 68 + row] = v.z;
      As[(k + 3) * 68 + row] = v.w;
    }
  }
  {
    int n4 = (tid & 15) * 4;
    int nbase = nb * 64 + n4;
    #pragma unroll
    for (int i = 0; i < 4; i++) {
      int k = (tid >> 4) + 16 * i;
      const float* Wr = W + (size_t)(k0 + k) * 112;
      float4 v;
      v.x = (nbase     < 112) ? Wr[nbase]     : 0.f;
      v.y = (nbase + 1 < 112) ? Wr[nbase + 1] : 0.f;
      v.z = (nbase + 2 < 112) ? Wr[nbase + 2] : 0.f;
      v.w = (nbase + 3 < 112) ? Wr[nbase + 3] : 0.f;
      *(float4*)(Bs + k * 68 + n4) = v;
    }
  }
  __syncthreads();
  int tm = tid >> 4, tn = tid & 15;
  int m0 = tm * 4, n0 = tn * 4;
  float acc[4][4] = {{0.f}};
  #pragma unroll 8
  for (int kk = 0; kk < 64; kk++) {
    float4 a = *(const float4*)(As + kk * 68 + m0);
    float4 b = *(const float4*)(Bs + kk * 68 + n0);
    acc[0][0] += a.x*b.x; acc[0][1] += a.x*b.y; acc[0][2] += a.x*b.z; acc[0][3] += a.x*b.w;
    acc[1][0] += a.y*b.x; acc[1][1] += a.y*b.y; acc[1][2] += a.y*b.z; acc[1][3] += a.y*b.w;
    acc[2][0] += a.z*b.x; acc[2][1] += a.z*b.y; acc[2][2] += a.z*b.z; acc[2][3] += a.z*b.w;
    acc[3][0] += a.w*b.x; acc[3][1] += a.w*b.y; acc[3][2] += a.w*b.z; acc[3][3] += a.w*b.w;
  }
  #pragma unroll
  for (int i = 0; i < 4; i++) {
    int m = mb * 64 + m0 + i;
    #pragma unroll
    for (int j = 0; j < 4; j++) {
      int n = nb * 64 + n0 + j;
      if (n < 112) {
        float v = acc[i][j] + (kc == 0 ? bias[n] : 0.f);
        atomicAdd(&C[m * 112 + n], v);
      }
    }
  }
}

// ======= A-fragment precompute: out1 f32 -> bf16 hi/lo, MFMA-frag layout =====
__global__ __launch_bounds__(256) void prep_a_k(const float* __restrict__ A,
    short* __restrict__ ahi, short* __restrict__ alo) {
  int gi = blockIdx.x * 256 + threadIdx.x;   // 0..32767
  int lane = gi & 63;
  int t = gi >> 6;
  int mt = t & 3; t >>= 2;
  int c = t & 31; int mb = t >> 5;
  int row = mb * 64 + mt * 16 + (lane & 15);
  int k0 = c * 32 + (lane >> 4) * 8;
  const float* src = A + (size_t)row * 1024 + k0;
  float4 v0 = *(const float4*)(src);
  float4 v1 = *(const float4*)(src + 4);
  float av[8] = {v0.x, v0.y, v0.z, v0.w, v1.x, v1.y, v1.z, v1.w};
  short8 h, lo;
  #pragma unroll
  for (int i = 0; i < 8; i++) {
    unsigned short hh = f2bf(av[i]);
    h[i] = (short)hh;
    lo[i] = (short)f2bf(av[i] - bf2f(hh));
  }
  *(short8*)(ahi + (size_t)gi * 8) = h;
  *(short8*)(alo + (size_t)gi * 8) = lo;
}

// ================= fused head GEMMs, compensated-bf16 MFMA ==================
// v6 (unchanged): grid (200,4), W dbuf in LDS, lgkmcnt-only barrier.
struct HeadArgs {
  const float* W[7];
  const float* b[7];
  float* dst[7];
  int off[8];
  int ldw[7];
  int op[7];
};

__global__ __launch_bounds__(256) void heads_mfma_k(const short* __restrict__ ahi,
                                                    const short* __restrict__ alo,
                                                    HeadArgs ha) {
  __shared__ __align__(16) short Wsh[2][2][2048];  // [buf][hi/lo][64col x 32k frag]
  int tid = threadIdx.x;
  int nb = blockIdx.x;          // 64-col tile, 0..199
  int mq = blockIdx.y;          // 64-row quarter, 0..3
  int gc = nb * 64;
  int r = 0;
  while (gc >= ha.off[r + 1]) r++;
  const float* Wp = ha.W[r];
  const float* bias = ha.b[r];
  float* dst = ha.dst[r];
  int ldw = ha.ldw[r];
  int op = ha.op[r];
  int nloc = gc - ha.off[r];

  int w = tid >> 6, l = tid & 63;
  int lane16 = l & 15, quad = l >> 4;

  int c64 = tid & 63, q4 = tid >> 6;
  const float* wcol = Wp + (size_t)(q4 * 8) * ldw + nloc + c64;
  int wg = ((c64 >> 4) * 64 + q4 * 16 + (c64 & 15)) * 8;  // shorts

  const short* agh = ahi + (size_t)mq * 65536 + w * 512 + l * 8;
  const short* agl = alo + (size_t)mq * 65536 + w * 512 + l * 8;

  const floatx4 zero4 = {0.f, 0.f, 0.f, 0.f};
  floatx4 acc[4] = {zero4, zero4, zero4, zero4};

  float wvN[8], wvF[8];
  short8 whiN, wloN;
  short8 aCh, aCl, aNh, aNl;

  {
    float wv0[8];
    #pragma unroll
    for (int j = 0; j < 8; j++) wv0[j] = wcol[(size_t)j * ldw];
    #pragma unroll
    for (int j = 0; j < 8; j++) wvN[j] = wcol[(size_t)(32 + j) * ldw];
    aCh = *(const short8*)(agh);
    aCl = *(const short8*)(agl);
    #pragma unroll
    for (int j = 0; j < 8; j++) wvF[j] = wcol[(size_t)(64 + j) * ldw];
    short8 t0h, t0l;
    #pragma unroll
    for (int j = 0; j < 8; j++) {
      unsigned short hh = f2bf(wv0[j]);
      t0h[j] = (short)hh;
      t0l[j] = (short)f2bf(wv0[j] - bf2f(hh));
    }
    *(short8*)(&Wsh[0][0][wg]) = t0h;
    *(short8*)(&Wsh[0][1][wg]) = t0l;
    #pragma unroll
    for (int j = 0; j < 8; j++) {
      unsigned short hh = f2bf(wvN[j]);
      whiN[j] = (short)hh;
      wloN[j] = (short)f2bf(wvN[j] - bf2f(hh));
    }
    #pragma unroll
    for (int j = 0; j < 8; j++) wvN[j] = wvF[j];
    asm volatile("s_waitcnt lgkmcnt(0)" ::: "memory");
    __builtin_amdgcn_s_barrier();
  }

  for (int ch = 0; ch < 32; ++ch) {
    int p = ch & 1;
    if (ch < 31) {
      *(short8*)(&Wsh[p ^ 1][0][wg]) = whiN;
      *(short8*)(&Wsh[p ^ 1][1][wg]) = wloN;
    }
    if (ch < 29) {
      #pragma unroll
      for (int j = 0; j < 8; j++)
        wvF[j] = wcol[(size_t)((ch + 3) * 32 + j) * ldw];
    }
    if (ch < 31) {
      aNh = *(const short8*)(agh + (size_t)(ch + 1) * 2048);
      aNl = *(const short8*)(agl + (size_t)(ch + 1) * 2048);
    }
    short8 bh0 = *(const short8*)(&Wsh[p][0][(0 * 64 + l) * 8]);
    short8 bl0 = *(const short8*)(&Wsh[p][1][(0 * 64 + l) * 8]);
    short8 bh1 = *(const short8*)(&Wsh[p][0][(1 * 64 + l) * 8]);
    short8 bl1 = *(const short8*)(&Wsh[p][1][(1 * 64 + l) * 8]);
    short8 bh2 = *(const short8*)(&Wsh[p][0][(2 * 64 + l) * 8]);
    short8 bl2 = *(const short8*)(&Wsh[p][1][(2 * 64 + l) * 8]);
    short8 bh3 = *(const short8*)(&Wsh[p][0][(3 * 64 + l) * 8]);
    short8 bl3 = *(const short8*)(&Wsh[p][1][(3 * 64 + l) * 8]);
    acc[0] = __builtin_amdgcn_mfma_f32_16x16x32_bf16(aCh, bh0, acc[0], 0, 0, 0);
    acc[0] = __builtin_amdgcn_mfma_f32_16x16x32_bf16(aCh, bl0, acc[0], 0, 0, 0);
    acc[0] = __builtin_amdgcn_mfma_f32_16x16x32_bf16(aCl, bh0, acc[0], 0, 0, 0);
    acc[1] = __builtin_amdgcn_mfma_f32_16x16x32_bf16(aCh, bh1, acc[1], 0, 0, 0);
    acc[1] = __builtin_amdgcn_mfma_f32_16x16x32_bf16(aCh, bl1, acc[1], 0, 0, 0);
    acc[1] = __builtin_amdgcn_mfma_f32_16x16x32_bf16(aCl, bh1, acc[1], 0, 0, 0);
    acc[2] = __builtin_amdgcn_mfma_f32_16x16x32_bf16(aCh, bh2, acc[2], 0, 0, 0);
    acc[2] = __builtin_amdgcn_mfma_f32_16x16x32_bf16(aCh, bl2, acc[2], 0, 0, 0);
    acc[2] = __builtin_amdgcn_mfma_f32_16x16x32_bf16(aCl, bh2, acc[2], 0, 0, 0);
    acc[3] = __builtin_amdgcn_mfma_f32_16x16x32_bf16(aCh, bh3, acc[3], 0, 0, 0);
    acc[3] = __builtin_amdgcn_mfma_f32_16x16x32_bf16(aCh, bl3, acc[3], 0, 0, 0);
    acc[3] = __builtin_amdgcn_mfma_f32_16x16x32_bf16(aCl, bh3, acc[3], 0, 0, 0);
    if (ch < 30) {
      #pragma unroll
      for (int j = 0; j < 8; j++) {
        unsigned short hh = f2bf(wvN[j]);
        whiN[j] = (short)hh;
        wloN[j] = (short)f2bf(wvN[j] - bf2f(hh));
      }
    }
    if (ch < 29) {
      #pragma unroll
      for (int j = 0; j < 8; j++) wvN[j] = wvF[j];
    }
    if (ch < 31) { aCh = aNh; aCl = aNl; }
    asm volatile("s_waitcnt lgkmcnt(0)" ::: "memory");
    __builtin_amdgcn_s_barrier();
  }

  #pragma unroll
  for (int nf = 0; nf < 4; nf++) {
    int n = nloc + nf * 16 + lane16;
    float bv = bias[n];
    #pragma unroll
    for (int i = 0; i < 4; i++) {
      int m = mq * 64 + w * 16 + quad * 4 + i;
      float v = acc[nf][i] + bv;
      if (op == 1) v = tanhf(v);
      dst[(size_t)m * ldw + n] = v;
    }
  }
}

// ============ Newton-Schulz: fully compensated f16 MFMA =====================
// v6 = v3 (R5's proven 57us structure: b16 cm-scatter kept, single MFMA
// pass) + ONLY the gram-B register dedup from v4 (fgh/fgl = wave-uniform
// select of fah[wid], replacing 4 redundant ds_read_b128; bitwise-identical
// values, same MFMA order). v4/v5's operand-swapped pass B is REVERTED:
// it forced ~90MB of scratch stores (WRITE_SIZE 8->99MB) that
// __launch_bounds__(128,1) could not release (VGPR pinned at 68 both
// rounds). Tripwire: if WRITE_SIZE != ~8MB, drop the dedup too.
__global__ __launch_bounds__(128) void ns_f16split_k(const float* __restrict__ q,
                                                     float* __restrict__ amat) {
  __align__(16) __shared__ _Float16 arena[12288];
  int tid = threadIdx.x;
  int wid = tid >> 6;
  int l = tid & 63;
  int lane16 = l & 15, quad = l >> 4;
  _Float16* Ah_cm = arena;          // [32][72]
  _Float16* Al_cm = arena + 2304;   // [32][72]
  _Float16* Mh_cm = arena + 4608;   // [32][40]
  _Float16* Ml_cm = arena + 5888;   // [32][40]
  _Float16* Ah_rm = arena + 7168;   // [64][40]
  _Float16* Al_rm = arena + 9728;   // [64][40]
  float* Afin = (float*)arena;      // [64][36]

  const float* g = q + (size_t)blockIdx.x * 2048;
  float* o = amat + (size_t)blockIdx.x * 2048;

  if (wid == 0) {
    float vals[32];
    float ss = 0.f;
    #pragma unroll
    for (int j = 0; j < 8; j++) {
      float4 v = *(const float4*)(g + l * 32 + j * 4);
      vals[4*j] = v.x; vals[4*j+1] = v.y; vals[4*j+2] = v.z; vals[4*j+3] = v.w;
      ss += v.x*v.x + v.y*v.y + v.z*v.z + v.w*v.w;
    }
    #pragma unroll
    for (int off = 32; off > 0; off >>= 1) ss += __shfl_xor(ss, off);
    float rn = rsqrtf(ss);
    #pragma unroll
    for (int i = 0; i < 32; i++) vals[i] *= rn;
    #pragma unroll
    for (int j = 0; j < 8; j++) {
      half4v ph, pl;
      #pragma unroll
      for (int rr = 0; rr < 4; rr++) {
        float v = vals[4*j + rr];
        _Float16 h = (_Float16)v;
        _Float16 lo = (_Float16)(v - (float)h);
        ph[rr] = h; pl[rr] = lo;
      }
      *(half4v*)(Ah_rm + l * 40 + j * 4) = ph;
      *(half4v*)(Al_rm + l * 40 + j * 4) = pl;
    }
    #pragma unroll
    for (int i = 0; i < 32; i++) {
      float v = vals[i];
      _Float16 h = (_Float16)v;
      Ah_cm[i * 72 + l] = h;
      Al_cm[i * 72 + l] = (_Float16)(v - (float)h);
    }
  }
  __syncthreads();

  const floatx4 zero4 = {0.f, 0.f, 0.f, 0.f};
  for (int s = 0; s < NS_STEPS; s++) {
    bool last = (s == NS_STEPS - 1);
    // ---- gram: wave computes tiles (ti=0..1, tj=wid) ----
    half8 fah[2][2], fal[2][2];
    #pragma unroll
    for (int ti = 0; ti < 2; ti++)
      #pragma unroll
      for (int c = 0; c < 2; c++) {
        fah[ti][c] = *(half8*)(Ah_cm + (ti * 16 + lane16) * 72 + c * 32 + quad * 8);
        fal[ti][c] = *(half8*)(Al_cm + (ti * 16 + lane16) * 72 + c * 32 + quad * 8);
      }
    // B-operand = this wave's column tile: wave-uniform register select
    half8 fgh[2], fgl[2];
    #pragma unroll
    for (int c = 0; c < 2; c++) {
      fgh[c] = (wid == 0) ? fah[0][c] : fah[1][c];
      fgl[c] = (wid == 0) ? fal[0][c] : fal[1][c];
    }
    floatx4 gf[2] = {zero4, zero4};
    #pragma unroll
    for (int ti = 0; ti < 2; ti++)
      #pragma unroll
      for (int c = 0; c < 2; c++) {
        gf[ti] = __builtin_amdgcn_mfma_f32_16x16x32_f16(
            fah[ti][c], fgh[c], gf[ti], 0, 0, 0);
        gf[ti] = __builtin_amdgcn_mfma_f32_16x16x32_f16(
            fah[ti][c], fgl[c], gf[ti], 0, 0, 0);
        gf[ti] = __builtin_amdgcn_mfma_f32_16x16x32_f16(
            fal[ti][c], fgh[c], gf[ti], 0, 0, 0);
      }
    #pragma unroll
    for (int ti = 0; ti < 2; ti++) {
      int col = wid * 16 + lane16;
      int row0 = ti * 16 + quad * 4;
      half4v ph, pl;
      #pragma unroll
      for (int rr = 0; rr < 4; rr++) {
        float m = ((row0 + rr) == col ? 1.5f : 0.f) - 0.5f * gf[ti][rr];
        _Float16 h = (_Float16)m;
        ph[rr] = h; pl[rr] = (_Float16)(m - (float)h);
      }
      *(half4v*)(Mh_cm + col * 40 + row0) = ph;
      *(half4v*)(Ml_cm + col * 40 + row0) = pl;
    }
    __syncthreads();
    // ---- update: wave computes tiles (ti=0..1, tj in {2*wid, 2*wid+1}) ----
    half8 fmh[2], fml[2], fbh[2], fbl[2];
    #pragma unroll
    for (int ti = 0; ti < 2; ti++) {
      fmh[ti] = *(half8*)(Mh_cm + (ti * 16 + lane16) * 40 + quad * 8);
      fml[ti] = *(half8*)(Ml_cm + (ti * 16 + lane16) * 40 + quad * 8);
    }
    #pragma unroll
    for (int jj = 0; jj < 2; jj++) {
      int tj = 2 * wid + jj;
      fbh[jj] = *(half8*)(Ah_rm + (tj * 16 + lane16) * 40 + quad * 8);
      fbl[jj] = *(half8*)(Al_rm + (tj * 16 + lane16) * 40 + quad * 8);
    }
    floatx4 df[2][2];
    #pragma unroll
    for (int ti = 0; ti < 2; ti++)
      #pragma unroll
      for (int jj = 0; jj < 2; jj++) {
        df[ti][jj] = __builtin_amdgcn_mfma_f32_16x16x32_f16(
            fmh[ti], fbh[jj], zero4, 0, 0, 0);
        df[ti][jj] = __builtin_amdgcn_mfma_f32_16x16x32_f16(
            fmh[ti], fbl[jj], df[ti][jj], 0, 0, 0);
        df[ti][jj] = __builtin_amdgcn_mfma_f32_16x16x32_f16(
            fml[ti], fbh[jj], df[ti][jj], 0, 0, 0);
      }
    __syncthreads();   // WAR: all reads of Ah_rm/M done before overwrite
    if (!last) {
      #pragma unroll
      for (int ti = 0; ti < 2; ti++)
        #pragma unroll
        for (int jj = 0; jj < 2; jj++) {
          int tj = 2 * wid + jj;
          int z = tj * 16 + lane16;
          int d0 = ti * 16 + quad * 4;
          half4v ph, pl;
          #pragma unroll
          for (int rr = 0; rr < 4; rr++) {
            float v = df[ti][jj][rr];
            _Float16 h = (_Float16)v;
            ph[rr] = h; pl[rr] = (_Float16)(v - (float)h);
          }
          *(half4v*)(Ah_rm + z * 40 + d0) = ph;
          *(half4v*)(Al_rm + z * 40 + d0) = pl;
          #pragma unroll
          for (int rr = 0; rr < 4; rr++) {
            Ah_cm[(d0 + rr) * 72 + z] = ph[rr];
            Al_cm[(d0 + rr) * 72 + z] = pl[rr];
          }
        }
    } else {
      #pragma unroll
      for (int ti = 0; ti < 2; ti++)
        #pragma unroll
        for (int jj = 0; jj < 2; jj++) {
          int tj = 2 * wid + jj;
          int z = tj * 16 + lane16;
          int d0 = ti * 16 + quad * 4;
          float4 v;
          v.x = df[ti][jj][0]; v.y = df[ti][jj][1];
          v.z = df[ti][jj][2]; v.w = df[ti][jj][3];
          *(float4*)(Afin + z * 36 + d0) = v;
        }
    }
    __syncthreads();
  }
  #pragma unroll
  for (int j = 0; j < 4; j++) {
    int f = j * 512 + tid * 4;
    int z = f >> 5, d = f & 31;
    float4 v = *(const float4*)(Afin + z * 36 + d);
    *(float4*)(o + f) = v;
  }
}

// ======================= Sylvester flow (K=4 steps) =======================
__global__ __launch_bounds__(64) void flow_k(const float* __restrict__ amat,
    const float* __restrict__ fd, const float* __restrict__ dg1,
    const float* __restrict__ dg2, const float* __restrict__ ab,
    const float* __restrict__ eps, float* __restrict__ dout) {
  __shared__ float Ps[32][64];
  __shared__ float wsh[32], tsh[32], ush[32];
  int b = blockIdx.x, l = threadIdx.x;
  float mv  = dout[26624 + b * 64 + l];
  float lvv = dout[43008 + b * 64 + l];
  float z0 = mv + eps[b * 64 + l] * expf(0.5f * lvv);
  dout[59648 + b * 64 + l] = z0;
  float zv = z0;
  float ldj = 0.f;
  float q[32];
  for (int k = 0; k < 4; k++) {
    const float4* qrow = (const float4*)(amat + (size_t)(b * 4 + k) * 2048 + l * 32);
    #pragma unroll
    for (int j = 0; j < 8; j++) {
      float4 v = qrow[j];
      q[4*j] = v.x; q[4*j+1] = v.y; q[4*j+2] = v.z; q[4*j+3] = v.w;
    }
    #pragma unroll
    for (int d = 0; d < 32; d++) Ps[d][l] = zv * q[d];
    __syncthreads();
    if (l < 32) {
      const float4* pr = (const float4*)Ps[l];
      float s = 0.f;
      #pragma unroll
      for (int j = 0; j < 16; j++) {
        float4 v = pr[j];
        s += v.x + v.y + v.z + v.w;
      }
      wsh[l] = s;
    }
    __syncthreads();
    if (l < 32) {
      int e = l;
      float acc = ab[b * 128 + e * 4 + k] + wsh[e] * dg2[b * 128 + e * 4 + k];
      for (int d = e + 1; d < 32; d++)
        acc += wsh[d] * fd[b * 4096 + d * 128 + e * 4 + k];
      float tt = tanhf(acc);
      tsh[e] = tt;
      float dd = (1.f - tt * tt) * (dg1[b*128 + e*4 + k] * dg2[b*128 + e*4 + k]) + 1.f;
      ldj += logf(fabsf(dd));
    }
    __syncthreads();
    if (l < 32) {
      int d = l;
      float acc = tsh[d] * dg1[b * 128 + d * 4 + k];
      for (int e = d + 1; e < 32; e++)
        acc += fd[b * 4096 + d * 128 + e * 4 + k] * tsh[e];
      ush[d] = acc;
    }
    __syncthreads();
    #pragma unroll
    for (int d = 0; d < 32; d++) zv += q[d] * ush[d];
    __syncthreads();
  }
  dout[76032 + b * 64 + l] = zv;
  for (int off = 16; off > 0; off >>= 1) ldj += __shfl_down(ldj, off, 32);
  if (l == 0) dout[59392 + b] = ldj;
}

// ======================= host launch =======================
extern "C" void kernel_launch(void* const* d_in, const int* in_sizes, int n_in,
                              void* d_out, int out_size, void* d_ws, size_t ws_size,
                              hipStream_t stream) {
  (void)in_sizes; (void)n_in; (void)out_size; (void)ws_size;
  const float* x     = (const float*)d_in[0];
  const float* eps   = (const float*)d_in[1];
  const float* cw1   = (const float*)d_in[2];
  const float* cb1   = (const float*)d_in[3];
  const float* g1    = (const float*)d_in[4];
  const float* be1   = (const float*)d_in[5];
  const float* cw2   = (const float*)d_in[6];
  const float* cb2   = (const float*)d_in[7];
  const float* g2    = (const float*)d_in[8];
  const float* be2   = (const float*)d_in[9];
  const float* cw3   = (const float*)d_in[10];
  const float* cb3   = (const float*)d_in[11];
  const float* g3    = (const float*)d_in[12];
  const float* be3   = (const float*)d_in[13];
  const float* d1_w  = (const float*)d_in[14];
  const float* d1_b  = (const float*)d_in[15];
  const float* bn1_g = (const float*)d_in[16];
  const float* bn1_b = (const float*)d_in[17];
  const float* mu_w  = (const float*)d_in[18];
  const float* mu_b  = (const float*)d_in[19];
  const float* lv_w  = (const float*)d_in[20];
  const float* lv_b  = (const float*)d_in[21];
  const float* ad_w  = (const float*)d_in[22];
  const float* ad_b  = (const float*)d_in[23];
  const float* adg1_w= (const float*)d_in[24];
  const float* adg1_b= (const float*)d_in[25];
  const float* adg2_w= (const float*)d_in[26];
  const float* adg2_b= (const float*)d_in[27];
  const float* aq_w  = (const float*)d_in[28];
  const float* aq_b  = (const float*)d_in[29];
  const float* ab_w  = (const float*)d_in[30];
  const float* ab_b  = (const float*)d_in[31];
  const float* d3_w  = (const float*)d_in[32];
  const float* d3_b  = (const float*)d_in[33];
  const float* bn3_g = (const float*)d_in[34];
  const float* bn3_b = (const float*)d_in[35];
  const float* d4_w  = (const float*)d_in[36];
  const float* d4_b  = (const float*)d_in[37];
  const float* bn4_g = (const float*)d_in[38];
  const float* bn4_b = (const float*)d_in[39];
  const float* tw1   = (const float*)d_in[40];
  const float* tb1   = (const float*)d_in[41];
  const float* tg1   = (const float*)d_in[42];
  const float* tbe1  = (const float*)d_in[43];
  const float* tw2   = (const float*)d_in[44];
  const float* tb2   = (const float*)d_in[45];
  const float* tg2   = (const float*)d_in[46];
  const float* tbe2  = (const float*)d_in[47];
  const float* tw3   = (const float*)d_in[48];
  const float* tb3   = (const float*)d_in[49];

  float* out = (float*)d_out;
  float* wsf = (float*)d_ws;
  float* h1   = wsf;                 // 196608  (later: abuf, t2)
  float* h2   = wsf + 196608;        // 81920   (later: abuf tail, t1)
  float* h3   = wsf + 278528;        // 28672   (later: dec2)
  float* out1 = wsf + 307200;        // 262144  (later: dec1)
  float* fd   = wsf + 569344;        // 1048576
  float* dg1  = wsf + 1617920;       // 32768
  float* dg2  = wsf + 1650688;       // 32768
  float* qb   = wsf + 1683456;       // 2097152
  float* ab   = wsf + 3780608;       // 32768
  float* amat = wsf + 3813376;       // 2097152
  float* dec1 = out1;
  float* dec2 = h3;
  float* t1   = h2;
  float* t2   = h1;

  // A-fragment buffer: 524288 shorts = 262144 floats, reuses dead h1+h2
  short* ahi = (short*)wsf;
  short* alo = ahi + 262144;

  float* mean_o = out + 26624;
  float* lv_o   = out + 43008;
  float* z_o    = out + 76032;

  // ---------------- encoder ----------------
  conv1_k<<<768, 256, 0, stream>>>(x, cw1, cb1, h1);
  bn2d_k<<<32, 256, 0, stream>>>(h1, g1, be1, 32, 24);
  conv2_k<<<320, 256, 0, stream>>>(h1, cw2, cb2, h2);
  bn2d_k<<<16, 256, 0, stream>>>(h2, g2, be2, 16, 20);
  conv3_k<<<112, 256, 0, stream>>>(h2, cw3, cb3, h3);
  bn2d_k<<<8, 256, 0, stream>>>(h3, g3, be3, 8, 14);

  gemm_os_k<<<dim3(16, 4), 256, 0, stream>>>(h3, d1_w, d1_b, out1, 112, 1024);
  bn1d_k<<<32, 256, 0, stream>>>(out1, bn1_g, bn1_b, 1024);

  // ---------------- fused heads (MFMA) ----------------
  prep_a_k<<<128, 256, 0, stream>>>(out1, ahi, alo);

  HeadArgs ha;
  ha.W[0] = mu_w;   ha.b[0] = mu_b;   ha.dst[0] = mean_o; ha.ldw[0] = 64;   ha.op[0] = 0;
  ha.W[1] = lv_w;   ha.b[1] = lv_b;   ha.dst[1] = lv_o;   ha.ldw[1] = 64;   ha.op[1] = 0;
  ha.W[2] = ad_w;   ha.b[2] = ad_b;   ha.dst[2] = fd;     ha.ldw[2] = 4096; ha.op[2] = 0;
  ha.W[3] = adg1_w; ha.b[3] = adg1_b; ha.dst[3] = dg1;    ha.ldw[3] = 128;  ha.op[3] = 1;
  ha.W[4] = adg2_w; ha.b[4] = adg2_b; ha.dst[4] = dg2;    ha.ldw[4] = 128;  ha.op[4] = 1;
  ha.W[5] = aq_w;   ha.b[5] = aq_b;   ha.dst[5] = qb;     ha.ldw[5] = 8192; ha.op[5] = 0;
  ha.W[6] = ab_w;   ha.b[6] = ab_b;   ha.dst[6] = ab;     ha.ldw[6] = 128;  ha.op[6] = 0;
  ha.off[0] = 0;    ha.off[1] = 64;   ha.off[2] = 128;  ha.off[3] = 4224;
  ha.off[4] = 4352; ha.off[5] = 4480; ha.off[6] = 12672; ha.off[7] = 12800;
  heads_mfma_k<<<dim3(200, 4), 256, 0, stream>>>(ahi, alo, ha);

  // ---------------- orthogonalization + flow ----------------
  ns_f16split_k<<<1024, 128, 0, stream>>>(qb, amat);
  flow_k<<<256, 64, 0, stream>>>(amat, fd, dg1, dg2, ab, eps, out);

  // ---------------- decoder ----------------
  gemm_os_k<<<dim3(16, 4), 256, 0, stream>>>(z_o, d3_w, d3_b, dec1, 64, 1024);
  bn1d_k<<<32, 256, 0, stream>>>(dec1, bn3_g, bn3_b, 1024);
  hipMemsetAsync(dec2, 0, 28672 * sizeof(float), stream);
  gemm_ks_k<<<dim3(2, 4, 16), 256, 0, stream>>>(dec1, d4_w, d4_b, dec2);
  bn1d_k<<<4, 256, 0, stream>>>(dec2, bn4_g, bn4_b, 112);

  tconv1_k<<<320, 256, 0, stream>>>(dec2, tw1, tb1, t1);
  bn2d_k<<<16, 256, 0, stream>>>(t1, tg1, tbe1, 16, 20);
  tconv2_k<<<768, 256, 0, stream>>>(t1, tw2, tb2, t2);
  bn2d_k<<<32, 256, 0, stream>>>(t2, tg2, tbe2, 32, 24);
  tconv3_k<<<104, 256, 0, stream>>>(t2, tw3, tb3, out);
}

// Round 10
// 510.989 us; speedup vs baseline: 1.0987x; 1.0974x over previous
//
#include <hip/hip_runtime.h>
#include <math.h>

#define NS_STEPS 30

typedef __attribute__((ext_vector_type(8))) _Float16 half8;
typedef __attribute__((ext_vector_type(4))) _Float16 half4v;
typedef __attribute__((ext_vector_type(8))) short short8;
typedef __attribute__((ext_vector_type(4))) float floatx4;

static __device__ inline unsigned short f2bf(float f) {
  union { float f; unsigned u; } v; v.f = f;
  unsigned r = v.u + 0x7fffu + ((v.u >> 16) & 1u);
  return (unsigned short)(r >> 16);
}
static __device__ inline float bf2f(unsigned short h) {
  union { unsigned u; float f; } v; v.u = ((unsigned)h) << 16;
  return v.f;
}

// ======================= encoder convs =======================
__global__ __launch_bounds__(256) void conv1_k(const float* __restrict__ x,
    const float* __restrict__ w, const float* __restrict__ bias,
    float* __restrict__ out) {
  __shared__ float ws[384];
  int tid = threadIdx.x;
  for (int i = tid; i < 384; i += 256) ws[i] = w[i];
  __syncthreads();
  int idx = blockIdx.x * 256 + tid;
  if (idx >= 196608) return;
  int b = idx / 768, r = idx % 768;
  int c = r / 24, h = r % 24;
  const float* xb = x + b * 104 + h * 4;
  const float* wc = ws + c * 12;
  float acc = bias[c];
  #pragma unroll
  for (int kh = 0; kh < 3; kh++) {
    #pragma unroll
    for (int kw = 0; kw < 4; kw++)
      acc += xb[kh * 4 + kw] * wc[kh * 4 + kw];
  }
  out[idx] = acc;
}

__global__ __launch_bounds__(256) void conv2_k(const float* __restrict__ in,
    const float* __restrict__ w, const float* __restrict__ bias,
    float* __restrict__ out) {
  __shared__ float ws[2560];
  int tid = threadIdx.x;
  for (int i = tid; i < 2560; i += 256) ws[i] = w[i];
  __syncthreads();
  int idx = blockIdx.x * 256 + tid;
  if (idx >= 81920) return;
  int b = idx / 320, r = idx % 320;
  int c = r / 20, h = r % 20;
  const float* ib = in + b * 768 + h;
  const float* wc = ws + c * 160;
  float acc = bias[c];
  for (int i = 0; i < 32; i++) {
    #pragma unroll
    for (int kh = 0; kh < 5; kh++)
      acc += ib[i * 24 + kh] * wc[i * 5 + kh];
  }
  out[idx] = acc;
}

__global__ __launch_bounds__(256) void conv3_k(const float* __restrict__ in,
    const float* __restrict__ w, const float* __restrict__ bias,
    float* __restrict__ out) {
  __shared__ float ws[896];
  int tid = threadIdx.x;
  for (int i = tid; i < 896; i += 256) ws[i] = w[i];
  __syncthreads();
  int idx = blockIdx.x * 256 + tid;
  if (idx >= 28672) return;
  int b = idx / 112, r = idx % 112;
  int c = r / 14, h = r % 14;
  const float* ib = in + b * 320 + h;
  const float* wc = ws + c * 112;
  float acc = bias[c];
  for (int i = 0; i < 16; i++) {
    #pragma unroll
    for (int kh = 0; kh < 7; kh++)
      acc += ib[i * 20 + kh] * wc[i * 7 + kh];
  }
  out[idx] = acc;
}

// ======================= decoder tconvs =======================
__global__ __launch_bounds__(256) void tconv1_k(const float* __restrict__ in,
    const float* __restrict__ w, const float* __restrict__ bias,
    float* __restrict__ out) {
  __shared__ float ws[896];
  int tid = threadIdx.x;
  for (int i = tid; i < 896; i += 256) ws[i] = w[i];
  __syncthreads();
  int idx = blockIdx.x * 256 + tid;
  if (idx >= 81920) return;
  int b = idx / 320, r = idx % 320;
  int c = r / 20, s = r % 20;
  float acc = bias[c];
  for (int o = 0; o < 8; o++) {
    #pragma unroll
    for (int kh = 0; kh < 7; kh++) {
      int hs = s - kh;
      if (hs >= 0 && hs < 14)
        acc += in[b * 112 + o * 14 + hs] * ws[o * 112 + c * 7 + kh];
    }
  }
  out[idx] = acc;
}

__global__ __launch_bounds__(256) void tconv2_k(const float* __restrict__ in,
    const float* __restrict__ w, const float* __restrict__ bias,
    float* __restrict__ out) {
  __shared__ float ws[2560];
  int tid = threadIdx.x;
  for (int i = tid; i < 2560; i += 256) ws[i] = w[i];
  __syncthreads();
  int idx = blockIdx.x * 256 + tid;
  if (idx >= 196608) return;
  int b = idx / 768, r = idx % 768;
  int c = r / 24, s = r % 24;
  float acc = bias[c];
  for (int o = 0; o < 16; o++) {
    #pragma unroll
    for (int kh = 0; kh < 5; kh++) {
      int hs = s - kh;
      if (hs >= 0 && hs < 20)
        acc += in[b * 320 + o * 20 + hs] * ws[o * 160 + c * 5 + kh];
    }
  }
  out[idx] = acc;
}

__global__ __launch_bounds__(256) void tconv3_k(const float* __restrict__ in,
    const float* __restrict__ w, const float* __restrict__ bias,
    float* __restrict__ out) {
  __shared__ float ws[384];
  int tid = threadIdx.x;
  for (int i = tid; i < 384; i += 256) ws[i] = w[i];
  __syncthreads();
  int idx = blockIdx.x * 256 + tid;
  if (idx >= 26624) return;
  int b = idx / 104, r = idx % 104;
  int sh = r / 4, sw = r % 4;
  float acc = bias[0];
  for (int o = 0; o < 32; o++) {
    #pragma unroll
    for (int kh = 0; kh < 3; kh++) {
      int hs = sh - kh;
      if (hs >= 0 && hs < 24)
        acc += in[b * 768 + o * 24 + hs] * ws[o * 12 + kh * 4 + sw];
    }
  }
  out[idx] = acc;
}

// ======================= batchnorm =======================
__global__ __launch_bounds__(256) void bn2d_k(float* __restrict__ x,
    const float* __restrict__ g, const float* __restrict__ be,
    int C, int HW) {
  __shared__ float rs[256], rs2[256];
  int c = blockIdx.x, tid = threadIdx.x;
  int total = 256 * HW;
  float s = 0.f, s2 = 0.f;
  for (int i = tid; i < total; i += 256) {
    int b = i / HW, j = i - b * HW;
    float v = x[(b * C + c) * HW + j];
    s += v; s2 += v * v;
  }
  rs[tid] = s; rs2[tid] = s2;
  __syncthreads();
  for (int off = 128; off > 0; off >>= 1) {
    if (tid < off) { rs[tid] += rs[tid + off]; rs2[tid] += rs2[tid + off]; }
    __syncthreads();
  }
  float m = rs[0] / (float)total;
  float var = rs2[0] / (float)total - m * m;
  float rstd = rsqrtf(var + 1e-5f) * g[c];
  float bb = be[c];
  for (int i = tid; i < total; i += 256) {
    int b = i / HW, j = i - b * HW;
    size_t idx = (size_t)(b * C + c) * HW + j;
    float v = (x[idx] - m) * rstd + bb;
    x[idx] = v > 0.f ? v : 0.f;
  }
}

__global__ __launch_bounds__(256) void bn1d_k(float* __restrict__ x,
    const float* __restrict__ g, const float* __restrict__ be, int N) {
  __shared__ float p1[8][32], p2[8][32];
  int t = threadIdx.x;
  int cl = t & 31, rg = t >> 5;
  int c = blockIdx.x * 32 + cl;
  float s = 0.f, s2 = 0.f;
  if (c < N) {
    for (int r = rg * 32; r < rg * 32 + 32; r++) {
      float v = x[r * N + c];
      s += v; s2 += v * v;
    }
  }
  p1[rg][cl] = s; p2[rg][cl] = s2;
  __syncthreads();
  float ts = 0.f, ts2 = 0.f;
  #pragma unroll
  for (int i = 0; i < 8; i++) { ts += p1[i][cl]; ts2 += p2[i][cl]; }
  float m = ts * (1.f / 256.f);
  float var = ts2 * (1.f / 256.f) - m * m;
  float rstd = rsqrtf(var + 1e-5f) * ((c < N) ? g[c] : 1.f);
  float bb = (c < N) ? be[c] : 0.f;
  if (c < N) {
    for (int r = rg * 32; r < rg * 32 + 32; r++) {
      float v = (x[r * N + c] - m) * rstd + bb;
      x[r * N + c] = v > 0.f ? v : 0.f;
    }
  }
}

// ============== one-shot fp32 GEMM (K<=112, N multiple of 64) ===============
__global__ __launch_bounds__(256) void gemm_os_k(const float* __restrict__ A,
    const float* __restrict__ W, const float* __restrict__ bias,
    float* __restrict__ C, int K, int N) {
  __shared__ float As[112 * 68];
  __shared__ float Bs[112 * 68];
  int tid = threadIdx.x;
  int nb = blockIdx.x, mb = blockIdx.y;
  int K16 = K >> 4;
  {
    int row = tid >> 2;
    const float* Ar = A + (size_t)(mb * 64 + row) * K;
    for (int i = 0; i < K16; i++) {
      int j = (tid & 3) + 4 * i;
      float4 v = *(const float4*)(Ar + j * 4);
      int k = j * 4;
      As[k * 68 + row] = v.x;
      As[(k + 1) * 68 + row] = v.y;
      As[(k + 2) * 68 + row] = v.z;
      As[(k + 3) * 68 + row] = v.w;
    }
  }
  {
    int n4 = (tid & 15) * 4;
    for (int i = 0; i < K16; i++) {
      int k = (tid >> 4) + 16 * i;
      float4 v = *(const float4*)(W + (size_t)k * N + nb * 64 + n4);
      *(float4*)(Bs + k * 68 + n4) = v;
    }
  }
  __syncthreads();
  int tm = tid >> 4, tn = tid & 15;
  int m0 = tm * 4, n0 = tn * 4;
  float acc[4][4] = {{0.f}};
  #pragma unroll 8
  for (int kk = 0; kk < K; kk++) {
    float4 a = *(const float4*)(As + kk * 68 + m0);
    float4 b = *(const float4*)(Bs + kk * 68 + n0);
    acc[0][0] += a.x*b.x; acc[0][1] += a.x*b.y; acc[0][2] += a.x*b.z; acc[0][3] += a.x*b.w;
    acc[1][0] += a.y*b.x; acc[1][1] += a.y*b.y; acc[1][2] += a.y*b.z; acc[1][3] += a.y*b.w;
    acc[2][0] += a.z*b.x; acc[2][1] += a.z*b.y; acc[2][2] += a.z*b.z; acc[2][3] += a.z*b.w;
    acc[3][0] += a.w*b.x; acc[3][1] += a.w*b.y; acc[3][2] += a.w*b.z; acc[3][3] += a.w*b.w;
  }
  #pragma unroll
  for (int i = 0; i < 4; i++) {
    int m = mb * 64 + m0 + i;
    #pragma unroll
    for (int j = 0; j < 4; j++) {
      int n = nb * 64 + n0 + j;
      C[(size_t)m * N + n] = acc[i][j] + bias[n];
    }
  }
}

// ============== K-split fp32 GEMM for d4: C(256,112) += A@W chunk ===========
__global__ __launch_bounds__(256) void gemm_ks_k(const float* __restrict__ A,
    const float* __restrict__ W, const float* __restrict__ bias,
    float* __restrict__ C) {
  __shared__ float As[64 * 68];
  __shared__ float Bs[64 * 68];
  int tid = threadIdx.x;
  int nb = blockIdx.x, mb = blockIdx.y, kc = blockIdx.z;
  int k0 = kc * 64;
  {
    int row = tid >> 2;
    const float* Ar = A + (size_t)(mb * 64 + row) * 1024 + k0;
    #pragma unroll
    for (int i = 0; i < 4; i++) {
      int j = (tid & 3) + 4 * i;
      float4 v = *(const float4*)(Ar + j * 4);
      int k = j * 4;
      As[k * 68 + row] = v.x;
      As[(k + 1) * 68 + row] = v.y;
      As[(k + 2) * 68 + row] = v.z;
      As[(k + 3) * 68 + row] = v.w;
    }
  }
  {
    int n4 = (tid & 15) * 4;
    int nbase = nb * 64 + n4;
    #pragma unroll
    for (int i = 0; i < 4; i++) {
      int k = (tid >> 4) + 16 * i;
      const float* Wr = W + (size_t)(k0 + k) * 112;
      float4 v;
      v.x = (nbase     < 112) ? Wr[nbase]     : 0.f;
      v.y = (nbase + 1 < 112) ? Wr[nbase + 1] : 0.f;
      v.z = (nbase + 2 < 112) ? Wr[nbase + 2] : 0.f;
      v.w = (nbase + 3 < 112) ? Wr[nbase + 3] : 0.f;
      *(float4*)(Bs + k * 68 + n4) = v;
    }
  }
  __syncthreads();
  int tm = tid >> 4, tn = tid & 15;
  int m0 = tm * 4, n0 = tn * 4;
  float acc[4][4] = {{0.f}};
  #pragma unroll 8
  for (int kk = 0; kk < 64; kk++) {
    float4 a = *(const float4*)(As + kk * 68 + m0);
    float4 b = *(const float4*)(Bs + kk * 68 + n0);
    acc[0][0] += a.x*b.x; acc[0][1] += a.x*b.y; acc[0][2] += a.x*b.z; acc[0][3] += a.x*b.w;
    acc[1][0] += a.y*b.x; acc[1][1] += a.y*b.y; acc[1][2] += a.y*b.z; acc[1][3] += a.y*b.w;
    acc[2][0] += a.z*b.x; acc[2][1] += a.z*b.y; acc[2][2] += a.z*b.z; acc[2][3] += a.z*b.w;
    acc[3][0] += a.w*b.x; acc[3][1] += a.w*b.y; acc[3][2] += a.w*b.z; acc[3][3] += a.w*b.w;
  }
  #pragma unroll
  for (int i = 0; i < 4; i++) {
    int m = mb * 64 + m0 + i;
    #pragma unroll
    for (int j = 0; j < 4; j++) {
      int n = nb * 64 + n0 + j;
      if (n < 112) {
        float v = acc[i][j] + (kc == 0 ? bias[n] : 0.f);
        atomicAdd(&C[m * 112 + n], v);
      }
    }
  }
}

// ======= A-fragment precompute: out1 f32 -> bf16 hi/lo, MFMA-frag layout =====
__global__ __launch_bounds__(256) void prep_a_k(const float* __restrict__ A,
    short* __restrict__ ahi, short* __restrict__ alo) {
  int gi = blockIdx.x * 256 + threadIdx.x;   // 0..32767
  int lane = gi & 63;
  int t = gi >> 6;
  int mt = t & 3; t >>= 2;
  int c = t & 31; int mb = t >> 5;
  int row = mb * 64 + mt * 16 + (lane & 15);
  int k0 = c * 32 + (lane >> 4) * 8;
  const float* src = A + (size_t)row * 1024 + k0;
  float4 v0 = *(const float4*)(src);
  float4 v1 = *(const float4*)(src + 4);
  float av[8] = {v0.x, v0.y, v0.z, v0.w, v1.x, v1.y, v1.z, v1.w};
  short8 h, lo;
  #pragma unroll
  for (int i = 0; i < 8; i++) {
    unsigned short hh = f2bf(av[i]);
    h[i] = (short)hh;
    lo[i] = (short)f2bf(av[i] - bf2f(hh));
  }
  *(short8*)(ahi + (size_t)gi * 8) = h;
  *(short8*)(alo + (size_t)gi * 8) = lo;
}

// ================= fused head GEMMs, compensated-bf16 MFMA ==================
// v6 (unchanged): grid (200,4), W dbuf in LDS, lgkmcnt-only barrier.
struct HeadArgs {
  const float* W[7];
  const float* b[7];
  float* dst[7];
  int off[8];
  int ldw[7];
  int op[7];
};

__global__ __launch_bounds__(256) void heads_mfma_k(const short* __restrict__ ahi,
                                                    const short* __restrict__ alo,
                                                    HeadArgs ha) {
  __shared__ __align__(16) short Wsh[2][2][2048];  // [buf][hi/lo][64col x 32k frag]
  int tid = threadIdx.x;
  int nb = blockIdx.x;          // 64-col tile, 0..199
  int mq = blockIdx.y;          // 64-row quarter, 0..3
  int gc = nb * 64;
  int r = 0;
  while (gc >= ha.off[r + 1]) r++;
  const float* Wp = ha.W[r];
  const float* bias = ha.b[r];
  float* dst = ha.dst[r];
  int ldw = ha.ldw[r];
  int op = ha.op[r];
  int nloc = gc - ha.off[r];

  int w = tid >> 6, l = tid & 63;
  int lane16 = l & 15, quad = l >> 4;

  int c64 = tid & 63, q4 = tid >> 6;
  const float* wcol = Wp + (size_t)(q4 * 8) * ldw + nloc + c64;
  int wg = ((c64 >> 4) * 64 + q4 * 16 + (c64 & 15)) * 8;  // shorts

  const short* agh = ahi + (size_t)mq * 65536 + w * 512 + l * 8;
  const short* agl = alo + (size_t)mq * 65536 + w * 512 + l * 8;

  const floatx4 zero4 = {0.f, 0.f, 0.f, 0.f};
  floatx4 acc[4] = {zero4, zero4, zero4, zero4};

  float wvN[8], wvF[8];
  short8 whiN, wloN;
  short8 aCh, aCl, aNh, aNl;

  {
    float wv0[8];
    #pragma unroll
    for (int j = 0; j < 8; j++) wv0[j] = wcol[(size_t)j * ldw];
    #pragma unroll
    for (int j = 0; j < 8; j++) wvN[j] = wcol[(size_t)(32 + j) * ldw];
    aCh = *(const short8*)(agh);
    aCl = *(const short8*)(agl);
    #pragma unroll
    for (int j = 0; j < 8; j++) wvF[j] = wcol[(size_t)(64 + j) * ldw];
    short8 t0h, t0l;
    #pragma unroll
    for (int j = 0; j < 8; j++) {
      unsigned short hh = f2bf(wv0[j]);
      t0h[j] = (short)hh;
      t0l[j] = (short)f2bf(wv0[j] - bf2f(hh));
    }
    *(short8*)(&Wsh[0][0][wg]) = t0h;
    *(short8*)(&Wsh[0][1][wg]) = t0l;
    #pragma unroll
    for (int j = 0; j < 8; j++) {
      unsigned short hh = f2bf(wvN[j]);
      whiN[j] = (short)hh;
      wloN[j] = (short)f2bf(wvN[j] - bf2f(hh));
    }
    #pragma unroll
    for (int j = 0; j < 8; j++) wvN[j] = wvF[j];
    asm volatile("s_waitcnt lgkmcnt(0)" ::: "memory");
    __builtin_amdgcn_s_barrier();
  }

  for (int ch = 0; ch < 32; ++ch) {
    int p = ch & 1;
    if (ch < 31) {
      *(short8*)(&Wsh[p ^ 1][0][wg]) = whiN;
      *(short8*)(&Wsh[p ^ 1][1][wg]) = wloN;
    }
    if (ch < 29) {
      #pragma unroll
      for (int j = 0; j < 8; j++)
        wvF[j] = wcol[(size_t)((ch + 3) * 32 + j) * ldw];
    }
    if (ch < 31) {
      aNh = *(const short8*)(agh + (size_t)(ch + 1) * 2048);
      aNl = *(const short8*)(agl + (size_t)(ch + 1) * 2048);
    }
    short8 bh0 = *(const short8*)(&Wsh[p][0][(0 * 64 + l) * 8]);
    short8 bl0 = *(const short8*)(&Wsh[p][1][(0 * 64 + l) * 8]);
    short8 bh1 = *(const short8*)(&Wsh[p][0][(1 * 64 + l) * 8]);
    short8 bl1 = *(const short8*)(&Wsh[p][1][(1 * 64 + l) * 8]);
    short8 bh2 = *(const short8*)(&Wsh[p][0][(2 * 64 + l) * 8]);
    short8 bl2 = *(const short8*)(&Wsh[p][1][(2 * 64 + l) * 8]);
    short8 bh3 = *(const short8*)(&Wsh[p][0][(3 * 64 + l) * 8]);
    short8 bl3 = *(const short8*)(&Wsh[p][1][(3 * 64 + l) * 8]);
    acc[0] = __builtin_amdgcn_mfma_f32_16x16x32_bf16(aCh, bh0, acc[0], 0, 0, 0);
    acc[0] = __builtin_amdgcn_mfma_f32_16x16x32_bf16(aCh, bl0, acc[0], 0, 0, 0);
    acc[0] = __builtin_amdgcn_mfma_f32_16x16x32_bf16(aCl, bh0, acc[0], 0, 0, 0);
    acc[1] = __builtin_amdgcn_mfma_f32_16x16x32_bf16(aCh, bh1, acc[1], 0, 0, 0);
    acc[1] = __builtin_amdgcn_mfma_f32_16x16x32_bf16(aCh, bl1, acc[1], 0, 0, 0);
    acc[1] = __builtin_amdgcn_mfma_f32_16x16x32_bf16(aCl, bh1, acc[1], 0, 0, 0);
    acc[2] = __builtin_amdgcn_mfma_f32_16x16x32_bf16(aCh, bh2, acc[2], 0, 0, 0);
    acc[2] = __builtin_amdgcn_mfma_f32_16x16x32_bf16(aCh, bl2, acc[2], 0, 0, 0);
    acc[2] = __builtin_amdgcn_mfma_f32_16x16x32_bf16(aCl, bh2, acc[2], 0, 0, 0);
    acc[3] = __builtin_amdgcn_mfma_f32_16x16x32_bf16(aCh, bh3, acc[3], 0, 0, 0);
    acc[3] = __builtin_amdgcn_mfma_f32_16x16x32_bf16(aCh, bl3, acc[3], 0, 0, 0);
    acc[3] = __builtin_amdgcn_mfma_f32_16x16x32_bf16(aCl, bh3, acc[3], 0, 0, 0);
    if (ch < 30) {
      #pragma unroll
      for (int j = 0; j < 8; j++) {
        unsigned short hh = f2bf(wvN[j]);
        whiN[j] = (short)hh;
        wloN[j] = (short)f2bf(wvN[j] - bf2f(hh));
      }
    }
    if (ch < 29) {
      #pragma unroll
      for (int j = 0; j < 8; j++) wvN[j] = wvF[j];
    }
    if (ch < 31) { aCh = aNh; aCl = aNl; }
    asm volatile("s_waitcnt lgkmcnt(0)" ::: "memory");
    __builtin_amdgcn_s_barrier();
  }

  #pragma unroll
  for (int nf = 0; nf < 4; nf++) {
    int n = nloc + nf * 16 + lane16;
    float bv = bias[n];
    #pragma unroll
    for (int i = 0; i < 4; i++) {
      int m = mq * 64 + w * 16 + quad * 4 + i;
      float v = acc[nf][i] + bv;
      if (op == 1) v = tanhf(v);
      dst[(size_t)m * ldw + n] = v;
    }
  }
}

// ============ Newton-Schulz: fully compensated f16 MFMA =====================
// v3 EXACT (R5's proven 57us / 509us-total version). v4-v6 all regressed:
// the operand-swapped cm pass AND even the wave-uniform half8 ternary dedup
// both trip a fixed-budget register-allocator cliff (VGPR pinned at 68,
// ~80-99MB scratch stores). Do not re-derive fgh/fgl from registers; the
// LDS loads below are the stable form.
__global__ __launch_bounds__(128) void ns_f16split_k(const float* __restrict__ q,
                                                     float* __restrict__ amat) {
  __align__(16) __shared__ _Float16 arena[12288];
  int tid = threadIdx.x;
  int wid = tid >> 6;
  int l = tid & 63;
  int lane16 = l & 15, quad = l >> 4;
  _Float16* Ah_cm = arena;          // [32][72]
  _Float16* Al_cm = arena + 2304;   // [32][72]
  _Float16* Mh_cm = arena + 4608;   // [32][40]
  _Float16* Ml_cm = arena + 5888;   // [32][40]
  _Float16* Ah_rm = arena + 7168;   // [64][40]
  _Float16* Al_rm = arena + 9728;   // [64][40]
  float* Afin = (float*)arena;      // [64][36]

  const float* g = q + (size_t)blockIdx.x * 2048;
  float* o = amat + (size_t)blockIdx.x * 2048;

  if (wid == 0) {
    float vals[32];
    float ss = 0.f;
    #pragma unroll
    for (int j = 0; j < 8; j++) {
      float4 v = *(const float4*)(g + l * 32 + j * 4);
      vals[4*j] = v.x; vals[4*j+1] = v.y; vals[4*j+2] = v.z; vals[4*j+3] = v.w;
      ss += v.x*v.x + v.y*v.y + v.z*v.z + v.w*v.w;
    }
    #pragma unroll
    for (int off = 32; off > 0; off >>= 1) ss += __shfl_xor(ss, off);
    float rn = rsqrtf(ss);
    #pragma unroll
    for (int i = 0; i < 32; i++) vals[i] *= rn;
    #pragma unroll
    for (int j = 0; j < 8; j++) {
      half4v ph, pl;
      #pragma unroll
      for (int rr = 0; rr < 4; rr++) {
        float v = vals[4*j + rr];
        _Float16 h = (_Float16)v;
        _Float16 lo = (_Float16)(v - (float)h);
        ph[rr] = h; pl[rr] = lo;
      }
      *(half4v*)(Ah_rm + l * 40 + j * 4) = ph;
      *(half4v*)(Al_rm + l * 40 + j * 4) = pl;
    }
    #pragma unroll
    for (int i = 0; i < 32; i++) {
      float v = vals[i];
      _Float16 h = (_Float16)v;
      Ah_cm[i * 72 + l] = h;
      Al_cm[i * 72 + l] = (_Float16)(v - (float)h);
    }
  }
  __syncthreads();

  const floatx4 zero4 = {0.f, 0.f, 0.f, 0.f};
  for (int s = 0; s < NS_STEPS; s++) {
    bool last = (s == NS_STEPS - 1);
    half8 fgh[2], fgl[2];
    #pragma unroll
    for (int c = 0; c < 2; c++) {
      fgh[c] = *(half8*)(Ah_cm + (wid * 16 + lane16) * 72 + c * 32 + quad * 8);
      fgl[c] = *(half8*)(Al_cm + (wid * 16 + lane16) * 72 + c * 32 + quad * 8);
    }
    half8 fah[2][2], fal[2][2];
    #pragma unroll
    for (int ti = 0; ti < 2; ti++)
      #pragma unroll
      for (int c = 0; c < 2; c++) {
        fah[ti][c] = *(half8*)(Ah_cm + (ti * 16 + lane16) * 72 + c * 32 + quad * 8);
        fal[ti][c] = *(half8*)(Al_cm + (ti * 16 + lane16) * 72 + c * 32 + quad * 8);
      }
    floatx4 gf[2] = {zero4, zero4};
    #pragma unroll
    for (int ti = 0; ti < 2; ti++)
      #pragma unroll
      for (int c = 0; c < 2; c++) {
        gf[ti] = __builtin_amdgcn_mfma_f32_16x16x32_f16(
            fah[ti][c], fgh[c], gf[ti], 0, 0, 0);
        gf[ti] = __builtin_amdgcn_mfma_f32_16x16x32_f16(
            fah[ti][c], fgl[c], gf[ti], 0, 0, 0);
        gf[ti] = __builtin_amdgcn_mfma_f32_16x16x32_f16(
            fal[ti][c], fgh[c], gf[ti], 0, 0, 0);
      }
    #pragma unroll
    for (int ti = 0; ti < 2; ti++) {
      int col = wid * 16 + lane16;
      int row0 = ti * 16 + quad * 4;
      half4v ph, pl;
      #pragma unroll
      for (int rr = 0; rr < 4; rr++) {
        float m = ((row0 + rr) == col ? 1.5f : 0.f) - 0.5f * gf[ti][rr];
        _Float16 h = (_Float16)m;
        ph[rr] = h; pl[rr] = (_Float16)(m - (float)h);
      }
      *(half4v*)(Mh_cm + col * 40 + row0) = ph;
      *(half4v*)(Ml_cm + col * 40 + row0) = pl;
    }
    __syncthreads();
    half8 fmh[2], fml[2], fbh[2], fbl[2];
    #pragma unroll
    for (int ti = 0; ti < 2; ti++) {
      fmh[ti] = *(half8*)(Mh_cm + (ti * 16 + lane16) * 40 + quad * 8);
      fml[ti] = *(half8*)(Ml_cm + (ti * 16 + lane16) * 40 + quad * 8);
    }
    #pragma unroll
    for (int jj = 0; jj < 2; jj++) {
      int tj = 2 * wid + jj;
      fbh[jj] = *(half8*)(Ah_rm + (tj * 16 + lane16) * 40 + quad * 8);
      fbl[jj] = *(half8*)(Al_rm + (tj * 16 + lane16) * 40 + quad * 8);
    }
    floatx4 df[2][2];
    #pragma unroll
    for (int ti = 0; ti < 2; ti++)
      #pragma unroll
      for (int jj = 0; jj < 2; jj++) {
        df[ti][jj] = __builtin_amdgcn_mfma_f32_16x16x32_f16(
            fmh[ti], fbh[jj], zero4, 0, 0, 0);
        df[ti][jj] = __builtin_amdgcn_mfma_f32_16x16x32_f16(
            fmh[ti], fbl[jj], df[ti][jj], 0, 0, 0);
        df[ti][jj] = __builtin_amdgcn_mfma_f32_16x16x32_f16(
            fml[ti], fbh[jj], df[ti][jj], 0, 0, 0);
      }
    __syncthreads();   // WAR: all reads of Ah_rm/M done before overwrite
    if (!last) {
      #pragma unroll
      for (int ti = 0; ti < 2; ti++)
        #pragma unroll
        for (int jj = 0; jj < 2; jj++) {
          int tj = 2 * wid + jj;
          int z = tj * 16 + lane16;
          int d0 = ti * 16 + quad * 4;
          half4v ph, pl;
          #pragma unroll
          for (int rr = 0; rr < 4; rr++) {
            float v = df[ti][jj][rr];
            _Float16 h = (_Float16)v;
            ph[rr] = h; pl[rr] = (_Float16)(v - (float)h);
          }
          *(half4v*)(Ah_rm + z * 40 + d0) = ph;
          *(half4v*)(Al_rm + z * 40 + d0) = pl;
          #pragma unroll
          for (int rr = 0; rr < 4; rr++) {
            Ah_cm[(d0 + rr) * 72 + z] = ph[rr];
            Al_cm[(d0 + rr) * 72 + z] = pl[rr];
          }
        }
    } else {
      #pragma unroll
      for (int ti = 0; ti < 2; ti++)
        #pragma unroll
        for (int jj = 0; jj < 2; jj++) {
          int tj = 2 * wid + jj;
          int z = tj * 16 + lane16;
          int d0 = ti * 16 + quad * 4;
          float4 v;
          v.x = df[ti][jj][0]; v.y = df[ti][jj][1];
          v.z = df[ti][jj][2]; v.w = df[ti][jj][3];
          *(float4*)(Afin + z * 36 + d0) = v;
        }
    }
    __syncthreads();
  }
  #pragma unroll
  for (int j = 0; j < 4; j++) {
    int f = j * 512 + tid * 4;
    int z = f >> 5, d = f & 31;
    float4 v = *(const float4*)(Afin + z * 36 + d);
    *(float4*)(o + f) = v;
  }
}

// ======================= Sylvester flow (K=4 steps) =======================
__global__ __launch_bounds__(64) void flow_k(const float* __restrict__ amat,
    const float* __restrict__ fd, const float* __restrict__ dg1,
    const float* __restrict__ dg2, const float* __restrict__ ab,
    const float* __restrict__ eps, float* __restrict__ dout) {
  __shared__ float Ps[32][64];
  __shared__ float wsh[32], tsh[32], ush[32];
  int b = blockIdx.x, l = threadIdx.x;
  float mv  = dout[26624 + b * 64 + l];
  float lvv = dout[43008 + b * 64 + l];
  float z0 = mv + eps[b * 64 + l] * expf(0.5f * lvv);
  dout[59648 + b * 64 + l] = z0;
  float zv = z0;
  float ldj = 0.f;
  float q[32];
  for (int k = 0; k < 4; k++) {
    const float4* qrow = (const float4*)(amat + (size_t)(b * 4 + k) * 2048 + l * 32);
    #pragma unroll
    for (int j = 0; j < 8; j++) {
      float4 v = qrow[j];
      q[4*j] = v.x; q[4*j+1] = v.y; q[4*j+2] = v.z; q[4*j+3] = v.w;
    }
    #pragma unroll
    for (int d = 0; d < 32; d++) Ps[d][l] = zv * q[d];
    __syncthreads();
    if (l < 32) {
      const float4* pr = (const float4*)Ps[l];
      float s = 0.f;
      #pragma unroll
      for (int j = 0; j < 16; j++) {
        float4 v = pr[j];
        s += v.x + v.y + v.z + v.w;
      }
      wsh[l] = s;
    }
    __syncthreads();
    if (l < 32) {
      int e = l;
      float acc = ab[b * 128 + e * 4 + k] + wsh[e] * dg2[b * 128 + e * 4 + k];
      for (int d = e + 1; d < 32; d++)
        acc += wsh[d] * fd[b * 4096 + d * 128 + e * 4 + k];
      float tt = tanhf(acc);
      tsh[e] = tt;
      float dd = (1.f - tt * tt) * (dg1[b*128 + e*4 + k] * dg2[b*128 + e*4 + k]) + 1.f;
      ldj += logf(fabsf(dd));
    }
    __syncthreads();
    if (l < 32) {
      int d = l;
      float acc = tsh[d] * dg1[b * 128 + d * 4 + k];
      for (int e = d + 1; e < 32; e++)
        acc += fd[b * 4096 + d * 128 + e * 4 + k] * tsh[e];
      ush[d] = acc;
    }
    __syncthreads();
    #pragma unroll
    for (int d = 0; d < 32; d++) zv += q[d] * ush[d];
    __syncthreads();
  }
  dout[76032 + b * 64 + l] = zv;
  for (int off = 16; off > 0; off >>= 1) ldj += __shfl_down(ldj, off, 32);
  if (l == 0) dout[59392 + b] = ldj;
}

// ======================= host launch =======================
extern "C" void kernel_launch(void* const* d_in, const int* in_sizes, int n_in,
                              void* d_out, int out_size, void* d_ws, size_t ws_size,
                              hipStream_t stream) {
  (void)in_sizes; (void)n_in; (void)out_size; (void)ws_size;
  const float* x     = (const float*)d_in[0];
  const float* eps   = (const float*)d_in[1];
  const float* cw1   = (const float*)d_in[2];
  const float* cb1   = (const float*)d_in[3];
  const float* g1    = (const float*)d_in[4];
  const float* be1   = (const float*)d_in[5];
  const float* cw2   = (const float*)d_in[6];
  const float* cb2   = (const float*)d_in[7];
  const float* g2    = (const float*)d_in[8];
  const float* be2   = (const float*)d_in[9];
  const float* cw3   = (const float*)d_in[10];
  const float* cb3   = (const float*)d_in[11];
  const float* g3    = (const float*)d_in[12];
  const float* be3   = (const float*)d_in[13];
  const float* d1_w  = (const float*)d_in[14];
  const float* d1_b  = (const float*)d_in[15];
  const float* bn1_g = (const float*)d_in[16];
  const float* bn1_b = (const float*)d_in[17];
  const float* mu_w  = (const float*)d_in[18];
  const float* mu_b  = (const float*)d_in[19];
  const float* lv_w  = (const float*)d_in[20];
  const float* lv_b  = (const float*)d_in[21];
  const float* ad_w  = (const float*)d_in[22];
  const float* ad_b  = (const float*)d_in[23];
  const float* adg1_w= (const float*)d_in[24];
  const float* adg1_b= (const float*)d_in[25];
  const float* adg2_w= (const float*)d_in[26];
  const float* adg2_b= (const float*)d_in[27];
  const float* aq_w  = (const float*)d_in[28];
  const float* aq_b  = (const float*)d_in[29];
  const float* ab_w  = (const float*)d_in[30];
  const float* ab_b  = (const float*)d_in[31];
  const float* d3_w  = (const float*)d_in[32];
  const float* d3_b  = (const float*)d_in[33];
  const float* bn3_g = (const float*)d_in[34];
  const float* bn3_b = (const float*)d_in[35];
  const float* d4_w  = (const float*)d_in[36];
  const float* d4_b  = (const float*)d_in[37];
  const float* bn4_g = (const float*)d_in[38];
  const float* bn4_b = (const float*)d_in[39];
  const float* tw1   = (const float*)d_in[40];
  const float* tb1   = (const float*)d_in[41];
  const float* tg1   = (const float*)d_in[42];
  const float* tbe1  = (const float*)d_in[43];
  const float* tw2   = (const float*)d_in[44];
  const float* tb2   = (const float*)d_in[45];
  const float* tg2   = (const float*)d_in[46];
  const float* tbe2  = (const float*)d_in[47];
  const float* tw3   = (const float*)d_in[48];
  const float* tb3   = (const float*)d_in[49];

  float* out = (float*)d_out;
  float* wsf = (float*)d_ws;
  float* h1   = wsf;                 // 196608  (later: abuf, t2)
  float* h2   = wsf + 196608;        // 81920   (later: abuf tail, t1)
  float* h3   = wsf + 278528;        // 28672   (later: dec2)
  float* out1 = wsf + 307200;        // 262144  (later: dec1)
  float* fd   = wsf + 569344;        // 1048576
  float* dg1  = wsf + 1617920;       // 32768
  float* dg2  = wsf + 1650688;       // 32768
  float* qb   = wsf + 1683456;       // 2097152
  float* ab   = wsf + 3780608;       // 32768
  float* amat = wsf + 3813376;       // 2097152
  float* dec1 = out1;
  float* dec2 = h3;
  float* t1   = h2;
  float* t2   = h1;

  // A-fragment buffer: 524288 shorts = 262144 floats, reuses dead h1+h2
  short* ahi = (short*)wsf;
  short* alo = ahi + 262144;

  float* mean_o = out + 26624;
  float* lv_o   = out + 43008;
  float* z_o    = out + 76032;

  // ---------------- encoder ----------------
  conv1_k<<<768, 256, 0, stream>>>(x, cw1, cb1, h1);
  bn2d_k<<<32, 256, 0, stream>>>(h1, g1, be1, 32, 24);
  conv2_k<<<320, 256, 0, stream>>>(h1, cw2, cb2, h2);
  bn2d_k<<<16, 256, 0, stream>>>(h2, g2, be2, 16, 20);
  conv3_k<<<112, 256, 0, stream>>>(h2, cw3, cb3, h3);
  bn2d_k<<<8, 256, 0, stream>>>(h3, g3, be3, 8, 14);

  gemm_os_k<<<dim3(16, 4), 256, 0, stream>>>(h3, d1_w, d1_b, out1, 112, 1024);
  bn1d_k<<<32, 256, 0, stream>>>(out1, bn1_g, bn1_b, 1024);

  // ---------------- fused heads (MFMA) ----------------
  prep_a_k<<<128, 256, 0, stream>>>(out1, ahi, alo);

  HeadArgs ha;
  ha.W[0] = mu_w;   ha.b[0] = mu_b;   ha.dst[0] = mean_o; ha.ldw[0] = 64;   ha.op[0] = 0;
  ha.W[1] = lv_w;   ha.b[1] = lv_b;   ha.dst[1] = lv_o;   ha.ldw[1] = 64;   ha.op[1] = 0;
  ha.W[2] = ad_w;   ha.b[2] = ad_b;   ha.dst[2] = fd;     ha.ldw[2] = 4096; ha.op[2] = 0;
  ha.W[3] = adg1_w; ha.b[3] = adg1_b; ha.dst[3] = dg1;    ha.ldw[3] = 128;  ha.op[3] = 1;
  ha.W[4] = adg2_w; ha.b[4] = adg2_b; ha.dst[4] = dg2;    ha.ldw[4] = 128;  ha.op[4] = 1;
  ha.W[5] = aq_w;   ha.b[5] = aq_b;   ha.dst[5] = qb;     ha.ldw[5] = 8192; ha.op[5] = 0;
  ha.W[6] = ab_w;   ha.b[6] = ab_b;   ha.dst[6] = ab;     ha.ldw[6] = 128;  ha.op[6] = 0;
  ha.off[0] = 0;    ha.off[1] = 64;   ha.off[2] = 128;  ha.off[3] = 4224;
  ha.off[4] = 4352; ha.off[5] = 4480; ha.off[6] = 12672; ha.off[7] = 12800;
  heads_mfma_k<<<dim3(200, 4), 256, 0, stream>>>(ahi, alo, ha);

  // ---------------- orthogonalization + flow ----------------
  ns_f16split_k<<<1024, 128, 0, stream>>>(qb, amat);
  flow_k<<<256, 64, 0, stream>>>(amat, fd, dg1, dg2, ab, eps, out);

  // ---------------- decoder ----------------
  gemm_os_k<<<dim3(16, 4), 256, 0, stream>>>(z_o, d3_w, d3_b, dec1, 64, 1024);
  bn1d_k<<<32, 256, 0, stream>>>(dec1, bn3_g, bn3_b, 1024);
  hipMemsetAsync(dec2, 0, 28672 * sizeof(float), stream);
  gemm_ks_k<<<dim3(2, 4, 16), 256, 0, stream>>>(dec1, d4_w, d4_b, dec2);
  bn1d_k<<<4, 256, 0, stream>>>(dec2, bn4_g, bn4_b, 112);

  tconv1_k<<<320, 256, 0, stream>>>(dec2, tw1, tb1, t1);
  bn2d_k<<<16, 256, 0, stream>>>(t1, tg1, tbe1, 16, 20);
  tconv2_k<<<768, 256, 0, stream>>>(t1, tw2, tb2, t2);
  bn2d_k<<<32, 256, 0, stream>>>(t2, tg2, tbe2, 32, 24);
  tconv3_k<<<104, 256, 0, stream>>>(t2, tw3, tb3, out);
}

// Round 11
// 502.313 us; speedup vs baseline: 1.1177x; 1.0173x over previous
//
#include <hip/hip_runtime.h>
#include <math.h>

#define NS_STEPS 24

typedef __attribute__((ext_vector_type(8))) _Float16 half8;
typedef __attribute__((ext_vector_type(4))) _Float16 half4v;
typedef __attribute__((ext_vector_type(8))) short short8;
typedef __attribute__((ext_vector_type(4))) float floatx4;

static __device__ inline unsigned short f2bf(float f) {
  union { float f; unsigned u; } v; v.f = f;
  unsigned r = v.u + 0x7fffu + ((v.u >> 16) & 1u);
  return (unsigned short)(r >> 16);
}
static __device__ inline float bf2f(unsigned short h) {
  union { unsigned u; float f; } v; v.u = ((unsigned)h) << 16;
  return v.f;
}

// ======================= encoder convs =======================
__global__ __launch_bounds__(256) void conv1_k(const float* __restrict__ x,
    const float* __restrict__ w, const float* __restrict__ bias,
    float* __restrict__ out) {
  __shared__ float ws[384];
  int tid = threadIdx.x;
  for (int i = tid; i < 384; i += 256) ws[i] = w[i];
  __syncthreads();
  int idx = blockIdx.x * 256 + tid;
  if (idx >= 196608) return;
  int b = idx / 768, r = idx % 768;
  int c = r / 24, h = r % 24;
  const float* xb = x + b * 104 + h * 4;
  const float* wc = ws + c * 12;
  float acc = bias[c];
  #pragma unroll
  for (int kh = 0; kh < 3; kh++) {
    #pragma unroll
    for (int kw = 0; kw < 4; kw++)
      acc += xb[kh * 4 + kw] * wc[kh * 4 + kw];
  }
  out[idx] = acc;
}

__global__ __launch_bounds__(256) void conv2_k(const float* __restrict__ in,
    const float* __restrict__ w, const float* __restrict__ bias,
    float* __restrict__ out) {
  __shared__ float ws[2560];
  int tid = threadIdx.x;
  for (int i = tid; i < 2560; i += 256) ws[i] = w[i];
  __syncthreads();
  int idx = blockIdx.x * 256 + tid;
  if (idx >= 81920) return;
  int b = idx / 320, r = idx % 320;
  int c = r / 20, h = r % 20;
  const float* ib = in + b * 768 + h;
  const float* wc = ws + c * 160;
  float acc = bias[c];
  for (int i = 0; i < 32; i++) {
    #pragma unroll
    for (int kh = 0; kh < 5; kh++)
      acc += ib[i * 24 + kh] * wc[i * 5 + kh];
  }
  out[idx] = acc;
}

__global__ __launch_bounds__(256) void conv3_k(const float* __restrict__ in,
    const float* __restrict__ w, const float* __restrict__ bias,
    float* __restrict__ out) {
  __shared__ float ws[896];
  int tid = threadIdx.x;
  for (int i = tid; i < 896; i += 256) ws[i] = w[i];
  __syncthreads();
  int idx = blockIdx.x * 256 + tid;
  if (idx >= 28672) return;
  int b = idx / 112, r = idx % 112;
  int c = r / 14, h = r % 14;
  const float* ib = in + b * 320 + h;
  const float* wc = ws + c * 112;
  float acc = bias[c];
  for (int i = 0; i < 16; i++) {
    #pragma unroll
    for (int kh = 0; kh < 7; kh++)
      acc += ib[i * 20 + kh] * wc[i * 7 + kh];
  }
  out[idx] = acc;
}

// ======================= decoder tconvs =======================
__global__ __launch_bounds__(256) void tconv1_k(const float* __restrict__ in,
    const float* __restrict__ w, const float* __restrict__ bias,
    float* __restrict__ out) {
  __shared__ float ws[896];
  int tid = threadIdx.x;
  for (int i = tid; i < 896; i += 256) ws[i] = w[i];
  __syncthreads();
  int idx = blockIdx.x * 256 + tid;
  if (idx >= 81920) return;
  int b = idx / 320, r = idx % 320;
  int c = r / 20, s = r % 20;
  float acc = bias[c];
  for (int o = 0; o < 8; o++) {
    #pragma unroll
    for (int kh = 0; kh < 7; kh++) {
      int hs = s - kh;
      if (hs >= 0 && hs < 14)
        acc += in[b * 112 + o * 14 + hs] * ws[o * 112 + c * 7 + kh];
    }
  }
  out[idx] = acc;
}

__global__ __launch_bounds__(256) void tconv2_k(const float* __restrict__ in,
    const float* __restrict__ w, const float* __restrict__ bias,
    float* __restrict__ out) {
  __shared__ float ws[2560];
  int tid = threadIdx.x;
  for (int i = tid; i < 2560; i += 256) ws[i] = w[i];
  __syncthreads();
  int idx = blockIdx.x * 256 + tid;
  if (idx >= 196608) return;
  int b = idx / 768, r = idx % 768;
  int c = r / 24, s = r % 24;
  float acc = bias[c];
  for (int o = 0; o < 16; o++) {
    #pragma unroll
    for (int kh = 0; kh < 5; kh++) {
      int hs = s - kh;
      if (hs >= 0 && hs < 20)
        acc += in[b * 320 + o * 20 + hs] * ws[o * 160 + c * 5 + kh];
    }
  }
  out[idx] = acc;
}

__global__ __launch_bounds__(256) void tconv3_k(const float* __restrict__ in,
    const float* __restrict__ w, const float* __restrict__ bias,
    float* __restrict__ out) {
  __shared__ float ws[384];
  int tid = threadIdx.x;
  for (int i = tid; i < 384; i += 256) ws[i] = w[i];
  __syncthreads();
  int idx = blockIdx.x * 256 + tid;
  if (idx >= 26624) return;
  int b = idx / 104, r = idx % 104;
  int sh = r / 4, sw = r % 4;
  float acc = bias[0];
  for (int o = 0; o < 32; o++) {
    #pragma unroll
    for (int kh = 0; kh < 3; kh++) {
      int hs = sh - kh;
      if (hs >= 0 && hs < 24)
        acc += in[b * 768 + o * 24 + hs] * ws[o * 12 + kh * 4 + sw];
    }
  }
  out[idx] = acc;
}

// ======================= batchnorm =======================
__global__ __launch_bounds__(256) void bn2d_k(float* __restrict__ x,
    const float* __restrict__ g, const float* __restrict__ be,
    int C, int HW) {
  __shared__ float rs[256], rs2[256];
  int c = blockIdx.x, tid = threadIdx.x;
  int total = 256 * HW;
  float s = 0.f, s2 = 0.f;
  for (int i = tid; i < total; i += 256) {
    int b = i / HW, j = i - b * HW;
    float v = x[(b * C + c) * HW + j];
    s += v; s2 += v * v;
  }
  rs[tid] = s; rs2[tid] = s2;
  __syncthreads();
  for (int off = 128; off > 0; off >>= 1) {
    if (tid < off) { rs[tid] += rs[tid + off]; rs2[tid] += rs2[tid + off]; }
    __syncthreads();
  }
  float m = rs[0] / (float)total;
  float var = rs2[0] / (float)total - m * m;
  float rstd = rsqrtf(var + 1e-5f) * g[c];
  float bb = be[c];
  for (int i = tid; i < total; i += 256) {
    int b = i / HW, j = i - b * HW;
    size_t idx = (size_t)(b * C + c) * HW + j;
    float v = (x[idx] - m) * rstd + bb;
    x[idx] = v > 0.f ? v : 0.f;
  }
}

__global__ __launch_bounds__(256) void bn1d_k(float* __restrict__ x,
    const float* __restrict__ g, const float* __restrict__ be, int N) {
  __shared__ float p1[8][32], p2[8][32];
  int t = threadIdx.x;
  int cl = t & 31, rg = t >> 5;
  int c = blockIdx.x * 32 + cl;
  float s = 0.f, s2 = 0.f;
  if (c < N) {
    for (int r = rg * 32; r < rg * 32 + 32; r++) {
      float v = x[r * N + c];
      s += v; s2 += v * v;
    }
  }
  p1[rg][cl] = s; p2[rg][cl] = s2;
  __syncthreads();
  float ts = 0.f, ts2 = 0.f;
  #pragma unroll
  for (int i = 0; i < 8; i++) { ts += p1[i][cl]; ts2 += p2[i][cl]; }
  float m = ts * (1.f / 256.f);
  float var = ts2 * (1.f / 256.f) - m * m;
  float rstd = rsqrtf(var + 1e-5f) * ((c < N) ? g[c] : 1.f);
  float bb = (c < N) ? be[c] : 0.f;
  if (c < N) {
    for (int r = rg * 32; r < rg * 32 + 32; r++) {
      float v = (x[r * N + c] - m) * rstd + bb;
      x[r * N + c] = v > 0.f ? v : 0.f;
    }
  }
}

// ============== one-shot fp32 GEMM (K<=112, N multiple of 64) ===============
__global__ __launch_bounds__(256) void gemm_os_k(const float* __restrict__ A,
    const float* __restrict__ W, const float* __restrict__ bias,
    float* __restrict__ C, int K, int N) {
  __shared__ float As[112 * 68];
  __shared__ float Bs[112 * 68];
  int tid = threadIdx.x;
  int nb = blockIdx.x, mb = blockIdx.y;
  int K16 = K >> 4;
  {
    int row = tid >> 2;
    const float* Ar = A + (size_t)(mb * 64 + row) * K;
    for (int i = 0; i < K16; i++) {
      int j = (tid & 3) + 4 * i;
      float4 v = *(const float4*)(Ar + j * 4);
      int k = j * 4;
      As[k * 68 + row] = v.x;
      As[(k + 1) * 68 + row] = v.y;
      As[(k + 2) * 68 + row] = v.z;
      As[(k + 3) * 68 + row] = v.w;
    }
  }
  {
    int n4 = (tid & 15) * 4;
    for (int i = 0; i < K16; i++) {
      int k = (tid >> 4) + 16 * i;
      float4 v = *(const float4*)(W + (size_t)k * N + nb * 64 + n4);
      *(float4*)(Bs + k * 68 + n4) = v;
    }
  }
  __syncthreads();
  int tm = tid >> 4, tn = tid & 15;
  int m0 = tm * 4, n0 = tn * 4;
  float acc[4][4] = {{0.f}};
  #pragma unroll 8
  for (int kk = 0; kk < K; kk++) {
    float4 a = *(const float4*)(As + kk * 68 + m0);
    float4 b = *(const float4*)(Bs + kk * 68 + n0);
    acc[0][0] += a.x*b.x; acc[0][1] += a.x*b.y; acc[0][2] += a.x*b.z; acc[0][3] += a.x*b.w;
    acc[1][0] += a.y*b.x; acc[1][1] += a.y*b.y; acc[1][2] += a.y*b.z; acc[1][3] += a.y*b.w;
    acc[2][0] += a.z*b.x; acc[2][1] += a.z*b.y; acc[2][2] += a.z*b.z; acc[2][3] += a.z*b.w;
    acc[3][0] += a.w*b.x; acc[3][1] += a.w*b.y; acc[3][2] += a.w*b.z; acc[3][3] += a.w*b.w;
  }
  #pragma unroll
  for (int i = 0; i < 4; i++) {
    int m = mb * 64 + m0 + i;
    #pragma unroll
    for (int j = 0; j < 4; j++) {
      int n = nb * 64 + n0 + j;
      C[(size_t)m * N + n] = acc[i][j] + bias[n];
    }
  }
}

// ============== K-split fp32 GEMM for d4: C(256,112) += A@W chunk ===========
__global__ __launch_bounds__(256) void gemm_ks_k(const float* __restrict__ A,
    const float* __restrict__ W, const float* __restrict__ bias,
    float* __restrict__ C) {
  __shared__ float As[64 * 68];
  __shared__ float Bs[64 * 68];
  int tid = threadIdx.x;
  int nb = blockIdx.x, mb = blockIdx.y, kc = blockIdx.z;
  int k0 = kc * 64;
  {
    int row = tid >> 2;
    const float* Ar = A + (size_t)(mb * 64 + row) * 1024 + k0;
    #pragma unroll
    for (int i = 0; i < 4; i++) {
      int j = (tid & 3) + 4 * i;
      float4 v = *(const float4*)(Ar + j * 4);
      int k = j * 4;
      As[k * 68 + row] = v.x;
      As[(k + 1) * 68 + row] = v.y;
      As[(k + 2) * 68 + row] = v.z;
      As[(k + 3) * 68 + row] = v.w;
    }
  }
  {
    int n4 = (tid & 15) * 4;
    int nbase = nb * 64 + n4;
    #pragma unroll
    for (int i = 0; i < 4; i++) {
      int k = (tid >> 4) + 16 * i;
      const float* Wr = W + (size_t)(k0 + k) * 112;
      float4 v;
      v.x = (nbase     < 112) ? Wr[nbase]     : 0.f;
      v.y = (nbase + 1 < 112) ? Wr[nbase + 1] : 0.f;
      v.z = (nbase + 2 < 112) ? Wr[nbase + 2] : 0.f;
      v.w = (nbase + 3 < 112) ? Wr[nbase + 3] : 0.f;
      *(float4*)(Bs + k * 68 + n4) = v;
    }
  }
  __syncthreads();
  int tm = tid >> 4, tn = tid & 15;
  int m0 = tm * 4, n0 = tn * 4;
  float acc[4][4] = {{0.f}};
  #pragma unroll 8
  for (int kk = 0; kk < 64; kk++) {
    float4 a = *(const float4*)(As + kk * 68 + m0);
    float4 b = *(const float4*)(Bs + kk * 68 + n0);
    acc[0][0] += a.x*b.x; acc[0][1] += a.x*b.y; acc[0][2] += a.x*b.z; acc[0][3] += a.x*b.w;
    acc[1][0] += a.y*b.x; acc[1][1] += a.y*b.y; acc[1][2] += a.y*b.z; acc[1][3] += a.y*b.w;
    acc[2][0] += a.z*b.x; acc[2][1] += a.z*b.y; acc[2][2] += a.z*b.z; acc[2][3] += a.z*b.w;
    acc[3][0] += a.w*b.x; acc[3][1] += a.w*b.y; acc[3][2] += a.w*b.z; acc[3][3] += a.w*b.w;
  }
  #pragma unroll
  for (int i = 0; i < 4; i++) {
    int m = mb * 64 + m0 + i;
    #pragma unroll
    for (int j = 0; j < 4; j++) {
      int n = nb * 64 + n0 + j;
      if (n < 112) {
        float v = acc[i][j] + (kc == 0 ? bias[n] : 0.f);
        atomicAdd(&C[m * 112 + n], v);
      }
    }
  }
}

// ======= A-fragment precompute: out1 f32 -> bf16 hi/lo, MFMA-frag layout =====
__global__ __launch_bounds__(256) void prep_a_k(const float* __restrict__ A,
    short* __restrict__ ahi, short* __restrict__ alo) {
  int gi = blockIdx.x * 256 + threadIdx.x;   // 0..32767
  int lane = gi & 63;
  int t = gi >> 6;
  int mt = t & 3; t >>= 2;
  int c = t & 31; int mb = t >> 5;
  int row = mb * 64 + mt * 16 + (lane & 15);
  int k0 = c * 32 + (lane >> 4) * 8;
  const float* src = A + (size_t)row * 1024 + k0;
  float4 v0 = *(const float4*)(src);
  float4 v1 = *(const float4*)(src + 4);
  float av[8] = {v0.x, v0.y, v0.z, v0.w, v1.x, v1.y, v1.z, v1.w};
  short8 h, lo;
  #pragma unroll
  for (int i = 0; i < 8; i++) {
    unsigned short hh = f2bf(av[i]);
    h[i] = (short)hh;
    lo[i] = (short)f2bf(av[i] - bf2f(hh));
  }
  *(short8*)(ahi + (size_t)gi * 8) = h;
  *(short8*)(alo + (size_t)gi * 8) = lo;
}

// ================= fused head GEMMs, compensated-bf16 MFMA ==================
// v6 (unchanged): grid (200,4), W dbuf in LDS, lgkmcnt-only barrier.
struct HeadArgs {
  const float* W[7];
  const float* b[7];
  float* dst[7];
  int off[8];
  int ldw[7];
  int op[7];
};

__global__ __launch_bounds__(256) void heads_mfma_k(const short* __restrict__ ahi,
                                                    const short* __restrict__ alo,
                                                    HeadArgs ha) {
  __shared__ __align__(16) short Wsh[2][2][2048];  // [buf][hi/lo][64col x 32k frag]
  int tid = threadIdx.x;
  int nb = blockIdx.x;          // 64-col tile, 0..199
  int mq = blockIdx.y;          // 64-row quarter, 0..3
  int gc = nb * 64;
  int r = 0;
  while (gc >= ha.off[r + 1]) r++;
  const float* Wp = ha.W[r];
  const float* bias = ha.b[r];
  float* dst = ha.dst[r];
  int ldw = ha.ldw[r];
  int op = ha.op[r];
  int nloc = gc - ha.off[r];

  int w = tid >> 6, l = tid & 63;
  int lane16 = l & 15, quad = l >> 4;

  int c64 = tid & 63, q4 = tid >> 6;
  const float* wcol = Wp + (size_t)(q4 * 8) * ldw + nloc + c64;
  int wg = ((c64 >> 4) * 64 + q4 * 16 + (c64 & 15)) * 8;  // shorts

  const short* agh = ahi + (size_t)mq * 65536 + w * 512 + l * 8;
  const short* agl = alo + (size_t)mq * 65536 + w * 512 + l * 8;

  const floatx4 zero4 = {0.f, 0.f, 0.f, 0.f};
  floatx4 acc[4] = {zero4, zero4, zero4, zero4};

  float wvN[8], wvF[8];
  short8 whiN, wloN;
  short8 aCh, aCl, aNh, aNl;

  {
    float wv0[8];
    #pragma unroll
    for (int j = 0; j < 8; j++) wv0[j] = wcol[(size_t)j * ldw];
    #pragma unroll
    for (int j = 0; j < 8; j++) wvN[j] = wcol[(size_t)(32 + j) * ldw];
    aCh = *(const short8*)(agh);
    aCl = *(const short8*)(agl);
    #pragma unroll
    for (int j = 0; j < 8; j++) wvF[j] = wcol[(size_t)(64 + j) * ldw];
    short8 t0h, t0l;
    #pragma unroll
    for (int j = 0; j < 8; j++) {
      unsigned short hh = f2bf(wv0[j]);
      t0h[j] = (short)hh;
      t0l[j] = (short)f2bf(wv0[j] - bf2f(hh));
    }
    *(short8*)(&Wsh[0][0][wg]) = t0h;
    *(short8*)(&Wsh[0][1][wg]) = t0l;
    #pragma unroll
    for (int j = 0; j < 8; j++) {
      unsigned short hh = f2bf(wvN[j]);
      whiN[j] = (short)hh;
      wloN[j] = (short)f2bf(wvN[j] - bf2f(hh));
    }
    #pragma unroll
    for (int j = 0; j < 8; j++) wvN[j] = wvF[j];
    asm volatile("s_waitcnt lgkmcnt(0)" ::: "memory");
    __builtin_amdgcn_s_barrier();
  }

  for (int ch = 0; ch < 32; ++ch) {
    int p = ch & 1;
    if (ch < 31) {
      *(short8*)(&Wsh[p ^ 1][0][wg]) = whiN;
      *(short8*)(&Wsh[p ^ 1][1][wg]) = wloN;
    }
    if (ch < 29) {
      #pragma unroll
      for (int j = 0; j < 8; j++)
        wvF[j] = wcol[(size_t)((ch + 3) * 32 + j) * ldw];
    }
    if (ch < 31) {
      aNh = *(const short8*)(agh + (size_t)(ch + 1) * 2048);
      aNl = *(const short8*)(agl + (size_t)(ch + 1) * 2048);
    }
    short8 bh0 = *(const short8*)(&Wsh[p][0][(0 * 64 + l) * 8]);
    short8 bl0 = *(const short8*)(&Wsh[p][1][(0 * 64 + l) * 8]);
    short8 bh1 = *(const short8*)(&Wsh[p][0][(1 * 64 + l) * 8]);
    short8 bl1 = *(const short8*)(&Wsh[p][1][(1 * 64 + l) * 8]);
    short8 bh2 = *(const short8*)(&Wsh[p][0][(2 * 64 + l) * 8]);
    short8 bl2 = *(const short8*)(&Wsh[p][1][(2 * 64 + l) * 8]);
    short8 bh3 = *(const short8*)(&Wsh[p][0][(3 * 64 + l) * 8]);
    short8 bl3 = *(const short8*)(&Wsh[p][1][(3 * 64 + l) * 8]);
    acc[0] = __builtin_amdgcn_mfma_f32_16x16x32_bf16(aCh, bh0, acc[0], 0, 0, 0);
    acc[0] = __builtin_amdgcn_mfma_f32_16x16x32_bf16(aCh, bl0, acc[0], 0, 0, 0);
    acc[0] = __builtin_amdgcn_mfma_f32_16x16x32_bf16(aCl, bh0, acc[0], 0, 0, 0);
    acc[1] = __builtin_amdgcn_mfma_f32_16x16x32_bf16(aCh, bh1, acc[1], 0, 0, 0);
    acc[1] = __builtin_amdgcn_mfma_f32_16x16x32_bf16(aCh, bl1, acc[1], 0, 0, 0);
    acc[1] = __builtin_amdgcn_mfma_f32_16x16x32_bf16(aCl, bh1, acc[1], 0, 0, 0);
    acc[2] = __builtin_amdgcn_mfma_f32_16x16x32_bf16(aCh, bh2, acc[2], 0, 0, 0);
    acc[2] = __builtin_amdgcn_mfma_f32_16x16x32_bf16(aCh, bl2, acc[2], 0, 0, 0);
    acc[2] = __builtin_amdgcn_mfma_f32_16x16x32_bf16(aCl, bh2, acc[2], 0, 0, 0);
    acc[3] = __builtin_amdgcn_mfma_f32_16x16x32_bf16(aCh, bh3, acc[3], 0, 0, 0);
    acc[3] = __builtin_amdgcn_mfma_f32_16x16x32_bf16(aCh, bl3, acc[3], 0, 0, 0);
    acc[3] = __builtin_amdgcn_mfma_f32_16x16x32_bf16(aCl, bh3, acc[3], 0, 0, 0);
    if (ch < 30) {
      #pragma unroll
      for (int j = 0; j < 8; j++) {
        unsigned short hh = f2bf(wvN[j]);
        whiN[j] = (short)hh;
        wloN[j] = (short)f2bf(wvN[j] - bf2f(hh));
      }
    }
    if (ch < 29) {
      #pragma unroll
      for (int j = 0; j < 8; j++) wvN[j] = wvF[j];
    }
    if (ch < 31) { aCh = aNh; aCl = aNl; }
    asm volatile("s_waitcnt lgkmcnt(0)" ::: "memory");
    __builtin_amdgcn_s_barrier();
  }

  #pragma unroll
  for (int nf = 0; nf < 4; nf++) {
    int n = nloc + nf * 16 + lane16;
    float bv = bias[n];
    #pragma unroll
    for (int i = 0; i < 4; i++) {
      int m = mq * 64 + w * 16 + quad * 4 + i;
      float v = acc[nf][i] + bv;
      if (op == 1) v = tanhf(v);
      dst[(size_t)m * ldw + n] = v;
    }
  }
}

// ============ Newton-Schulz: fully compensated f16 MFMA =====================
// v3 structure (proven stable; do NOT re-derive fgh/fgl from registers —
// register-allocator cliff, see R6-R8). NS_STEPS 30->24: NS converges
// quadratically; 30 was converged with margin (absmax pinned at 0.0625 by
// the bf16 heads, not NS). Tripwire: if absmax changes at all, revert to 30.
__global__ __launch_bounds__(128) void ns_f16split_k(const float* __restrict__ q,
                                                     float* __restrict__ amat) {
  __align__(16) __shared__ _Float16 arena[12288];
  int tid = threadIdx.x;
  int wid = tid >> 6;
  int l = tid & 63;
  int lane16 = l & 15, quad = l >> 4;
  _Float16* Ah_cm = arena;          // [32][72]
  _Float16* Al_cm = arena + 2304;   // [32][72]
  _Float16* Mh_cm = arena + 4608;   // [32][40]
  _Float16* Ml_cm = arena + 5888;   // [32][40]
  _Float16* Ah_rm = arena + 7168;   // [64][40]
  _Float16* Al_rm = arena + 9728;   // [64][40]
  float* Afin = (float*)arena;      // [64][36]

  const float* g = q + (size_t)blockIdx.x * 2048;
  float* o = amat + (size_t)blockIdx.x * 2048;

  if (wid == 0) {
    float vals[32];
    float ss = 0.f;
    #pragma unroll
    for (int j = 0; j < 8; j++) {
      float4 v = *(const float4*)(g + l * 32 + j * 4);
      vals[4*j] = v.x; vals[4*j+1] = v.y; vals[4*j+2] = v.z; vals[4*j+3] = v.w;
      ss += v.x*v.x + v.y*v.y + v.z*v.z + v.w*v.w;
    }
    #pragma unroll
    for (int off = 32; off > 0; off >>= 1) ss += __shfl_xor(ss, off);
    float rn = rsqrtf(ss);
    #pragma unroll
    for (int i = 0; i < 32; i++) vals[i] *= rn;
    #pragma unroll
    for (int j = 0; j < 8; j++) {
      half4v ph, pl;
      #pragma unroll
      for (int rr = 0; rr < 4; rr++) {
        float v = vals[4*j + rr];
        _Float16 h = (_Float16)v;
        _Float16 lo = (_Float16)(v - (float)h);
        ph[rr] = h; pl[rr] = lo;
      }
      *(half4v*)(Ah_rm + l * 40 + j * 4) = ph;
      *(half4v*)(Al_rm + l * 40 + j * 4) = pl;
    }
    #pragma unroll
    for (int i = 0; i < 32; i++) {
      float v = vals[i];
      _Float16 h = (_Float16)v;
      Ah_cm[i * 72 + l] = h;
      Al_cm[i * 72 + l] = (_Float16)(v - (float)h);
    }
  }
  __syncthreads();

  const floatx4 zero4 = {0.f, 0.f, 0.f, 0.f};
  for (int s = 0; s < NS_STEPS; s++) {
    bool last = (s == NS_STEPS - 1);
    half8 fgh[2], fgl[2];
    #pragma unroll
    for (int c = 0; c < 2; c++) {
      fgh[c] = *(half8*)(Ah_cm + (wid * 16 + lane16) * 72 + c * 32 + quad * 8);
      fgl[c] = *(half8*)(Al_cm + (wid * 16 + lane16) * 72 + c * 32 + quad * 8);
    }
    half8 fah[2][2], fal[2][2];
    #pragma unroll
    for (int ti = 0; ti < 2; ti++)
      #pragma unroll
      for (int c = 0; c < 2; c++) {
        fah[ti][c] = *(half8*)(Ah_cm + (ti * 16 + lane16) * 72 + c * 32 + quad * 8);
        fal[ti][c] = *(half8*)(Al_cm + (ti * 16 + lane16) * 72 + c * 32 + quad * 8);
      }
    floatx4 gf[2] = {zero4, zero4};
    #pragma unroll
    for (int ti = 0; ti < 2; ti++)
      #pragma unroll
      for (int c = 0; c < 2; c++) {
        gf[ti] = __builtin_amdgcn_mfma_f32_16x16x32_f16(
            fah[ti][c], fgh[c], gf[ti], 0, 0, 0);
        gf[ti] = __builtin_amdgcn_mfma_f32_16x16x32_f16(
            fah[ti][c], fgl[c], gf[ti], 0, 0, 0);
        gf[ti] = __builtin_amdgcn_mfma_f32_16x16x32_f16(
            fal[ti][c], fgh[c], gf[ti], 0, 0, 0);
      }
    #pragma unroll
    for (int ti = 0; ti < 2; ti++) {
      int col = wid * 16 + lane16;
      int row0 = ti * 16 + quad * 4;
      half4v ph, pl;
      #pragma unroll
      for (int rr = 0; rr < 4; rr++) {
        float m = ((row0 + rr) == col ? 1.5f : 0.f) - 0.5f * gf[ti][rr];
        _Float16 h = (_Float16)m;
        ph[rr] = h; pl[rr] = (_Float16)(m - (float)h);
      }
      *(half4v*)(Mh_cm + col * 40 + row0) = ph;
      *(half4v*)(Ml_cm + col * 40 + row0) = pl;
    }
    __syncthreads();
    half8 fmh[2], fml[2], fbh[2], fbl[2];
    #pragma unroll
    for (int ti = 0; ti < 2; ti++) {
      fmh[ti] = *(half8*)(Mh_cm + (ti * 16 + lane16) * 40 + quad * 8);
      fml[ti] = *(half8*)(Ml_cm + (ti * 16 + lane16) * 40 + quad * 8);
    }
    #pragma unroll
    for (int jj = 0; jj < 2; jj++) {
      int tj = 2 * wid + jj;
      fbh[jj] = *(half8*)(Ah_rm + (tj * 16 + lane16) * 40 + quad * 8);
      fbl[jj] = *(half8*)(Al_rm + (tj * 16 + lane16) * 40 + quad * 8);
    }
    floatx4 df[2][2];
    #pragma unroll
    for (int ti = 0; ti < 2; ti++)
      #pragma unroll
      for (int jj = 0; jj < 2; jj++) {
        df[ti][jj] = __builtin_amdgcn_mfma_f32_16x16x32_f16(
            fmh[ti], fbh[jj], zero4, 0, 0, 0);
        df[ti][jj] = __builtin_amdgcn_mfma_f32_16x16x32_f16(
            fmh[ti], fbl[jj], df[ti][jj], 0, 0, 0);
        df[ti][jj] = __builtin_amdgcn_mfma_f32_16x16x32_f16(
            fml[ti], fbh[jj], df[ti][jj], 0, 0, 0);
      }
    __syncthreads();   // WAR: all reads of Ah_rm/M done before overwrite
    if (!last) {
      #pragma unroll
      for (int ti = 0; ti < 2; ti++)
        #pragma unroll
        for (int jj = 0; jj < 2; jj++) {
          int tj = 2 * wid + jj;
          int z = tj * 16 + lane16;
          int d0 = ti * 16 + quad * 4;
          half4v ph, pl;
          #pragma unroll
          for (int rr = 0; rr < 4; rr++) {
            float v = df[ti][jj][rr];
            _Float16 h = (_Float16)v;
            ph[rr] = h; pl[rr] = (_Float16)(v - (float)h);
          }
          *(half4v*)(Ah_rm + z * 40 + d0) = ph;
          *(half4v*)(Al_rm + z * 40 + d0) = pl;
          #pragma unroll
          for (int rr = 0; rr < 4; rr++) {
            Ah_cm[(d0 + rr) * 72 + z] = ph[rr];
            Al_cm[(d0 + rr) * 72 + z] = pl[rr];
          }
        }
    } else {
      #pragma unroll
      for (int ti = 0; ti < 2; ti++)
        #pragma unroll
        for (int jj = 0; jj < 2; jj++) {
          int tj = 2 * wid + jj;
          int z = tj * 16 + lane16;
          int d0 = ti * 16 + quad * 4;
          float4 v;
          v.x = df[ti][jj][0]; v.y = df[ti][jj][1];
          v.z = df[ti][jj][2]; v.w = df[ti][jj][3];
          *(float4*)(Afin + z * 36 + d0) = v;
        }
    }
    __syncthreads();
  }
  #pragma unroll
  for (int j = 0; j < 4; j++) {
    int f = j * 512 + tid * 4;
    int z = f >> 5, d = f & 31;
    float4 v = *(const float4*)(Afin + z * 36 + d);
    *(float4*)(o + f) = v;
  }
}

// ======================= Sylvester flow (K=4 steps) =======================
__global__ __launch_bounds__(64) void flow_k(const float* __restrict__ amat,
    const float* __restrict__ fd, const float* __restrict__ dg1,
    const float* __restrict__ dg2, const float* __restrict__ ab,
    const float* __restrict__ eps, float* __restrict__ dout) {
  __shared__ float Ps[32][64];
  __shared__ float wsh[32], tsh[32], ush[32];
  int b = blockIdx.x, l = threadIdx.x;
  float mv  = dout[26624 + b * 64 + l];
  float lvv = dout[43008 + b * 64 + l];
  float z0 = mv + eps[b * 64 + l] * expf(0.5f * lvv);
  dout[59648 + b * 64 + l] = z0;
  float zv = z0;
  float ldj = 0.f;
  float q[32];
  for (int k = 0; k < 4; k++) {
    const float4* qrow = (const float4*)(amat + (size_t)(b * 4 + k) * 2048 + l * 32);
    #pragma unroll
    for (int j = 0; j < 8; j++) {
      float4 v = qrow[j];
      q[4*j] = v.x; q[4*j+1] = v.y; q[4*j+2] = v.z; q[4*j+3] = v.w;
    }
    #pragma unroll
    for (int d = 0; d < 32; d++) Ps[d][l] = zv * q[d];
    __syncthreads();
    if (l < 32) {
      const float4* pr = (const float4*)Ps[l];
      float s = 0.f;
      #pragma unroll
      for (int j = 0; j < 16; j++) {
        float4 v = pr[j];
        s += v.x + v.y + v.z + v.w;
      }
      wsh[l] = s;
    }
    __syncthreads();
    if (l < 32) {
      int e = l;
      float acc = ab[b * 128 + e * 4 + k] + wsh[e] * dg2[b * 128 + e * 4 + k];
      for (int d = e + 1; d < 32; d++)
        acc += wsh[d] * fd[b * 4096 + d * 128 + e * 4 + k];
      float tt = tanhf(acc);
      tsh[e] = tt;
      float dd = (1.f - tt * tt) * (dg1[b*128 + e*4 + k] * dg2[b*128 + e*4 + k]) + 1.f;
      ldj += logf(fabsf(dd));
    }
    __syncthreads();
    if (l < 32) {
      int d = l;
      float acc = tsh[d] * dg1[b * 128 + d * 4 + k];
      for (int e = d + 1; e < 32; e++)
        acc += fd[b * 4096 + d * 128 + e * 4 + k] * tsh[e];
      ush[d] = acc;
    }
    __syncthreads();
    #pragma unroll
    for (int d = 0; d < 32; d++) zv += q[d] * ush[d];
    __syncthreads();
  }
  dout[76032 + b * 64 + l] = zv;
  for (int off = 16; off > 0; off >>= 1) ldj += __shfl_down(ldj, off, 32);
  if (l == 0) dout[59392 + b] = ldj;
}

// ======================= host launch =======================
extern "C" void kernel_launch(void* const* d_in, const int* in_sizes, int n_in,
                              void* d_out, int out_size, void* d_ws, size_t ws_size,
                              hipStream_t stream) {
  (void)in_sizes; (void)n_in; (void)out_size; (void)ws_size;
  const float* x     = (const float*)d_in[0];
  const float* eps   = (const float*)d_in[1];
  const float* cw1   = (const float*)d_in[2];
  const float* cb1   = (const float*)d_in[3];
  const float* g1    = (const float*)d_in[4];
  const float* be1   = (const float*)d_in[5];
  const float* cw2   = (const float*)d_in[6];
  const float* cb2   = (const float*)d_in[7];
  const float* g2    = (const float*)d_in[8];
  const float* be2   = (const float*)d_in[9];
  const float* cw3   = (const float*)d_in[10];
  const float* cb3   = (const float*)d_in[11];
  const float* g3    = (const float*)d_in[12];
  const float* be3   = (const float*)d_in[13];
  const float* d1_w  = (const float*)d_in[14];
  const float* d1_b  = (const float*)d_in[15];
  const float* bn1_g = (const float*)d_in[16];
  const float* bn1_b = (const float*)d_in[17];
  const float* mu_w  = (const float*)d_in[18];
  const float* mu_b  = (const float*)d_in[19];
  const float* lv_w  = (const float*)d_in[20];
  const float* lv_b  = (const float*)d_in[21];
  const float* ad_w  = (const float*)d_in[22];
  const float* ad_b  = (const float*)d_in[23];
  const float* adg1_w= (const float*)d_in[24];
  const float* adg1_b= (const float*)d_in[25];
  const float* adg2_w= (const float*)d_in[26];
  const float* adg2_b= (const float*)d_in[27];
  const float* aq_w  = (const float*)d_in[28];
  const float* aq_b  = (const float*)d_in[29];
  const float* ab_w  = (const float*)d_in[30];
  const float* ab_b  = (const float*)d_in[31];
  const float* d3_w  = (const float*)d_in[32];
  const float* d3_b  = (const float*)d_in[33];
  const float* bn3_g = (const float*)d_in[34];
  const float* bn3_b = (const float*)d_in[35];
  const float* d4_w  = (const float*)d_in[36];
  const float* d4_b  = (const float*)d_in[37];
  const float* bn4_g = (const float*)d_in[38];
  const float* bn4_b = (const float*)d_in[39];
  const float* tw1   = (const float*)d_in[40];
  const float* tb1   = (const float*)d_in[41];
  const float* tg1   = (const float*)d_in[42];
  const float* tbe1  = (const float*)d_in[43];
  const float* tw2   = (const float*)d_in[44];
  const float* tb2   = (const float*)d_in[45];
  const float* tg2   = (const float*)d_in[46];
  const float* tbe2  = (const float*)d_in[47];
  const float* tw3   = (const float*)d_in[48];
  const float* tb3   = (const float*)d_in[49];

  float* out = (float*)d_out;
  float* wsf = (float*)d_ws;
  float* h1   = wsf;                 // 196608  (later: abuf, t2)
  float* h2   = wsf + 196608;        // 81920   (later: abuf tail, t1)
  float* h3   = wsf + 278528;        // 28672   (later: dec2)
  float* out1 = wsf + 307200;        // 262144  (later: dec1)
  float* fd   = wsf + 569344;        // 1048576
  float* dg1  = wsf + 1617920;       // 32768
  float* dg2  = wsf + 1650688;       // 32768
  float* qb   = wsf + 1683456;       // 2097152
  float* ab   = wsf + 3780608;       // 32768
  float* amat = wsf + 3813376;       // 2097152
  float* dec1 = out1;
  float* dec2 = h3;
  float* t1   = h2;
  float* t2   = h1;

  // A-fragment buffer: 524288 shorts = 262144 floats, reuses dead h1+h2
  short* ahi = (short*)wsf;
  short* alo = ahi + 262144;

  float* mean_o = out + 26624;
  float* lv_o   = out + 43008;
  float* z_o    = out + 76032;

  // ---------------- encoder ----------------
  conv1_k<<<768, 256, 0, stream>>>(x, cw1, cb1, h1);
  bn2d_k<<<32, 256, 0, stream>>>(h1, g1, be1, 32, 24);
  conv2_k<<<320, 256, 0, stream>>>(h1, cw2, cb2, h2);
  bn2d_k<<<16, 256, 0, stream>>>(h2, g2, be2, 16, 20);
  conv3_k<<<112, 256, 0, stream>>>(h2, cw3, cb3, h3);
  bn2d_k<<<8, 256, 0, stream>>>(h3, g3, be3, 8, 14);

  gemm_os_k<<<dim3(16, 4), 256, 0, stream>>>(h3, d1_w, d1_b, out1, 112, 1024);
  bn1d_k<<<32, 256, 0, stream>>>(out1, bn1_g, bn1_b, 1024);

  // ---------------- fused heads (MFMA) ----------------
  prep_a_k<<<128, 256, 0, stream>>>(out1, ahi, alo);

  HeadArgs ha;
  ha.W[0] = mu_w;   ha.b[0] = mu_b;   ha.dst[0] = mean_o; ha.ldw[0] = 64;   ha.op[0] = 0;
  ha.W[1] = lv_w;   ha.b[1] = lv_b;   ha.dst[1] = lv_o;   ha.ldw[1] = 64;   ha.op[1] = 0;
  ha.W[2] = ad_w;   ha.b[2] = ad_b;   ha.dst[2] = fd;     ha.ldw[2] = 4096; ha.op[2] = 0;
  ha.W[3] = adg1_w; ha.b[3] = adg1_b; ha.dst[3] = dg1;    ha.ldw[3] = 128;  ha.op[3] = 1;
  ha.W[4] = adg2_w; ha.b[4] = adg2_b; ha.dst[4] = dg2;    ha.ldw[4] = 128;  ha.op[4] = 1;
  ha.W[5] = aq_w;   ha.b[5] = aq_b;   ha.dst[5] = qb;     ha.ldw[5] = 8192; ha.op[5] = 0;
  ha.W[6] = ab_w;   ha.b[6] = ab_b;   ha.dst[6] = ab;     ha.ldw[6] = 128;  ha.op[6] = 0;
  ha.off[0] = 0;    ha.off[1] = 64;   ha.off[2] = 128;  ha.off[3] = 4224;
  ha.off[4] = 4352; ha.off[5] = 4480; ha.off[6] = 12672; ha.off[7] = 12800;
  heads_mfma_k<<<dim3(200, 4), 256, 0, stream>>>(ahi, alo, ha);

  // ---------------- orthogonalization + flow ----------------
  ns_f16split_k<<<1024, 128, 0, stream>>>(qb, amat);
  flow_k<<<256, 64, 0, stream>>>(amat, fd, dg1, dg2, ab, eps, out);

  // ---------------- decoder ----------------
  gemm_os_k<<<dim3(16, 4), 256, 0, stream>>>(z_o, d3_w, d3_b, dec1, 64, 1024);
  bn1d_k<<<32, 256, 0, stream>>>(dec1, bn3_g, bn3_b, 1024);
  hipMemsetAsync(dec2, 0, 28672 * sizeof(float), stream);
  gemm_ks_k<<<dim3(2, 4, 16), 256, 0, stream>>>(dec1, d4_w, d4_b, dec2);
  bn1d_k<<<4, 256, 0, stream>>>(dec2, bn4_g, bn4_b, 112);

  tconv1_k<<<320, 256, 0, stream>>>(dec2, tw1, tb1, t1);
  bn2d_k<<<16, 256, 0, stream>>>(t1, tg1, tbe1, 16, 20);
  tconv2_k<<<768, 256, 0, stream>>>(t1, tw2, tb2, t2);
  bn2d_k<<<32, 256, 0, stream>>>(t2, tg2, tbe2, 32, 24);
  tconv3_k<<<104, 256, 0, stream>>>(t2, tw3, tb3, out);
}

// Round 12
// 488.851 us; speedup vs baseline: 1.1485x; 1.0275x over previous
//
#include <hip/hip_runtime.h>
#include <math.h>

#define NS_STEPS 16

typedef __attribute__((ext_vector_type(8))) _Float16 half8;
typedef __attribute__((ext_vector_type(4))) _Float16 half4v;
typedef __attribute__((ext_vector_type(8))) short short8;
typedef __attribute__((ext_vector_type(4))) float floatx4;

static __device__ inline unsigned short f2bf(float f) {
  union { float f; unsigned u; } v; v.f = f;
  unsigned r = v.u + 0x7fffu + ((v.u >> 16) & 1u);
  return (unsigned short)(r >> 16);
}
static __device__ inline float bf2f(unsigned short h) {
  union { unsigned u; float f; } v; v.u = ((unsigned)h) << 16;
  return v.f;
}

// ======================= encoder convs =======================
__global__ __launch_bounds__(256) void conv1_k(const float* __restrict__ x,
    const float* __restrict__ w, const float* __restrict__ bias,
    float* __restrict__ out) {
  __shared__ float ws[384];
  int tid = threadIdx.x;
  for (int i = tid; i < 384; i += 256) ws[i] = w[i];
  __syncthreads();
  int idx = blockIdx.x * 256 + tid;
  if (idx >= 196608) return;
  int b = idx / 768, r = idx % 768;
  int c = r / 24, h = r % 24;
  const float* xb = x + b * 104 + h * 4;
  const float* wc = ws + c * 12;
  float acc = bias[c];
  #pragma unroll
  for (int kh = 0; kh < 3; kh++) {
    #pragma unroll
    for (int kw = 0; kw < 4; kw++)
      acc += xb[kh * 4 + kw] * wc[kh * 4 + kw];
  }
  out[idx] = acc;
}

__global__ __launch_bounds__(256) void conv2_k(const float* __restrict__ in,
    const float* __restrict__ w, const float* __restrict__ bias,
    float* __restrict__ out) {
  __shared__ float ws[2560];
  int tid = threadIdx.x;
  for (int i = tid; i < 2560; i += 256) ws[i] = w[i];
  __syncthreads();
  int idx = blockIdx.x * 256 + tid;
  if (idx >= 81920) return;
  int b = idx / 320, r = idx % 320;
  int c = r / 20, h = r % 20;
  const float* ib = in + b * 768 + h;
  const float* wc = ws + c * 160;
  float acc = bias[c];
  for (int i = 0; i < 32; i++) {
    #pragma unroll
    for (int kh = 0; kh < 5; kh++)
      acc += ib[i * 24 + kh] * wc[i * 5 + kh];
  }
  out[idx] = acc;
}

__global__ __launch_bounds__(256) void conv3_k(const float* __restrict__ in,
    const float* __restrict__ w, const float* __restrict__ bias,
    float* __restrict__ out) {
  __shared__ float ws[896];
  int tid = threadIdx.x;
  for (int i = tid; i < 896; i += 256) ws[i] = w[i];
  __syncthreads();
  int idx = blockIdx.x * 256 + tid;
  if (idx >= 28672) return;
  int b = idx / 112, r = idx % 112;
  int c = r / 14, h = r % 14;
  const float* ib = in + b * 320 + h;
  const float* wc = ws + c * 112;
  float acc = bias[c];
  for (int i = 0; i < 16; i++) {
    #pragma unroll
    for (int kh = 0; kh < 7; kh++)
      acc += ib[i * 20 + kh] * wc[i * 7 + kh];
  }
  out[idx] = acc;
}

// ======================= decoder tconvs =======================
__global__ __launch_bounds__(256) void tconv1_k(const float* __restrict__ in,
    const float* __restrict__ w, const float* __restrict__ bias,
    float* __restrict__ out) {
  __shared__ float ws[896];
  int tid = threadIdx.x;
  for (int i = tid; i < 896; i += 256) ws[i] = w[i];
  __syncthreads();
  int idx = blockIdx.x * 256 + tid;
  if (idx >= 81920) return;
  int b = idx / 320, r = idx % 320;
  int c = r / 20, s = r % 20;
  float acc = bias[c];
  for (int o = 0; o < 8; o++) {
    #pragma unroll
    for (int kh = 0; kh < 7; kh++) {
      int hs = s - kh;
      if (hs >= 0 && hs < 14)
        acc += in[b * 112 + o * 14 + hs] * ws[o * 112 + c * 7 + kh];
    }
  }
  out[idx] = acc;
}

__global__ __launch_bounds__(256) void tconv2_k(const float* __restrict__ in,
    const float* __restrict__ w, const float* __restrict__ bias,
    float* __restrict__ out) {
  __shared__ float ws[2560];
  int tid = threadIdx.x;
  for (int i = tid; i < 2560; i += 256) ws[i] = w[i];
  __syncthreads();
  int idx = blockIdx.x * 256 + tid;
  if (idx >= 196608) return;
  int b = idx / 768, r = idx % 768;
  int c = r / 24, s = r % 24;
  float acc = bias[c];
  for (int o = 0; o < 16; o++) {
    #pragma unroll
    for (int kh = 0; kh < 5; kh++) {
      int hs = s - kh;
      if (hs >= 0 && hs < 20)
        acc += in[b * 320 + o * 20 + hs] * ws[o * 160 + c * 5 + kh];
    }
  }
  out[idx] = acc;
}

__global__ __launch_bounds__(256) void tconv3_k(const float* __restrict__ in,
    const float* __restrict__ w, const float* __restrict__ bias,
    float* __restrict__ out) {
  __shared__ float ws[384];
  int tid = threadIdx.x;
  for (int i = tid; i < 384; i += 256) ws[i] = w[i];
  __syncthreads();
  int idx = blockIdx.x * 256 + tid;
  if (idx >= 26624) return;
  int b = idx / 104, r = idx % 104;
  int sh = r / 4, sw = r % 4;
  float acc = bias[0];
  for (int o = 0; o < 32; o++) {
    #pragma unroll
    for (int kh = 0; kh < 3; kh++) {
      int hs = sh - kh;
      if (hs >= 0 && hs < 24)
        acc += in[b * 768 + o * 24 + hs] * ws[o * 12 + kh * 4 + sw];
    }
  }
  out[idx] = acc;
}

// ======================= batchnorm =======================
__global__ __launch_bounds__(256) void bn2d_k(float* __restrict__ x,
    const float* __restrict__ g, const float* __restrict__ be,
    int C, int HW) {
  __shared__ float rs[256], rs2[256];
  int c = blockIdx.x, tid = threadIdx.x;
  int total = 256 * HW;
  float s = 0.f, s2 = 0.f;
  for (int i = tid; i < total; i += 256) {
    int b = i / HW, j = i - b * HW;
    float v = x[(b * C + c) * HW + j];
    s += v; s2 += v * v;
  }
  rs[tid] = s; rs2[tid] = s2;
  __syncthreads();
  for (int off = 128; off > 0; off >>= 1) {
    if (tid < off) { rs[tid] += rs[tid + off]; rs2[tid] += rs2[tid + off]; }
    __syncthreads();
  }
  float m = rs[0] / (float)total;
  float var = rs2[0] / (float)total - m * m;
  float rstd = rsqrtf(var + 1e-5f) * g[c];
  float bb = be[c];
  for (int i = tid; i < total; i += 256) {
    int b = i / HW, j = i - b * HW;
    size_t idx = (size_t)(b * C + c) * HW + j;
    float v = (x[idx] - m) * rstd + bb;
    x[idx] = v > 0.f ? v : 0.f;
  }
}

__global__ __launch_bounds__(256) void bn1d_k(float* __restrict__ x,
    const float* __restrict__ g, const float* __restrict__ be, int N) {
  __shared__ float p1[8][32], p2[8][32];
  int t = threadIdx.x;
  int cl = t & 31, rg = t >> 5;
  int c = blockIdx.x * 32 + cl;
  float s = 0.f, s2 = 0.f;
  if (c < N) {
    for (int r = rg * 32; r < rg * 32 + 32; r++) {
      float v = x[r * N + c];
      s += v; s2 += v * v;
    }
  }
  p1[rg][cl] = s; p2[rg][cl] = s2;
  __syncthreads();
  float ts = 0.f, ts2 = 0.f;
  #pragma unroll
  for (int i = 0; i < 8; i++) { ts += p1[i][cl]; ts2 += p2[i][cl]; }
  float m = ts * (1.f / 256.f);
  float var = ts2 * (1.f / 256.f) - m * m;
  float rstd = rsqrtf(var + 1e-5f) * ((c < N) ? g[c] : 1.f);
  float bb = (c < N) ? be[c] : 0.f;
  if (c < N) {
    for (int r = rg * 32; r < rg * 32 + 32; r++) {
      float v = (x[r * N + c] - m) * rstd + bb;
      x[r * N + c] = v > 0.f ? v : 0.f;
    }
  }
}

// ============== one-shot fp32 GEMM (K<=112, N multiple of 64) ===============
__global__ __launch_bounds__(256) void gemm_os_k(const float* __restrict__ A,
    const float* __restrict__ W, const float* __restrict__ bias,
    float* __restrict__ C, int K, int N) {
  __shared__ float As[112 * 68];
  __shared__ float Bs[112 * 68];
  int tid = threadIdx.x;
  int nb = blockIdx.x, mb = blockIdx.y;
  int K16 = K >> 4;
  {
    int row = tid >> 2;
    const float* Ar = A + (size_t)(mb * 64 + row) * K;
    for (int i = 0; i < K16; i++) {
      int j = (tid & 3) + 4 * i;
      float4 v = *(const float4*)(Ar + j * 4);
      int k = j * 4;
      As[k * 68 + row] = v.x;
      As[(k + 1) * 68 + row] = v.y;
      As[(k + 2) * 68 + row] = v.z;
      As[(k + 3) * 68 + row] = v.w;
    }
  }
  {
    int n4 = (tid & 15) * 4;
    for (int i = 0; i < K16; i++) {
      int k = (tid >> 4) + 16 * i;
      float4 v = *(const float4*)(W + (size_t)k * N + nb * 64 + n4);
      *(float4*)(Bs + k * 68 + n4) = v;
    }
  }
  __syncthreads();
  int tm = tid >> 4, tn = tid & 15;
  int m0 = tm * 4, n0 = tn * 4;
  float acc[4][4] = {{0.f}};
  #pragma unroll 8
  for (int kk = 0; kk < K; kk++) {
    float4 a = *(const float4*)(As + kk * 68 + m0);
    float4 b = *(const float4*)(Bs + kk * 68 + n0);
    acc[0][0] += a.x*b.x; acc[0][1] += a.x*b.y; acc[0][2] += a.x*b.z; acc[0][3] += a.x*b.w;
    acc[1][0] += a.y*b.x; acc[1][1] += a.y*b.y; acc[1][2] += a.y*b.z; acc[1][3] += a.y*b.w;
    acc[2][0] += a.z*b.x; acc[2][1] += a.z*b.y; acc[2][2] += a.z*b.z; acc[2][3] += a.z*b.w;
    acc[3][0] += a.w*b.x; acc[3][1] += a.w*b.y; acc[3][2] += a.w*b.z; acc[3][3] += a.w*b.w;
  }
  #pragma unroll
  for (int i = 0; i < 4; i++) {
    int m = mb * 64 + m0 + i;
    #pragma unroll
    for (int j = 0; j < 4; j++) {
      int n = nb * 64 + n0 + j;
      C[(size_t)m * N + n] = acc[i][j] + bias[n];
    }
  }
}

// ============== K-split fp32 GEMM for d4: C(256,112) += A@W chunk ===========
__global__ __launch_bounds__(256) void gemm_ks_k(const float* __restrict__ A,
    const float* __restrict__ W, const float* __restrict__ bias,
    float* __restrict__ C) {
  __shared__ float As[64 * 68];
  __shared__ float Bs[64 * 68];
  int tid = threadIdx.x;
  int nb = blockIdx.x, mb = blockIdx.y, kc = blockIdx.z;
  int k0 = kc * 64;
  {
    int row = tid >> 2;
    const float* Ar = A + (size_t)(mb * 64 + row) * 1024 + k0;
    #pragma unroll
    for (int i = 0; i < 4; i++) {
      int j = (tid & 3) + 4 * i;
      float4 v = *(const float4*)(Ar + j * 4);
      int k = j * 4;
      As[k * 68 + row] = v.x;
      As[(k + 1) * 68 + row] = v.y;
      As[(k + 2) * 68 + row] = v.z;
      As[(k + 3) * 68 + row] = v.w;
    }
  }
  {
    int n4 = (tid & 15) * 4;
    int nbase = nb * 64 + n4;
    #pragma unroll
    for (int i = 0; i < 4; i++) {
      int k = (tid >> 4) + 16 * i;
      const float* Wr = W + (size_t)(k0 + k) * 112;
      float4 v;
      v.x = (nbase     < 112) ? Wr[nbase]     : 0.f;
      v.y = (nbase + 1 < 112) ? Wr[nbase + 1] : 0.f;
      v.z = (nbase + 2 < 112) ? Wr[nbase + 2] : 0.f;
      v.w = (nbase + 3 < 112) ? Wr[nbase + 3] : 0.f;
      *(float4*)(Bs + k * 68 + n4) = v;
    }
  }
  __syncthreads();
  int tm = tid >> 4, tn = tid & 15;
  int m0 = tm * 4, n0 = tn * 4;
  float acc[4][4] = {{0.f}};
  #pragma unroll 8
  for (int kk = 0; kk < 64; kk++) {
    float4 a = *(const float4*)(As + kk * 68 + m0);
    float4 b = *(const float4*)(Bs + kk * 68 + n0);
    acc[0][0] += a.x*b.x; acc[0][1] += a.x*b.y; acc[0][2] += a.x*b.z; acc[0][3] += a.x*b.w;
    acc[1][0] += a.y*b.x; acc[1][1] += a.y*b.y; acc[1][2] += a.y*b.z; acc[1][3] += a.y*b.w;
    acc[2][0] += a.z*b.x; acc[2][1] += a.z*b.y; acc[2][2] += a.z*b.z; acc[2][3] += a.z*b.w;
    acc[3][0] += a.w*b.x; acc[3][1] += a.w*b.y; acc[3][2] += a.w*b.z; acc[3][3] += a.w*b.w;
  }
  #pragma unroll
  for (int i = 0; i < 4; i++) {
    int m = mb * 64 + m0 + i;
    #pragma unroll
    for (int j = 0; j < 4; j++) {
      int n = nb * 64 + n0 + j;
      if (n < 112) {
        float v = acc[i][j] + (kc == 0 ? bias[n] : 0.f);
        atomicAdd(&C[m * 112 + n], v);
      }
    }
  }
}

// ======= A-fragment precompute: out1 f32 -> bf16 hi/lo, MFMA-frag layout =====
__global__ __launch_bounds__(256) void prep_a_k(const float* __restrict__ A,
    short* __restrict__ ahi, short* __restrict__ alo) {
  int gi = blockIdx.x * 256 + threadIdx.x;   // 0..32767
  int lane = gi & 63;
  int t = gi >> 6;
  int mt = t & 3; t >>= 2;
  int c = t & 31; int mb = t >> 5;
  int row = mb * 64 + mt * 16 + (lane & 15);
  int k0 = c * 32 + (lane >> 4) * 8;
  const float* src = A + (size_t)row * 1024 + k0;
  float4 v0 = *(const float4*)(src);
  float4 v1 = *(const float4*)(src + 4);
  float av[8] = {v0.x, v0.y, v0.z, v0.w, v1.x, v1.y, v1.z, v1.w};
  short8 h, lo;
  #pragma unroll
  for (int i = 0; i < 8; i++) {
    unsigned short hh = f2bf(av[i]);
    h[i] = (short)hh;
    lo[i] = (short)f2bf(av[i] - bf2f(hh));
  }
  *(short8*)(ahi + (size_t)gi * 8) = h;
  *(short8*)(alo + (size_t)gi * 8) = lo;
}

// ================= fused head GEMMs, compensated-bf16 MFMA ==================
// v6 (unchanged): grid (200,4), W dbuf in LDS, lgkmcnt-only barrier.
struct HeadArgs {
  const float* W[7];
  const float* b[7];
  float* dst[7];
  int off[8];
  int ldw[7];
  int op[7];
};

__global__ __launch_bounds__(256) void heads_mfma_k(const short* __restrict__ ahi,
                                                    const short* __restrict__ alo,
                                                    HeadArgs ha) {
  __shared__ __align__(16) short Wsh[2][2][2048];  // [buf][hi/lo][64col x 32k frag]
  int tid = threadIdx.x;
  int nb = blockIdx.x;          // 64-col tile, 0..199
  int mq = blockIdx.y;          // 64-row quarter, 0..3
  int gc = nb * 64;
  int r = 0;
  while (gc >= ha.off[r + 1]) r++;
  const float* Wp = ha.W[r];
  const float* bias = ha.b[r];
  float* dst = ha.dst[r];
  int ldw = ha.ldw[r];
  int op = ha.op[r];
  int nloc = gc - ha.off[r];

  int w = tid >> 6, l = tid & 63;
  int lane16 = l & 15, quad = l >> 4;

  int c64 = tid & 63, q4 = tid >> 6;
  const float* wcol = Wp + (size_t)(q4 * 8) * ldw + nloc + c64;
  int wg = ((c64 >> 4) * 64 + q4 * 16 + (c64 & 15)) * 8;  // shorts

  const short* agh = ahi + (size_t)mq * 65536 + w * 512 + l * 8;
  const short* agl = alo + (size_t)mq * 65536 + w * 512 + l * 8;

  const floatx4 zero4 = {0.f, 0.f, 0.f, 0.f};
  floatx4 acc[4] = {zero4, zero4, zero4, zero4};

  float wvN[8], wvF[8];
  short8 whiN, wloN;
  short8 aCh, aCl, aNh, aNl;

  {
    float wv0[8];
    #pragma unroll
    for (int j = 0; j < 8; j++) wv0[j] = wcol[(size_t)j * ldw];
    #pragma unroll
    for (int j = 0; j < 8; j++) wvN[j] = wcol[(size_t)(32 + j) * ldw];
    aCh = *(const short8*)(agh);
    aCl = *(const short8*)(agl);
    #pragma unroll
    for (int j = 0; j < 8; j++) wvF[j] = wcol[(size_t)(64 + j) * ldw];
    short8 t0h, t0l;
    #pragma unroll
    for (int j = 0; j < 8; j++) {
      unsigned short hh = f2bf(wv0[j]);
      t0h[j] = (short)hh;
      t0l[j] = (short)f2bf(wv0[j] - bf2f(hh));
    }
    *(short8*)(&Wsh[0][0][wg]) = t0h;
    *(short8*)(&Wsh[0][1][wg]) = t0l;
    #pragma unroll
    for (int j = 0; j < 8; j++) {
      unsigned short hh = f2bf(wvN[j]);
      whiN[j] = (short)hh;
      wloN[j] = (short)f2bf(wvN[j] - bf2f(hh));
    }
    #pragma unroll
    for (int j = 0; j < 8; j++) wvN[j] = wvF[j];
    asm volatile("s_waitcnt lgkmcnt(0)" ::: "memory");
    __builtin_amdgcn_s_barrier();
  }

  for (int ch = 0; ch < 32; ++ch) {
    int p = ch & 1;
    if (ch < 31) {
      *(short8*)(&Wsh[p ^ 1][0][wg]) = whiN;
      *(short8*)(&Wsh[p ^ 1][1][wg]) = wloN;
    }
    if (ch < 29) {
      #pragma unroll
      for (int j = 0; j < 8; j++)
        wvF[j] = wcol[(size_t)((ch + 3) * 32 + j) * ldw];
    }
    if (ch < 31) {
      aNh = *(const short8*)(agh + (size_t)(ch + 1) * 2048);
      aNl = *(const short8*)(agl + (size_t)(ch + 1) * 2048);
    }
    short8 bh0 = *(const short8*)(&Wsh[p][0][(0 * 64 + l) * 8]);
    short8 bl0 = *(const short8*)(&Wsh[p][1][(0 * 64 + l) * 8]);
    short8 bh1 = *(const short8*)(&Wsh[p][0][(1 * 64 + l) * 8]);
    short8 bl1 = *(const short8*)(&Wsh[p][1][(1 * 64 + l) * 8]);
    short8 bh2 = *(const short8*)(&Wsh[p][0][(2 * 64 + l) * 8]);
    short8 bl2 = *(const short8*)(&Wsh[p][1][(2 * 64 + l) * 8]);
    short8 bh3 = *(const short8*)(&Wsh[p][0][(3 * 64 + l) * 8]);
    short8 bl3 = *(const short8*)(&Wsh[p][1][(3 * 64 + l) * 8]);
    acc[0] = __builtin_amdgcn_mfma_f32_16x16x32_bf16(aCh, bh0, acc[0], 0, 0, 0);
    acc[0] = __builtin_amdgcn_mfma_f32_16x16x32_bf16(aCh, bl0, acc[0], 0, 0, 0);
    acc[0] = __builtin_amdgcn_mfma_f32_16x16x32_bf16(aCl, bh0, acc[0], 0, 0, 0);
    acc[1] = __builtin_amdgcn_mfma_f32_16x16x32_bf16(aCh, bh1, acc[1], 0, 0, 0);
    acc[1] = __builtin_amdgcn_mfma_f32_16x16x32_bf16(aCh, bl1, acc[1], 0, 0, 0);
    acc[1] = __builtin_amdgcn_mfma_f32_16x16x32_bf16(aCl, bh1, acc[1], 0, 0, 0);
    acc[2] = __builtin_amdgcn_mfma_f32_16x16x32_bf16(aCh, bh2, acc[2], 0, 0, 0);
    acc[2] = __builtin_amdgcn_mfma_f32_16x16x32_bf16(aCh, bl2, acc[2], 0, 0, 0);
    acc[2] = __builtin_amdgcn_mfma_f32_16x16x32_bf16(aCl, bh2, acc[2], 0, 0, 0);
    acc[3] = __builtin_amdgcn_mfma_f32_16x16x32_bf16(aCh, bh3, acc[3], 0, 0, 0);
    acc[3] = __builtin_amdgcn_mfma_f32_16x16x32_bf16(aCh, bl3, acc[3], 0, 0, 0);
    acc[3] = __builtin_amdgcn_mfma_f32_16x16x32_bf16(aCl, bh3, acc[3], 0, 0, 0);
    if (ch < 30) {
      #pragma unroll
      for (int j = 0; j < 8; j++) {
        unsigned short hh = f2bf(wvN[j]);
        whiN[j] = (short)hh;
        wloN[j] = (short)f2bf(wvN[j] - bf2f(hh));
      }
    }
    if (ch < 29) {
      #pragma unroll
      for (int j = 0; j < 8; j++) wvN[j] = wvF[j];
    }
    if (ch < 31) { aCh = aNh; aCl = aNl; }
    asm volatile("s_waitcnt lgkmcnt(0)" ::: "memory");
    __builtin_amdgcn_s_barrier();
  }

  #pragma unroll
  for (int nf = 0; nf < 4; nf++) {
    int n = nloc + nf * 16 + lane16;
    float bv = bias[n];
    #pragma unroll
    for (int i = 0; i < 4; i++) {
      int m = mq * 64 + w * 16 + quad * 4 + i;
      float v = acc[nf][i] + bv;
      if (op == 1) v = tanhf(v);
      dst[(size_t)m * ldw + n] = v;
    }
  }
}

// ============ Newton-Schulz: fully compensated f16 MFMA =====================
// v3 structure (proven stable; do NOT re-derive fgh/fgl from registers —
// register-allocator cliff, see R6-R8). NS_STEPS 24->16: MP-law estimate
// sigma_min ~0.043 -> ~11 steps to f16 convergence; 16 leaves ~5 steps
// margin; 24/30 both gave absmax exactly 0.0625 (pinned by bf16 heads).
// Tripwire: if absmax changes at all, revert to 20.
__global__ __launch_bounds__(128) void ns_f16split_k(const float* __restrict__ q,
                                                     float* __restrict__ amat) {
  __align__(16) __shared__ _Float16 arena[12288];
  int tid = threadIdx.x;
  int wid = tid >> 6;
  int l = tid & 63;
  int lane16 = l & 15, quad = l >> 4;
  _Float16* Ah_cm = arena;          // [32][72]
  _Float16* Al_cm = arena + 2304;   // [32][72]
  _Float16* Mh_cm = arena + 4608;   // [32][40]
  _Float16* Ml_cm = arena + 5888;   // [32][40]
  _Float16* Ah_rm = arena + 7168;   // [64][40]
  _Float16* Al_rm = arena + 9728;   // [64][40]
  float* Afin = (float*)arena;      // [64][36]

  const float* g = q + (size_t)blockIdx.x * 2048;
  float* o = amat + (size_t)blockIdx.x * 2048;

  if (wid == 0) {
    float vals[32];
    float ss = 0.f;
    #pragma unroll
    for (int j = 0; j < 8; j++) {
      float4 v = *(const float4*)(g + l * 32 + j * 4);
      vals[4*j] = v.x; vals[4*j+1] = v.y; vals[4*j+2] = v.z; vals[4*j+3] = v.w;
      ss += v.x*v.x + v.y*v.y + v.z*v.z + v.w*v.w;
    }
    #pragma unroll
    for (int off = 32; off > 0; off >>= 1) ss += __shfl_xor(ss, off);
    float rn = rsqrtf(ss);
    #pragma unroll
    for (int i = 0; i < 32; i++) vals[i] *= rn;
    #pragma unroll
    for (int j = 0; j < 8; j++) {
      half4v ph, pl;
      #pragma unroll
      for (int rr = 0; rr < 4; rr++) {
        float v = vals[4*j + rr];
        _Float16 h = (_Float16)v;
        _Float16 lo = (_Float16)(v - (float)h);
        ph[rr] = h; pl[rr] = lo;
      }
      *(half4v*)(Ah_rm + l * 40 + j * 4) = ph;
      *(half4v*)(Al_rm + l * 40 + j * 4) = pl;
    }
    #pragma unroll
    for (int i = 0; i < 32; i++) {
      float v = vals[i];
      _Float16 h = (_Float16)v;
      Ah_cm[i * 72 + l] = h;
      Al_cm[i * 72 + l] = (_Float16)(v - (float)h);
    }
  }
  __syncthreads();

  const floatx4 zero4 = {0.f, 0.f, 0.f, 0.f};
  for (int s = 0; s < NS_STEPS; s++) {
    bool last = (s == NS_STEPS - 1);
    half8 fgh[2], fgl[2];
    #pragma unroll
    for (int c = 0; c < 2; c++) {
      fgh[c] = *(half8*)(Ah_cm + (wid * 16 + lane16) * 72 + c * 32 + quad * 8);
      fgl[c] = *(half8*)(Al_cm + (wid * 16 + lane16) * 72 + c * 32 + quad * 8);
    }
    half8 fah[2][2], fal[2][2];
    #pragma unroll
    for (int ti = 0; ti < 2; ti++)
      #pragma unroll
      for (int c = 0; c < 2; c++) {
        fah[ti][c] = *(half8*)(Ah_cm + (ti * 16 + lane16) * 72 + c * 32 + quad * 8);
        fal[ti][c] = *(half8*)(Al_cm + (ti * 16 + lane16) * 72 + c * 32 + quad * 8);
      }
    floatx4 gf[2] = {zero4, zero4};
    #pragma unroll
    for (int ti = 0; ti < 2; ti++)
      #pragma unroll
      for (int c = 0; c < 2; c++) {
        gf[ti] = __builtin_amdgcn_mfma_f32_16x16x32_f16(
            fah[ti][c], fgh[c], gf[ti], 0, 0, 0);
        gf[ti] = __builtin_amdgcn_mfma_f32_16x16x32_f16(
            fah[ti][c], fgl[c], gf[ti], 0, 0, 0);
        gf[ti] = __builtin_amdgcn_mfma_f32_16x16x32_f16(
            fal[ti][c], fgh[c], gf[ti], 0, 0, 0);
      }
    #pragma unroll
    for (int ti = 0; ti < 2; ti++) {
      int col = wid * 16 + lane16;
      int row0 = ti * 16 + quad * 4;
      half4v ph, pl;
      #pragma unroll
      for (int rr = 0; rr < 4; rr++) {
        float m = ((row0 + rr) == col ? 1.5f : 0.f) - 0.5f * gf[ti][rr];
        _Float16 h = (_Float16)m;
        ph[rr] = h; pl[rr] = (_Float16)(m - (float)h);
      }
      *(half4v*)(Mh_cm + col * 40 + row0) = ph;
      *(half4v*)(Ml_cm + col * 40 + row0) = pl;
    }
    __syncthreads();
    half8 fmh[2], fml[2], fbh[2], fbl[2];
    #pragma unroll
    for (int ti = 0; ti < 2; ti++) {
      fmh[ti] = *(half8*)(Mh_cm + (ti * 16 + lane16) * 40 + quad * 8);
      fml[ti] = *(half8*)(Ml_cm + (ti * 16 + lane16) * 40 + quad * 8);
    }
    #pragma unroll
    for (int jj = 0; jj < 2; jj++) {
      int tj = 2 * wid + jj;
      fbh[jj] = *(half8*)(Ah_rm + (tj * 16 + lane16) * 40 + quad * 8);
      fbl[jj] = *(half8*)(Al_rm + (tj * 16 + lane16) * 40 + quad * 8);
    }
    floatx4 df[2][2];
    #pragma unroll
    for (int ti = 0; ti < 2; ti++)
      #pragma unroll
      for (int jj = 0; jj < 2; jj++) {
        df[ti][jj] = __builtin_amdgcn_mfma_f32_16x16x32_f16(
            fmh[ti], fbh[jj], zero4, 0, 0, 0);
        df[ti][jj] = __builtin_amdgcn_mfma_f32_16x16x32_f16(
            fmh[ti], fbl[jj], df[ti][jj], 0, 0, 0);
        df[ti][jj] = __builtin_amdgcn_mfma_f32_16x16x32_f16(
            fml[ti], fbh[jj], df[ti][jj], 0, 0, 0);
      }
    __syncthreads();   // WAR: all reads of Ah_rm/M done before overwrite
    if (!last) {
      #pragma unroll
      for (int ti = 0; ti < 2; ti++)
        #pragma unroll
        for (int jj = 0; jj < 2; jj++) {
          int tj = 2 * wid + jj;
          int z = tj * 16 + lane16;
          int d0 = ti * 16 + quad * 4;
          half4v ph, pl;
          #pragma unroll
          for (int rr = 0; rr < 4; rr++) {
            float v = df[ti][jj][rr];
            _Float16 h = (_Float16)v;
            ph[rr] = h; pl[rr] = (_Float16)(v - (float)h);
          }
          *(half4v*)(Ah_rm + z * 40 + d0) = ph;
          *(half4v*)(Al_rm + z * 40 + d0) = pl;
          #pragma unroll
          for (int rr = 0; rr < 4; rr++) {
            Ah_cm[(d0 + rr) * 72 + z] = ph[rr];
            Al_cm[(d0 + rr) * 72 + z] = pl[rr];
          }
        }
    } else {
      #pragma unroll
      for (int ti = 0; ti < 2; ti++)
        #pragma unroll
        for (int jj = 0; jj < 2; jj++) {
          int tj = 2 * wid + jj;
          int z = tj * 16 + lane16;
          int d0 = ti * 16 + quad * 4;
          float4 v;
          v.x = df[ti][jj][0]; v.y = df[ti][jj][1];
          v.z = df[ti][jj][2]; v.w = df[ti][jj][3];
          *(float4*)(Afin + z * 36 + d0) = v;
        }
    }
    __syncthreads();
  }
  #pragma unroll
  for (int j = 0; j < 4; j++) {
    int f = j * 512 + tid * 4;
    int z = f >> 5, d = f & 31;
    float4 v = *(const float4*)(Afin + z * 36 + d);
    *(float4*)(o + f) = v;
  }
}

// ======================= Sylvester flow (K=4 steps) =======================
__global__ __launch_bounds__(64) void flow_k(const float* __restrict__ amat,
    const float* __restrict__ fd, const float* __restrict__ dg1,
    const float* __restrict__ dg2, const float* __restrict__ ab,
    const float* __restrict__ eps, float* __restrict__ dout) {
  __shared__ float Ps[32][64];
  __shared__ float wsh[32], tsh[32], ush[32];
  int b = blockIdx.x, l = threadIdx.x;
  float mv  = dout[26624 + b * 64 + l];
  float lvv = dout[43008 + b * 64 + l];
  float z0 = mv + eps[b * 64 + l] * expf(0.5f * lvv);
  dout[59648 + b * 64 + l] = z0;
  float zv = z0;
  float ldj = 0.f;
  float q[32];
  for (int k = 0; k < 4; k++) {
    const float4* qrow = (const float4*)(amat + (size_t)(b * 4 + k) * 2048 + l * 32);
    #pragma unroll
    for (int j = 0; j < 8; j++) {
      float4 v = qrow[j];
      q[4*j] = v.x; q[4*j+1] = v.y; q[4*j+2] = v.z; q[4*j+3] = v.w;
    }
    #pragma unroll
    for (int d = 0; d < 32; d++) Ps[d][l] = zv * q[d];
    __syncthreads();
    if (l < 32) {
      const float4* pr = (const float4*)Ps[l];
      float s = 0.f;
      #pragma unroll
      for (int j = 0; j < 16; j++) {
        float4 v = pr[j];
        s += v.x + v.y + v.z + v.w;
      }
      wsh[l] = s;
    }
    __syncthreads();
    if (l < 32) {
      int e = l;
      float acc = ab[b * 128 + e * 4 + k] + wsh[e] * dg2[b * 128 + e * 4 + k];
      for (int d = e + 1; d < 32; d++)
        acc += wsh[d] * fd[b * 4096 + d * 128 + e * 4 + k];
      float tt = tanhf(acc);
      tsh[e] = tt;
      float dd = (1.f - tt * tt) * (dg1[b*128 + e*4 + k] * dg2[b*128 + e*4 + k]) + 1.f;
      ldj += logf(fabsf(dd));
    }
    __syncthreads();
    if (l < 32) {
      int d = l;
      float acc = tsh[d] * dg1[b * 128 + d * 4 + k];
      for (int e = d + 1; e < 32; e++)
        acc += fd[b * 4096 + d * 128 + e * 4 + k] * tsh[e];
      ush[d] = acc;
    }
    __syncthreads();
    #pragma unroll
    for (int d = 0; d < 32; d++) zv += q[d] * ush[d];
    __syncthreads();
  }
  dout[76032 + b * 64 + l] = zv;
  for (int off = 16; off > 0; off >>= 1) ldj += __shfl_down(ldj, off, 32);
  if (l == 0) dout[59392 + b] = ldj;
}

// ======================= host launch =======================
extern "C" void kernel_launch(void* const* d_in, const int* in_sizes, int n_in,
                              void* d_out, int out_size, void* d_ws, size_t ws_size,
                              hipStream_t stream) {
  (void)in_sizes; (void)n_in; (void)out_size; (void)ws_size;
  const float* x     = (const float*)d_in[0];
  const float* eps   = (const float*)d_in[1];
  const float* cw1   = (const float*)d_in[2];
  const float* cb1   = (const float*)d_in[3];
  const float* g1    = (const float*)d_in[4];
  const float* be1   = (const float*)d_in[5];
  const float* cw2   = (const float*)d_in[6];
  const float* cb2   = (const float*)d_in[7];
  const float* g2    = (const float*)d_in[8];
  const float* be2   = (const float*)d_in[9];
  const float* cw3   = (const float*)d_in[10];
  const float* cb3   = (const float*)d_in[11];
  const float* g3    = (const float*)d_in[12];
  const float* be3   = (const float*)d_in[13];
  const float* d1_w  = (const float*)d_in[14];
  const float* d1_b  = (const float*)d_in[15];
  const float* bn1_g = (const float*)d_in[16];
  const float* bn1_b = (const float*)d_in[17];
  const float* mu_w  = (const float*)d_in[18];
  const float* mu_b  = (const float*)d_in[19];
  const float* lv_w  = (const float*)d_in[20];
  const float* lv_b  = (const float*)d_in[21];
  const float* ad_w  = (const float*)d_in[22];
  const float* ad_b  = (const float*)d_in[23];
  const float* adg1_w= (const float*)d_in[24];
  const float* adg1_b= (const float*)d_in[25];
  const float* adg2_w= (const float*)d_in[26];
  const float* adg2_b= (const float*)d_in[27];
  const float* aq_w  = (const float*)d_in[28];
  const float* aq_b  = (const float*)d_in[29];
  const float* ab_w  = (const float*)d_in[30];
  const float* ab_b  = (const float*)d_in[31];
  const float* d3_w  = (const float*)d_in[32];
  const float* d3_b  = (const float*)d_in[33];
  const float* bn3_g = (const float*)d_in[34];
  const float* bn3_b = (const float*)d_in[35];
  const float* d4_w  = (const float*)d_in[36];
  const float* d4_b  = (const float*)d_in[37];
  const float* bn4_g = (const float*)d_in[38];
  const float* bn4_b = (const float*)d_in[39];
  const float* tw1   = (const float*)d_in[40];
  const float* tb1   = (const float*)d_in[41];
  const float* tg1   = (const float*)d_in[42];
  const float* tbe1  = (const float*)d_in[43];
  const float* tw2   = (const float*)d_in[44];
  const float* tb2   = (const float*)d_in[45];
  const float* tg2   = (const float*)d_in[46];
  const float* tbe2  = (const float*)d_in[47];
  const float* tw3   = (const float*)d_in[48];
  const float* tb3   = (const float*)d_in[49];

  float* out = (float*)d_out;
  float* wsf = (float*)d_ws;
  float* h1   = wsf;                 // 196608  (later: abuf, t2)
  float* h2   = wsf + 196608;        // 81920   (later: abuf tail, t1)
  float* h3   = wsf + 278528;        // 28672   (later: dec2)
  float* out1 = wsf + 307200;        // 262144  (later: dec1)
  float* fd   = wsf + 569344;        // 1048576
  float* dg1  = wsf + 1617920;       // 32768
  float* dg2  = wsf + 1650688;       // 32768
  float* qb   = wsf + 1683456;       // 2097152
  float* ab   = wsf + 3780608;       // 32768
  float* amat = wsf + 3813376;       // 2097152
  float* dec1 = out1;
  float* dec2 = h3;
  float* t1   = h2;
  float* t2   = h1;

  // A-fragment buffer: 524288 shorts = 262144 floats, reuses dead h1+h2
  short* ahi = (short*)wsf;
  short* alo = ahi + 262144;

  float* mean_o = out + 26624;
  float* lv_o   = out + 43008;
  float* z_o    = out + 76032;

  // ---------------- encoder ----------------
  conv1_k<<<768, 256, 0, stream>>>(x, cw1, cb1, h1);
  bn2d_k<<<32, 256, 0, stream>>>(h1, g1, be1, 32, 24);
  conv2_k<<<320, 256, 0, stream>>>(h1, cw2, cb2, h2);
  bn2d_k<<<16, 256, 0, stream>>>(h2, g2, be2, 16, 20);
  conv3_k<<<112, 256, 0, stream>>>(h2, cw3, cb3, h3);
  bn2d_k<<<8, 256, 0, stream>>>(h3, g3, be3, 8, 14);

  gemm_os_k<<<dim3(16, 4), 256, 0, stream>>>(h3, d1_w, d1_b, out1, 112, 1024);
  bn1d_k<<<32, 256, 0, stream>>>(out1, bn1_g, bn1_b, 1024);

  // ---------------- fused heads (MFMA) ----------------
  prep_a_k<<<128, 256, 0, stream>>>(out1, ahi, alo);

  HeadArgs ha;
  ha.W[0] = mu_w;   ha.b[0] = mu_b;   ha.dst[0] = mean_o; ha.ldw[0] = 64;   ha.op[0] = 0;
  ha.W[1] = lv_w;   ha.b[1] = lv_b;   ha.dst[1] = lv_o;   ha.ldw[1] = 64;   ha.op[1] = 0;
  ha.W[2] = ad_w;   ha.b[2] = ad_b;   ha.dst[2] = fd;     ha.ldw[2] = 4096; ha.op[2] = 0;
  ha.W[3] = adg1_w; ha.b[3] = adg1_b; ha.dst[3] = dg1;    ha.ldw[3] = 128;  ha.op[3] = 1;
  ha.W[4] = adg2_w; ha.b[4] = adg2_b; ha.dst[4] = dg2;    ha.ldw[4] = 128;  ha.op[4] = 1;
  ha.W[5] = aq_w;   ha.b[5] = aq_b;   ha.dst[5] = qb;     ha.ldw[5] = 8192; ha.op[5] = 0;
  ha.W[6] = ab_w;   ha.b[6] = ab_b;   ha.dst[6] = ab;     ha.ldw[6] = 128;  ha.op[6] = 0;
  ha.off[0] = 0;    ha.off[1] = 64;   ha.off[2] = 128;  ha.off[3] = 4224;
  ha.off[4] = 4352; ha.off[5] = 4480; ha.off[6] = 12672; ha.off[7] = 12800;
  heads_mfma_k<<<dim3(200, 4), 256, 0, stream>>>(ahi, alo, ha);

  // ---------------- orthogonalization + flow ----------------
  ns_f16split_k<<<1024, 128, 0, stream>>>(qb, amat);
  flow_k<<<256, 64, 0, stream>>>(amat, fd, dg1, dg2, ab, eps, out);

  // ---------------- decoder ----------------
  gemm_os_k<<<dim3(16, 4), 256, 0, stream>>>(z_o, d3_w, d3_b, dec1, 64, 1024);
  bn1d_k<<<32, 256, 0, stream>>>(dec1, bn3_g, bn3_b, 1024);
  hipMemsetAsync(dec2, 0, 28672 * sizeof(float), stream);
  gemm_ks_k<<<dim3(2, 4, 16), 256, 0, stream>>>(dec1, d4_w, d4_b, dec2);
  bn1d_k<<<4, 256, 0, stream>>>(dec2, bn4_g, bn4_b, 112);

  tconv1_k<<<320, 256, 0, stream>>>(dec2, tw1, tb1, t1);
  bn2d_k<<<16, 256, 0, stream>>>(t1, tg1, tbe1, 16, 20);
  tconv2_k<<<768, 256, 0, stream>>>(t1, tw2, tb2, t2);
  bn2d_k<<<32, 256, 0, stream>>>(t2, tg2, tbe2, 32, 24);
  tconv3_k<<<104, 256, 0, stream>>>(t2, tw3, tb3, out);
}

// Round 14
// 480.292 us; speedup vs baseline: 1.1689x; 1.0178x over previous
//
#include <hip/hip_runtime.h>
#include <math.h>

#define NS_STEPS 16

typedef __attribute__((ext_vector_type(8))) _Float16 half8;
typedef __attribute__((ext_vector_type(4))) _Float16 half4v;
typedef __attribute__((ext_vector_type(8))) short short8;
typedef __attribute__((ext_vector_type(4))) short short4v;
typedef __attribute__((ext_vector_type(4))) float floatx4;

static __device__ inline unsigned short f2bf(float f) {
  union { float f; unsigned u; } v; v.f = f;
  unsigned r = v.u + 0x7fffu + ((v.u >> 16) & 1u);
  return (unsigned short)(r >> 16);
}
static __device__ inline float bf2f(unsigned short h) {
  union { unsigned u; float f; } v; v.u = ((unsigned)h) << 16;
  return v.f;
}

// ======================= encoder convs =======================
__global__ __launch_bounds__(256) void conv1_k(const float* __restrict__ x,
    const float* __restrict__ w, const float* __restrict__ bias,
    float* __restrict__ out) {
  __shared__ float ws[384];
  int tid = threadIdx.x;
  for (int i = tid; i < 384; i += 256) ws[i] = w[i];
  __syncthreads();
  int idx = blockIdx.x * 256 + tid;
  if (idx >= 196608) return;
  int b = idx / 768, r = idx % 768;
  int c = r / 24, h = r % 24;
  const float* xb = x + b * 104 + h * 4;
  const float* wc = ws + c * 12;
  float acc = bias[c];
  #pragma unroll
  for (int kh = 0; kh < 3; kh++) {
    #pragma unroll
    for (int kw = 0; kw < 4; kw++)
      acc += xb[kh * 4 + kw] * wc[kh * 4 + kw];
  }
  out[idx] = acc;
}

__global__ __launch_bounds__(256) void conv2_k(const float* __restrict__ in,
    const float* __restrict__ w, const float* __restrict__ bias,
    float* __restrict__ out) {
  __shared__ float ws[2560];
  int tid = threadIdx.x;
  for (int i = tid; i < 2560; i += 256) ws[i] = w[i];
  __syncthreads();
  int idx = blockIdx.x * 256 + tid;
  if (idx >= 81920) return;
  int b = idx / 320, r = idx % 320;
  int c = r / 20, h = r % 20;
  const float* ib = in + b * 768 + h;
  const float* wc = ws + c * 160;
  float acc = bias[c];
  for (int i = 0; i < 32; i++) {
    #pragma unroll
    for (int kh = 0; kh < 5; kh++)
      acc += ib[i * 24 + kh] * wc[i * 5 + kh];
  }
  out[idx] = acc;
}

__global__ __launch_bounds__(256) void conv3_k(const float* __restrict__ in,
    const float* __restrict__ w, const float* __restrict__ bias,
    float* __restrict__ out) {
  __shared__ float ws[896];
  int tid = threadIdx.x;
  for (int i = tid; i < 896; i += 256) ws[i] = w[i];
  __syncthreads();
  int idx = blockIdx.x * 256 + tid;
  if (idx >= 28672) return;
  int b = idx / 112, r = idx % 112;
  int c = r / 14, h = r % 14;
  const float* ib = in + b * 320 + h;
  const float* wc = ws + c * 112;
  float acc = bias[c];
  for (int i = 0; i < 16; i++) {
    #pragma unroll
    for (int kh = 0; kh < 7; kh++)
      acc += ib[i * 20 + kh] * wc[i * 7 + kh];
  }
  out[idx] = acc;
}

// ======================= decoder tconvs =======================
__global__ __launch_bounds__(256) void tconv1_k(const float* __restrict__ in,
    const float* __restrict__ w, const float* __restrict__ bias,
    float* __restrict__ out) {
  __shared__ float ws[896];
  int tid = threadIdx.x;
  for (int i = tid; i < 896; i += 256) ws[i] = w[i];
  __syncthreads();
  int idx = blockIdx.x * 256 + tid;
  if (idx >= 81920) return;
  int b = idx / 320, r = idx % 320;
  int c = r / 20, s = r % 20;
  float acc = bias[c];
  for (int o = 0; o < 8; o++) {
    #pragma unroll
    for (int kh = 0; kh < 7; kh++) {
      int hs = s - kh;
      if (hs >= 0 && hs < 14)
        acc += in[b * 112 + o * 14 + hs] * ws[o * 112 + c * 7 + kh];
    }
  }
  out[idx] = acc;
}

__global__ __launch_bounds__(256) void tconv2_k(const float* __restrict__ in,
    const float* __restrict__ w, const float* __restrict__ bias,
    float* __restrict__ out) {
  __shared__ float ws[2560];
  int tid = threadIdx.x;
  for (int i = tid; i < 2560; i += 256) ws[i] = w[i];
  __syncthreads();
  int idx = blockIdx.x * 256 + tid;
  if (idx >= 196608) return;
  int b = idx / 768, r = idx % 768;
  int c = r / 24, s = r % 24;
  float acc = bias[c];
  for (int o = 0; o < 16; o++) {
    #pragma unroll
    for (int kh = 0; kh < 5; kh++) {
      int hs = s - kh;
      if (hs >= 0 && hs < 20)
        acc += in[b * 320 + o * 20 + hs] * ws[o * 160 + c * 5 + kh];
    }
  }
  out[idx] = acc;
}

__global__ __launch_bounds__(256) void tconv3_k(const float* __restrict__ in,
    const float* __restrict__ w, const float* __restrict__ bias,
    float* __restrict__ out) {
  __shared__ float ws[384];
  int tid = threadIdx.x;
  for (int i = tid; i < 384; i += 256) ws[i] = w[i];
  __syncthreads();
  int idx = blockIdx.x * 256 + tid;
  if (idx >= 26624) return;
  int b = idx / 104, r = idx % 104;
  int sh = r / 4, sw = r % 4;
  float acc = bias[0];
  for (int o = 0; o < 32; o++) {
    #pragma unroll
    for (int kh = 0; kh < 3; kh++) {
      int hs = sh - kh;
      if (hs >= 0 && hs < 24)
        acc += in[b * 768 + o * 24 + hs] * ws[o * 12 + kh * 4 + sw];
    }
  }
  out[idx] = acc;
}

// ======================= batchnorm =======================
__global__ __launch_bounds__(256) void bn2d_k(float* __restrict__ x,
    const float* __restrict__ g, const float* __restrict__ be,
    int C, int HW) {
  __shared__ float rs[256], rs2[256];
  int c = blockIdx.x, tid = threadIdx.x;
  int total = 256 * HW;
  float s = 0.f, s2 = 0.f;
  for (int i = tid; i < total; i += 256) {
    int b = i / HW, j = i - b * HW;
    float v = x[(b * C + c) * HW + j];
    s += v; s2 += v * v;
  }
  rs[tid] = s; rs2[tid] = s2;
  __syncthreads();
  for (int off = 128; off > 0; off >>= 1) {
    if (tid < off) { rs[tid] += rs[tid + off]; rs2[tid] += rs2[tid + off]; }
    __syncthreads();
  }
  float m = rs[0] / (float)total;
  float var = rs2[0] / (float)total - m * m;
  float rstd = rsqrtf(var + 1e-5f) * g[c];
  float bb = be[c];
  for (int i = tid; i < total; i += 256) {
    int b = i / HW, j = i - b * HW;
    size_t idx = (size_t)(b * C + c) * HW + j;
    float v = (x[idx] - m) * rstd + bb;
    x[idx] = v > 0.f ? v : 0.f;
  }
}

__global__ __launch_bounds__(256) void bn1d_k(float* __restrict__ x,
    const float* __restrict__ g, const float* __restrict__ be, int N) {
  __shared__ float p1[8][32], p2[8][32];
  int t = threadIdx.x;
  int cl = t & 31, rg = t >> 5;
  int c = blockIdx.x * 32 + cl;
  float s = 0.f, s2 = 0.f;
  if (c < N) {
    for (int r = rg * 32; r < rg * 32 + 32; r++) {
      float v = x[r * N + c];
      s += v; s2 += v * v;
    }
  }
  p1[rg][cl] = s; p2[rg][cl] = s2;
  __syncthreads();
  float ts = 0.f, ts2 = 0.f;
  #pragma unroll
  for (int i = 0; i < 8; i++) { ts += p1[i][cl]; ts2 += p2[i][cl]; }
  float m = ts * (1.f / 256.f);
  float var = ts2 * (1.f / 256.f) - m * m;
  float rstd = rsqrtf(var + 1e-5f) * ((c < N) ? g[c] : 1.f);
  float bb = (c < N) ? be[c] : 0.f;
  if (c < N) {
    for (int r = rg * 32; r < rg * 32 + 32; r++) {
      float v = (x[r * N + c] - m) * rstd + bb;
      x[r * N + c] = v > 0.f ? v : 0.f;
    }
  }
}

// ============== one-shot fp32 GEMM (K<=112, N multiple of 64) ===============
__global__ __launch_bounds__(256) void gemm_os_k(const float* __restrict__ A,
    const float* __restrict__ W, const float* __restrict__ bias,
    float* __restrict__ C, int K, int N) {
  __shared__ float As[112 * 68];
  __shared__ float Bs[112 * 68];
  int tid = threadIdx.x;
  int nb = blockIdx.x, mb = blockIdx.y;
  int K16 = K >> 4;
  {
    int row = tid >> 2;
    const float* Ar = A + (size_t)(mb * 64 + row) * K;
    for (int i = 0; i < K16; i++) {
      int j = (tid & 3) + 4 * i;
      float4 v = *(const float4*)(Ar + j * 4);
      int k = j * 4;
      As[k * 68 + row] = v.x;
      As[(k + 1) * 68 + row] = v.y;
      As[(k + 2) * 68 + row] = v.z;
      As[(k + 3) * 68 + row] = v.w;
    }
  }
  {
    int n4 = (tid & 15) * 4;
    for (int i = 0; i < K16; i++) {
      int k = (tid >> 4) + 16 * i;
      float4 v = *(const float4*)(W + (size_t)k * N + nb * 64 + n4);
      *(float4*)(Bs + k * 68 + n4) = v;
    }
  }
  __syncthreads();
  int tm = tid >> 4, tn = tid & 15;
  int m0 = tm * 4, n0 = tn * 4;
  float acc[4][4] = {{0.f}};
  #pragma unroll 8
  for (int kk = 0; kk < K; kk++) {
    float4 a = *(const float4*)(As + kk * 68 + m0);
    float4 b = *(const float4*)(Bs + kk * 68 + n0);
    acc[0][0] += a.x*b.x; acc[0][1] += a.x*b.y; acc[0][2] += a.x*b.z; acc[0][3] += a.x*b.w;
    acc[1][0] += a.y*b.x; acc[1][1] += a.y*b.y; acc[1][2] += a.y*b.z; acc[1][3] += a.y*b.w;
    acc[2][0] += a.z*b.x; acc[2][1] += a.z*b.y; acc[2][2] += a.z*b.z; acc[2][3] += a.z*b.w;
    acc[3][0] += a.w*b.x; acc[3][1] += a.w*b.y; acc[3][2] += a.w*b.z; acc[3][3] += a.w*b.w;
  }
  #pragma unroll
  for (int i = 0; i < 4; i++) {
    int m = mb * 64 + m0 + i;
    #pragma unroll
    for (int j = 0; j < 4; j++) {
      int n = nb * 64 + n0 + j;
      C[(size_t)m * N + n] = acc[i][j] + bias[n];
    }
  }
}

// ============== K-split fp32 GEMM for d4: C(256,112) += A@W chunk ===========
__global__ __launch_bounds__(256) void gemm_ks_k(const float* __restrict__ A,
    const float* __restrict__ W, const float* __restrict__ bias,
    float* __restrict__ C) {
  __shared__ float As[64 * 68];
  __shared__ float Bs[64 * 68];
  int tid = threadIdx.x;
  int nb = blockIdx.x, mb = blockIdx.y, kc = blockIdx.z;
  int k0 = kc * 64;
  {
    int row = tid >> 2;
    const float* Ar = A + (size_t)(mb * 64 + row) * 1024 + k0;
    #pragma unroll
    for (int i = 0; i < 4; i++) {
      int j = (tid & 3) + 4 * i;
      float4 v = *(const float4*)(Ar + j * 4);
      int k = j * 4;
      As[k * 68 + row] = v.x;
      As[(k + 1) * 68 + row] = v.y;
      As[(k + 2) * 68 + row] = v.z;
      As[(k + 3) * 68 + row] = v.w;
    }
  }
  {
    int n4 = (tid & 15) * 4;
    int nbase = nb * 64 + n4;
    #pragma unroll
    for (int i = 0; i < 4; i++) {
      int k = (tid >> 4) + 16 * i;
      const float* Wr = W + (size_t)(k0 + k) * 112;
      float4 v;
      v.x = (nbase     < 112) ? Wr[nbase]     : 0.f;
      v.y = (nbase + 1 < 112) ? Wr[nbase + 1] : 0.f;
      v.z = (nbase + 2 < 112) ? Wr[nbase + 2] : 0.f;
      v.w = (nbase + 3 < 112) ? Wr[nbase + 3] : 0.f;
      *(float4*)(Bs + k * 68 + n4) = v;
    }
  }
  __syncthreads();
  int tm = tid >> 4, tn = tid & 15;
  int m0 = tm * 4, n0 = tn * 4;
  float acc[4][4] = {{0.f}};
  #pragma unroll 8
  for (int kk = 0; kk < 64; kk++) {
    float4 a = *(const float4*)(As + kk * 68 + m0);
    float4 b = *(const float4*)(Bs + kk * 68 + n0);
    acc[0][0] += a.x*b.x; acc[0][1] += a.x*b.y; acc[0][2] += a.x*b.z; acc[0][3] += a.x*b.w;
    acc[1][0] += a.y*b.x; acc[1][1] += a.y*b.y; acc[1][2] += a.y*b.z; acc[1][3] += a.y*b.w;
    acc[2][0] += a.z*b.x; acc[2][1] += a.z*b.y; acc[2][2] += a.z*b.z; acc[2][3] += a.z*b.w;
    acc[3][0] += a.w*b.x; acc[3][1] += a.w*b.y; acc[3][2] += a.w*b.z; acc[3][3] += a.w*b.w;
  }
  #pragma unroll
  for (int i = 0; i < 4; i++) {
    int m = mb * 64 + m0 + i;
    #pragma unroll
    for (int j = 0; j < 4; j++) {
      int n = nb * 64 + n0 + j;
      if (n < 112) {
        float v = acc[i][j] + (kc == 0 ? bias[n] : 0.f);
        atomicAdd(&C[m * 112 + n], v);
      }
    }
  }
}

// ======= A-fragment precompute: out1 f32 -> bf16 hi/lo, MFMA-frag layout =====
__global__ __launch_bounds__(256) void prep_a_k(const float* __restrict__ A,
    short* __restrict__ ahi, short* __restrict__ alo) {
  int gi = blockIdx.x * 256 + threadIdx.x;   // 0..32767
  int lane = gi & 63;
  int t = gi >> 6;
  int mt = t & 3; t >>= 2;
  int c = t & 31; int mb = t >> 5;
  int row = mb * 64 + mt * 16 + (lane & 15);
  int k0 = c * 32 + (lane >> 4) * 8;
  const float* src = A + (size_t)row * 1024 + k0;
  float4 v0 = *(const float4*)(src);
  float4 v1 = *(const float4*)(src + 4);
  float av[8] = {v0.x, v0.y, v0.z, v0.w, v1.x, v1.y, v1.z, v1.w};
  short8 h, lo;
  #pragma unroll
  for (int i = 0; i < 8; i++) {
    unsigned short hh = f2bf(av[i]);
    h[i] = (short)hh;
    lo[i] = (short)f2bf(av[i] - bf2f(hh));
  }
  *(short8*)(ahi + (size_t)gi * 8) = h;
  *(short8*)(alo + (size_t)gi * 8) = lo;
}

// ================= fused head GEMMs, compensated-bf16 MFMA ==================
// v7: grid (200, 2), 512-thread blocks (8 waves x 16 rows). The W tile is
// converted by 2 blocks instead of 4 and by 512 threads (4 elem each,
// was 256x8) -> total W-conversion VALU halves (v6 was VALU-bound:
// VALUBusy 39% vs MfmaUtil 16%). Same fragments, same f2bf per element,
// same MFMA order -> bitwise identical. 3-deep W prefetch + lgkmcnt-only
// barrier unchanged. Staging writes: 4 shorts (8B-aligned ds_write_b64).
struct HeadArgs {
  const float* W[7];
  const float* b[7];
  float* dst[7];
  int off[8];
  int ldw[7];
  int op[7];
};

__global__ __launch_bounds__(512) void heads_mfma_k(const short* __restrict__ ahi,
                                                    const short* __restrict__ alo,
                                                    HeadArgs ha) {
  __shared__ __align__(16) short Wsh[2][2][2048];  // [buf][hi/lo][64col x 32k frag]
  int tid = threadIdx.x;
  int nb = blockIdx.x;          // 64-col tile, 0..199
  int mqh = blockIdx.y;         // 128-row half, 0..1
  int gc = nb * 64;
  int r = 0;
  while (gc >= ha.off[r + 1]) r++;
  const float* Wp = ha.W[r];
  const float* bias = ha.b[r];
  float* dst = ha.dst[r];
  int ldw = ha.ldw[r];
  int op = ha.op[r];
  int nloc = gc - ha.off[r];

  int w = tid >> 6, l = tid & 63;
  int lane16 = l & 15, quad = l >> 4;

  // staging role: column c64, k-quarter q8 (4 k-values each)
  int c64 = tid & 63, q8 = tid >> 6;
  const float* wcol = Wp + (size_t)(q8 * 4) * ldw + nloc + c64;
  // granule (ct*64 + kq*16 + lane16) holds col (ct*16+lane16), k kq*8..+7;
  // this thread covers k q8*4..q8*4+3 => granule kq = q8>>1, short offs (q8&1)*4
  int wg = ((c64 >> 4) * 64 + (q8 >> 1) * 16 + (c64 & 15)) * 8 + (q8 & 1) * 4;

  // wave w owns rows mqh*128 + w*16 .. +15
  int mb = mqh * 2 + (w >> 2);
  int mt = w & 3;
  const short* agh = ahi + (size_t)mb * 65536 + mt * 512 + l * 8;
  const short* agl = alo + (size_t)mb * 65536 + mt * 512 + l * 8;

  const floatx4 zero4 = {0.f, 0.f, 0.f, 0.f};
  floatx4 acc[4] = {zero4, zero4, zero4, zero4};

  float wvN[4], wvF[4];
  short4v whiN, wloN;
  short8 aCh, aCl, aNh, aNl;

  // prologue: buf0 <- W(0); whiN/wloN <- W(1); wvN raw <- W(2); aC <- A(0)
  {
    float wv0[4];
    #pragma unroll
    for (int j = 0; j < 4; j++) wv0[j] = wcol[(size_t)j * ldw];
    #pragma unroll
    for (int j = 0; j < 4; j++) wvN[j] = wcol[(size_t)(32 + j) * ldw];
    aCh = *(const short8*)(agh);
    aCl = *(const short8*)(agl);
    #pragma unroll
    for (int j = 0; j < 4; j++) wvF[j] = wcol[(size_t)(64 + j) * ldw];
    short4v t0h, t0l;
    #pragma unroll
    for (int j = 0; j < 4; j++) {
      unsigned short hh = f2bf(wv0[j]);
      t0h[j] = (short)hh;
      t0l[j] = (short)f2bf(wv0[j] - bf2f(hh));
    }
    *(short4v*)(&Wsh[0][0][wg]) = t0h;
    *(short4v*)(&Wsh[0][1][wg]) = t0l;
    #pragma unroll
    for (int j = 0; j < 4; j++) {
      unsigned short hh = f2bf(wvN[j]);
      whiN[j] = (short)hh;
      wloN[j] = (short)f2bf(wvN[j] - bf2f(hh));
    }
    #pragma unroll
    for (int j = 0; j < 4; j++) wvN[j] = wvF[j];
    asm volatile("s_waitcnt lgkmcnt(0)" ::: "memory");
    __builtin_amdgcn_s_barrier();
  }

  // invariant at top of iter ch: buf[ch&1]=W(ch) in LDS; whiN/wloN=W(ch+1);
  // wvN raw=W(ch+2); aC=A(ch).
  for (int ch = 0; ch < 32; ++ch) {
    int p = ch & 1;
    if (ch < 31) {
      *(short4v*)(&Wsh[p ^ 1][0][wg]) = whiN;
      *(short4v*)(&Wsh[p ^ 1][1][wg]) = wloN;
    }
    if (ch < 29) {
      #pragma unroll
      for (int j = 0; j < 4; j++)
        wvF[j] = wcol[(size_t)((ch + 3) * 32 + j) * ldw];
    }
    if (ch < 31) {
      aNh = *(const short8*)(agh + (size_t)(ch + 1) * 2048);
      aNl = *(const short8*)(agl + (size_t)(ch + 1) * 2048);
    }
    short8 bh0 = *(const short8*)(&Wsh[p][0][(0 * 64 + l) * 8]);
    short8 bl0 = *(const short8*)(&Wsh[p][1][(0 * 64 + l) * 8]);
    short8 bh1 = *(const short8*)(&Wsh[p][0][(1 * 64 + l) * 8]);
    short8 bl1 = *(const short8*)(&Wsh[p][1][(1 * 64 + l) * 8]);
    short8 bh2 = *(const short8*)(&Wsh[p][0][(2 * 64 + l) * 8]);
    short8 bl2 = *(const short8*)(&Wsh[p][1][(2 * 64 + l) * 8]);
    short8 bh3 = *(const short8*)(&Wsh[p][0][(3 * 64 + l) * 8]);
    short8 bl3 = *(const short8*)(&Wsh[p][1][(3 * 64 + l) * 8]);
    acc[0] = __builtin_amdgcn_mfma_f32_16x16x32_bf16(aCh, bh0, acc[0], 0, 0, 0);
    acc[0] = __builtin_amdgcn_mfma_f32_16x16x32_bf16(aCh, bl0, acc[0], 0, 0, 0);
    acc[0] = __builtin_amdgcn_mfma_f32_16x16x32_bf16(aCl, bh0, acc[0], 0, 0, 0);
    acc[1] = __builtin_amdgcn_mfma_f32_16x16x32_bf16(aCh, bh1, acc[1], 0, 0, 0);
    acc[1] = __builtin_amdgcn_mfma_f32_16x16x32_bf16(aCh, bl1, acc[1], 0, 0, 0);
    acc[1] = __builtin_amdgcn_mfma_f32_16x16x32_bf16(aCl, bh1, acc[1], 0, 0, 0);
    acc[2] = __builtin_amdgcn_mfma_f32_16x16x32_bf16(aCh, bh2, acc[2], 0, 0, 0);
    acc[2] = __builtin_amdgcn_mfma_f32_16x16x32_bf16(aCh, bl2, acc[2], 0, 0, 0);
    acc[2] = __builtin_amdgcn_mfma_f32_16x16x32_bf16(aCl, bh2, acc[2], 0, 0, 0);
    acc[3] = __builtin_amdgcn_mfma_f32_16x16x32_bf16(aCh, bh3, acc[3], 0, 0, 0);
    acc[3] = __builtin_amdgcn_mfma_f32_16x16x32_bf16(aCh, bl3, acc[3], 0, 0, 0);
    acc[3] = __builtin_amdgcn_mfma_f32_16x16x32_bf16(aCl, bh3, acc[3], 0, 0, 0);
    if (ch < 30) {
      #pragma unroll
      for (int j = 0; j < 4; j++) {
        unsigned short hh = f2bf(wvN[j]);
        whiN[j] = (short)hh;
        wloN[j] = (short)f2bf(wvN[j] - bf2f(hh));
      }
    }
    if (ch < 29) {
      #pragma unroll
      for (int j = 0; j < 4; j++) wvN[j] = wvF[j];
    }
    if (ch < 31) { aCh = aNh; aCl = aNl; }
    asm volatile("s_waitcnt lgkmcnt(0)" ::: "memory");
    __builtin_amdgcn_s_barrier();
  }

  #pragma unroll
  for (int nf = 0; nf < 4; nf++) {
    int n = nloc + nf * 16 + lane16;
    float bv = bias[n];
    #pragma unroll
    for (int i = 0; i < 4; i++) {
      int m = mqh * 128 + w * 16 + quad * 4 + i;
      float v = acc[nf][i] + bv;
      if (op == 1) v = tanhf(v);
      dst[(size_t)m * ldw + n] = v;
    }
  }
}

// ============ Newton-Schulz: fully compensated f16 MFMA =====================
// v3 structure (proven stable; do NOT re-derive fgh/fgl from registers —
// register-allocator cliff, see R6-R8). NS_STEPS=16 validated (absmax
// pinned at 0.0625 across 30/24/16).
__global__ __launch_bounds__(128) void ns_f16split_k(const float* __restrict__ q,
                                                     float* __restrict__ amat) {
  __align__(16) __shared__ _Float16 arena[12288];
  int tid = threadIdx.x;
  int wid = tid >> 6;
  int l = tid & 63;
  int lane16 = l & 15, quad = l >> 4;
  _Float16* Ah_cm = arena;          // [32][72]
  _Float16* Al_cm = arena + 2304;   // [32][72]
  _Float16* Mh_cm = arena + 4608;   // [32][40]
  _Float16* Ml_cm = arena + 5888;   // [32][40]
  _Float16* Ah_rm = arena + 7168;   // [64][40]
  _Float16* Al_rm = arena + 9728;   // [64][40]
  float* Afin = (float*)arena;      // [64][36]

  const float* g = q + (size_t)blockIdx.x * 2048;
  float* o = amat + (size_t)blockIdx.x * 2048;

  if (wid == 0) {
    float vals[32];
    float ss = 0.f;
    #pragma unroll
    for (int j = 0; j < 8; j++) {
      float4 v = *(const float4*)(g + l * 32 + j * 4);
      vals[4*j] = v.x; vals[4*j+1] = v.y; vals[4*j+2] = v.z; vals[4*j+3] = v.w;
      ss += v.x*v.x + v.y*v.y + v.z*v.z + v.w*v.w;
    }
    #pragma unroll
    for (int off = 32; off > 0; off >>= 1) ss += __shfl_xor(ss, off);
    float rn = rsqrtf(ss);
    #pragma unroll
    for (int i = 0; i < 32; i++) vals[i] *= rn;
    #pragma unroll
    for (int j = 0; j < 8; j++) {
      half4v ph, pl;
      #pragma unroll
      for (int rr = 0; rr < 4; rr++) {
        float v = vals[4*j + rr];
        _Float16 h = (_Float16)v;
        _Float16 lo = (_Float16)(v - (float)h);
        ph[rr] = h; pl[rr] = lo;
      }
      *(half4v*)(Ah_rm + l * 40 + j * 4) = ph;
      *(half4v*)(Al_rm + l * 40 + j * 4) = pl;
    }
    #pragma unroll
    for (int i = 0; i < 32; i++) {
      float v = vals[i];
      _Float16 h = (_Float16)v;
      Ah_cm[i * 72 + l] = h;
      Al_cm[i * 72 + l] = (_Float16)(v - (float)h);
    }
  }
  __syncthreads();

  const floatx4 zero4 = {0.f, 0.f, 0.f, 0.f};
  for (int s = 0; s < NS_STEPS; s++) {
    bool last = (s == NS_STEPS - 1);
    half8 fgh[2], fgl[2];
    #pragma unroll
    for (int c = 0; c < 2; c++) {
      fgh[c] = *(half8*)(Ah_cm + (wid * 16 + lane16) * 72 + c * 32 + quad * 8);
      fgl[c] = *(half8*)(Al_cm + (wid * 16 + lane16) * 72 + c * 32 + quad * 8);
    }
    half8 fah[2][2], fal[2][2];
    #pragma unroll
    for (int ti = 0; ti < 2; ti++)
      #pragma unroll
      for (int c = 0; c < 2; c++) {
        fah[ti][c] = *(half8*)(Ah_cm + (ti * 16 + lane16) * 72 + c * 32 + quad * 8);
        fal[ti][c] = *(half8*)(Al_cm + (ti * 16 + lane16) * 72 + c * 32 + quad * 8);
      }
    floatx4 gf[2] = {zero4, zero4};
    #pragma unroll
    for (int ti = 0; ti < 2; ti++)
      #pragma unroll
      for (int c = 0; c < 2; c++) {
        gf[ti] = __builtin_amdgcn_mfma_f32_16x16x32_f16(
            fah[ti][c], fgh[c], gf[ti], 0, 0, 0);
        gf[ti] = __builtin_amdgcn_mfma_f32_16x16x32_f16(
            fah[ti][c], fgl[c], gf[ti], 0, 0, 0);
        gf[ti] = __builtin_amdgcn_mfma_f32_16x16x32_f16(
            fal[ti][c], fgh[c], gf[ti], 0, 0, 0);
      }
    #pragma unroll
    for (int ti = 0; ti < 2; ti++) {
      int col = wid * 16 + lane16;
      int row0 = ti * 16 + quad * 4;
      half4v ph, pl;
      #pragma unroll
      for (int rr = 0; rr < 4; rr++) {
        float m = ((row0 + rr) == col ? 1.5f : 0.f) - 0.5f * gf[ti][rr];
        _Float16 h = (_Float16)m;
        ph[rr] = h; pl[rr] = (_Float16)(m - (float)h);
      }
      *(half4v*)(Mh_cm + col * 40 + row0) = ph;
      *(half4v*)(Ml_cm + col * 40 + row0) = pl;
    }
    __syncthreads();
    half8 fmh[2], fml[2], fbh[2], fbl[2];
    #pragma unroll
    for (int ti = 0; ti < 2; ti++) {
      fmh[ti] = *(half8*)(Mh_cm + (ti * 16 + lane16) * 40 + quad * 8);
      fml[ti] = *(half8*)(Ml_cm + (ti * 16 + lane16) * 40 + quad * 8);
    }
    #pragma unroll
    for (int jj = 0; jj < 2; jj++) {
      int tj = 2 * wid + jj;
      fbh[jj] = *(half8*)(Ah_rm + (tj * 16 + lane16) * 40 + quad * 8);
      fbl[jj] = *(half8*)(Al_rm + (tj * 16 + lane16) * 40 + quad * 8);
    }
    floatx4 df[2][2];
    #pragma unroll
    for (int ti = 0; ti < 2; ti++)
      #pragma unroll
      for (int jj = 0; jj < 2; jj++) {
        df[ti][jj] = __builtin_amdgcn_mfma_f32_16x16x32_f16(
            fmh[ti], fbh[jj], zero4, 0, 0, 0);
        df[ti][jj] = __builtin_amdgcn_mfma_f32_16x16x32_f16(
            fmh[ti], fbl[jj], df[ti][jj], 0, 0, 0);
        df[ti][jj] = __builtin_amdgcn_mfma_f32_16x16x32_f16(
            fml[ti], fbh[jj], df[ti][jj], 0, 0, 0);
      }
    __syncthreads();   // WAR: all reads of Ah_rm/M done before overwrite
    if (!last) {
      #pragma unroll
      for (int ti = 0; ti < 2; ti++)
        #pragma unroll
        for (int jj = 0; jj < 2; jj++) {
          int tj = 2 * wid + jj;
          int z = tj * 16 + lane16;
          int d0 = ti * 16 + quad * 4;
          half4v ph, pl;
          #pragma unroll
          for (int rr = 0; rr < 4; rr++) {
            float v = df[ti][jj][rr];
            _Float16 h = (_Float16)v;
            ph[rr] = h; pl[rr] = (_Float16)(v - (float)h);
          }
          *(half4v*)(Ah_rm + z * 40 + d0) = ph;
          *(half4v*)(Al_rm + z * 40 + d0) = pl;
          #pragma unroll
          for (int rr = 0; rr < 4; rr++) {
            Ah_cm[(d0 + rr) * 72 + z] = ph[rr];
            Al_cm[(d0 + rr) * 72 + z] = pl[rr];
          }
        }
    } else {
      #pragma unroll
      for (int ti = 0; ti < 2; ti++)
        #pragma unroll
        for (int jj = 0; jj < 2; jj++) {
          int tj = 2 * wid + jj;
          int z = tj * 16 + lane16;
          int d0 = ti * 16 + quad * 4;
          float4 v;
          v.x = df[ti][jj][0]; v.y = df[ti][jj][1];
          v.z = df[ti][jj][2]; v.w = df[ti][jj][3];
          *(float4*)(Afin + z * 36 + d0) = v;
        }
    }
    __syncthreads();
  }
  #pragma unroll
  for (int j = 0; j < 4; j++) {
    int f = j * 512 + tid * 4;
    int z = f >> 5, d = f & 31;
    float4 v = *(const float4*)(Afin + z * 36 + d);
    *(float4*)(o + f) = v;
  }
}

// ======================= Sylvester flow (K=4 steps) =======================
__global__ __launch_bounds__(64) void flow_k(const float* __restrict__ amat,
    const float* __restrict__ fd, const float* __restrict__ dg1,
    const float* __restrict__ dg2, const float* __restrict__ ab,
    const float* __restrict__ eps, float* __restrict__ dout) {
  __shared__ float Ps[32][64];
  __shared__ float wsh[32], tsh[32], ush[32];
  int b = blockIdx.x, l = threadIdx.x;
  float mv  = dout[26624 + b * 64 + l];
  float lvv = dout[43008 + b * 64 + l];
  float z0 = mv + eps[b * 64 + l] * expf(0.5f * lvv);
  dout[59648 + b * 64 + l] = z0;
  float zv = z0;
  float ldj = 0.f;
  float q[32];
  for (int k = 0; k < 4; k++) {
    const float4* qrow = (const float4*)(amat + (size_t)(b * 4 + k) * 2048 + l * 32);
    #pragma unroll
    for (int j = 0; j < 8; j++) {
      float4 v = qrow[j];
      q[4*j] = v.x; q[4*j+1] = v.y; q[4*j+2] = v.z; q[4*j+3] = v.w;
    }
    #pragma unroll
    for (int d = 0; d < 32; d++) Ps[d][l] = zv * q[d];
    __syncthreads();
    if (l < 32) {
      const float4* pr = (const float4*)Ps[l];
      float s = 0.f;
      #pragma unroll
      for (int j = 0; j < 16; j++) {
        float4 v = pr[j];
        s += v.x + v.y + v.z + v.w;
      }
      wsh[l] = s;
    }
    __syncthreads();
    if (l < 32) {
      int e = l;
      float acc = ab[b * 128 + e * 4 + k] + wsh[e] * dg2[b * 128 + e * 4 + k];
      for (int d = e + 1; d < 32; d++)
        acc += wsh[d] * fd[b * 4096 + d * 128 + e * 4 + k];
      float tt = tanhf(acc);
      tsh[e] = tt;
      float dd = (1.f - tt * tt) * (dg1[b*128 + e*4 + k] * dg2[b*128 + e*4 + k]) + 1.f;
      ldj += logf(fabsf(dd));
    }
    __syncthreads();
    if (l < 32) {
      int d = l;
      float acc = tsh[d] * dg1[b * 128 + d * 4 + k];
      for (int e = d + 1; e < 32; e++)
        acc += fd[b * 4096 + d * 128 + e * 4 + k] * tsh[e];
      ush[d] = acc;
    }
    __syncthreads();
    #pragma unroll
    for (int d = 0; d < 32; d++) zv += q[d] * ush[d];
    __syncthreads();
  }
  dout[76032 + b * 64 + l] = zv;
  for (int off = 16; off > 0; off >>= 1) ldj += __shfl_down(ldj, off, 32);
  if (l == 0) dout[59392 + b] = ldj;
}

// ======================= host launch =======================
extern "C" void kernel_launch(void* const* d_in, const int* in_sizes, int n_in,
                              void* d_out, int out_size, void* d_ws, size_t ws_size,
                              hipStream_t stream) {
  (void)in_sizes; (void)n_in; (void)out_size; (void)ws_size;
  const float* x     = (const float*)d_in[0];
  const float* eps   = (const float*)d_in[1];
  const float* cw1   = (const float*)d_in[2];
  const float* cb1   = (const float*)d_in[3];
  const float* g1    = (const float*)d_in[4];
  const float* be1   = (const float*)d_in[5];
  const float* cw2   = (const float*)d_in[6];
  const float* cb2   = (const float*)d_in[7];
  const float* g2    = (const float*)d_in[8];
  const float* be2   = (const float*)d_in[9];
  const float* cw3   = (const float*)d_in[10];
  const float* cb3   = (const float*)d_in[11];
  const float* g3    = (const float*)d_in[12];
  const float* be3   = (const float*)d_in[13];
  const float* d1_w  = (const float*)d_in[14];
  const float* d1_b  = (const float*)d_in[15];
  const float* bn1_g = (const float*)d_in[16];
  const float* bn1_b = (const float*)d_in[17];
  const float* mu_w  = (const float*)d_in[18];
  const float* mu_b  = (const float*)d_in[19];
  const float* lv_w  = (const float*)d_in[20];
  const float* lv_b  = (const float*)d_in[21];
  const float* ad_w  = (const float*)d_in[22];
  const float* ad_b  = (const float*)d_in[23];
  const float* adg1_w= (const float*)d_in[24];
  const float* adg1_b= (const float*)d_in[25];
  const float* adg2_w= (const float*)d_in[26];
  const float* adg2_b= (const float*)d_in[27];
  const float* aq_w  = (const float*)d_in[28];
  const float* aq_b  = (const float*)d_in[29];
  const float* ab_w  = (const float*)d_in[30];
  const float* ab_b  = (const float*)d_in[31];
  const float* d3_w  = (const float*)d_in[32];
  const float* d3_b  = (const float*)d_in[33];
  const float* bn3_g = (const float*)d_in[34];
  const float* bn3_b = (const float*)d_in[35];
  const float* d4_w  = (const float*)d_in[36];
  const float* d4_b  = (const float*)d_in[37];
  const float* bn4_g = (const float*)d_in[38];
  const float* bn4_b = (const float*)d_in[39];
  const float* tw1   = (const float*)d_in[40];
  const float* tb1   = (const float*)d_in[41];
  const float* tg1   = (const float*)d_in[42];
  const float* tbe1  = (const float*)d_in[43];
  const float* tw2   = (const float*)d_in[44];
  const float* tb2   = (const float*)d_in[45];
  const float* tg2   = (const float*)d_in[46];
  const float* tbe2  = (const float*)d_in[47];
  const float* tw3   = (const float*)d_in[48];
  const float* tb3   = (const float*)d_in[49];

  float* out = (float*)d_out;
  float* wsf = (float*)d_ws;
  float* h1   = wsf;                 // 196608  (later: abuf, t2)
  float* h2   = wsf + 196608;        // 81920   (later: abuf tail, t1)
  float* h3   = wsf + 278528;        // 28672   (later: dec2)
  float* out1 = wsf + 307200;        // 262144  (later: dec1)
  float* fd   = wsf + 569344;        // 1048576
  float* dg1  = wsf + 1617920;       // 32768
  float* dg2  = wsf + 1650688;       // 32768
  float* qb   = wsf + 1683456;       // 2097152
  float* ab   = wsf + 3780608;       // 32768
  float* amat = wsf + 3813376;       // 2097152
  float* dec1 = out1;
  float* dec2 = h3;
  float* t1   = h2;
  float* t2   = h1;

  // A-fragment buffer: 524288 shorts = 262144 floats, reuses dead h1+h2
  short* ahi = (short*)wsf;
  short* alo = ahi + 262144;

  float* mean_o = out + 26624;
  float* lv_o   = out + 43008;
  float* z_o    = out + 76032;

  // ---------------- encoder ----------------
  conv1_k<<<768, 256, 0, stream>>>(x, cw1, cb1, h1);
  bn2d_k<<<32, 256, 0, stream>>>(h1, g1, be1, 32, 24);
  conv2_k<<<320, 256, 0, stream>>>(h1, cw2, cb2, h2);
  bn2d_k<<<16, 256, 0, stream>>>(h2, g2, be2, 16, 20);
  conv3_k<<<112, 256, 0, stream>>>(h2, cw3, cb3, h3);
  bn2d_k<<<8, 256, 0, stream>>>(h3, g3, be3, 8, 14);

  gemm_os_k<<<dim3(16, 4), 256, 0, stream>>>(h3, d1_w, d1_b, out1, 112, 1024);
  bn1d_k<<<32, 256, 0, stream>>>(out1, bn1_g, bn1_b, 1024);

  // ---------------- fused heads (MFMA) ----------------
  prep_a_k<<<128, 256, 0, stream>>>(out1, ahi, alo);

  HeadArgs ha;
  ha.W[0] = mu_w;   ha.b[0] = mu_b;   ha.dst[0] = mean_o; ha.ldw[0] = 64;   ha.op[0] = 0;
  ha.W[1] = lv_w;   ha.b[1] = lv_b;   ha.dst[1] = lv_o;   ha.ldw[1] = 64;   ha.op[1] = 0;
  ha.W[2] = ad_w;   ha.b[2] = ad_b;   ha.dst[2] = fd;     ha.ldw[2] = 4096; ha.op[2] = 0;
  ha.W[3] = adg1_w; ha.b[3] = adg1_b; ha.dst[3] = dg1;    ha.ldw[3] = 128;  ha.op[3] = 1;
  ha.W[4] = adg2_w; ha.b[4] = adg2_b; ha.dst[4] = dg2;    ha.ldw[4] = 128;  ha.op[4] = 1;
  ha.W[5] = aq_w;   ha.b[5] = aq_b;   ha.dst[5] = qb;     ha.ldw[5] = 8192; ha.op[5] = 0;
  ha.W[6] = ab_w;   ha.b[6] = ab_b;   ha.dst[6] = ab;     ha.ldw[6] = 128;  ha.op[6] = 0;
  ha.off[0] = 0;    ha.off[1] = 64;   ha.off[2] = 128;  ha.off[3] = 4224;
  ha.off[4] = 4352; ha.off[5] = 4480; ha.off[6] = 12672; ha.off[7] = 12800;
  heads_mfma_k<<<dim3(200, 2), 512, 0, stream>>>(ahi, alo, ha);

  // ---------------- orthogonalization + flow ----------------
  ns_f16split_k<<<1024, 128, 0, stream>>>(qb, amat);
  flow_k<<<256, 64, 0, stream>>>(amat, fd, dg1, dg2, ab, eps, out);

  // ---------------- decoder ----------------
  gemm_os_k<<<dim3(16, 4), 256, 0, stream>>>(z_o, d3_w, d3_b, dec1, 64, 1024);
  bn1d_k<<<32, 256, 0, stream>>>(dec1, bn3_g, bn3_b, 1024);
  hipMemsetAsync(dec2, 0, 28672 * sizeof(float), stream);
  gemm_ks_k<<<dim3(2, 4, 16), 256, 0, stream>>>(dec1, d4_w, d4_b, dec2);
  bn1d_k<<<4, 256, 0, stream>>>(dec2, bn4_g, bn4_b, 112);

  tconv1_k<<<320, 256, 0, stream>>>(dec2, tw1, tb1, t1);
  bn2d_k<<<16, 256, 0, stream>>>(t1, tg1, tbe1, 16, 20);
  tconv2_k<<<768, 256, 0, stream>>>(t1, tw2, tb2, t2);
  bn2d_k<<<32, 256, 0, stream>>>(t2, tg2, tbe2, 32, 24);
  tconv3_k<<<104, 256, 0, stream>>>(t2, tw3, tb3, out);
}

// Round 15
// 453.594 us; speedup vs baseline: 1.2377x; 1.0589x over previous
//
#include <hip/hip_runtime.h>
#include <math.h>

#define NS_STEPS 16

typedef __attribute__((ext_vector_type(8))) _Float16 half8;
typedef __attribute__((ext_vector_type(4))) _Float16 half4v;
typedef __attribute__((ext_vector_type(8))) short short8;
typedef __attribute__((ext_vector_type(4))) short short4v;
typedef __attribute__((ext_vector_type(4))) float floatx4;

static __device__ inline unsigned short f2bf(float f) {
  union { float f; unsigned u; } v; v.f = f;
  unsigned r = v.u + 0x7fffu + ((v.u >> 16) & 1u);
  return (unsigned short)(r >> 16);
}
static __device__ inline float bf2f(unsigned short h) {
  union { unsigned u; float f; } v; v.u = ((unsigned)h) << 16;
  return v.f;
}

// ======================= encoder convs =======================
__global__ __launch_bounds__(256) void conv1_k(const float* __restrict__ x,
    const float* __restrict__ w, const float* __restrict__ bias,
    float* __restrict__ out) {
  __shared__ float ws[384];
  int tid = threadIdx.x;
  for (int i = tid; i < 384; i += 256) ws[i] = w[i];
  __syncthreads();
  int idx = blockIdx.x * 256 + tid;
  if (idx >= 196608) return;
  int b = idx / 768, r = idx % 768;
  int c = r / 24, h = r % 24;
  const float* xb = x + b * 104 + h * 4;
  const float* wc = ws + c * 12;
  float acc = bias[c];
  #pragma unroll
  for (int kh = 0; kh < 3; kh++) {
    #pragma unroll
    for (int kw = 0; kw < 4; kw++)
      acc += xb[kh * 4 + kw] * wc[kh * 4 + kw];
  }
  out[idx] = acc;
}

__global__ __launch_bounds__(256) void conv2_k(const float* __restrict__ in,
    const float* __restrict__ w, const float* __restrict__ bias,
    float* __restrict__ out) {
  __shared__ float ws[2560];
  int tid = threadIdx.x;
  for (int i = tid; i < 2560; i += 256) ws[i] = w[i];
  __syncthreads();
  int idx = blockIdx.x * 256 + tid;
  if (idx >= 81920) return;
  int b = idx / 320, r = idx % 320;
  int c = r / 20, h = r % 20;
  const float* ib = in + b * 768 + h;
  const float* wc = ws + c * 160;
  float acc = bias[c];
  for (int i = 0; i < 32; i++) {
    #pragma unroll
    for (int kh = 0; kh < 5; kh++)
      acc += ib[i * 24 + kh] * wc[i * 5 + kh];
  }
  out[idx] = acc;
}

__global__ __launch_bounds__(256) void conv3_k(const float* __restrict__ in,
    const float* __restrict__ w, const float* __restrict__ bias,
    float* __restrict__ out) {
  __shared__ float ws[896];
  int tid = threadIdx.x;
  for (int i = tid; i < 896; i += 256) ws[i] = w[i];
  __syncthreads();
  int idx = blockIdx.x * 256 + tid;
  if (idx >= 28672) return;
  int b = idx / 112, r = idx % 112;
  int c = r / 14, h = r % 14;
  const float* ib = in + b * 320 + h;
  const float* wc = ws + c * 112;
  float acc = bias[c];
  for (int i = 0; i < 16; i++) {
    #pragma unroll
    for (int kh = 0; kh < 7; kh++)
      acc += ib[i * 20 + kh] * wc[i * 7 + kh];
  }
  out[idx] = acc;
}

// ======================= decoder tconvs =======================
__global__ __launch_bounds__(256) void tconv1_k(const float* __restrict__ in,
    const float* __restrict__ w, const float* __restrict__ bias,
    float* __restrict__ out) {
  __shared__ float ws[896];
  int tid = threadIdx.x;
  for (int i = tid; i < 896; i += 256) ws[i] = w[i];
  __syncthreads();
  int idx = blockIdx.x * 256 + tid;
  if (idx >= 81920) return;
  int b = idx / 320, r = idx % 320;
  int c = r / 20, s = r % 20;
  float acc = bias[c];
  for (int o = 0; o < 8; o++) {
    #pragma unroll
    for (int kh = 0; kh < 7; kh++) {
      int hs = s - kh;
      if (hs >= 0 && hs < 14)
        acc += in[b * 112 + o * 14 + hs] * ws[o * 112 + c * 7 + kh];
    }
  }
  out[idx] = acc;
}

__global__ __launch_bounds__(256) void tconv2_k(const float* __restrict__ in,
    const float* __restrict__ w, const float* __restrict__ bias,
    float* __restrict__ out) {
  __shared__ float ws[2560];
  int tid = threadIdx.x;
  for (int i = tid; i < 2560; i += 256) ws[i] = w[i];
  __syncthreads();
  int idx = blockIdx.x * 256 + tid;
  if (idx >= 196608) return;
  int b = idx / 768, r = idx % 768;
  int c = r / 24, s = r % 24;
  float acc = bias[c];
  for (int o = 0; o < 16; o++) {
    #pragma unroll
    for (int kh = 0; kh < 5; kh++) {
      int hs = s - kh;
      if (hs >= 0 && hs < 20)
        acc += in[b * 320 + o * 20 + hs] * ws[o * 160 + c * 5 + kh];
    }
  }
  out[idx] = acc;
}

__global__ __launch_bounds__(256) void tconv3_k(const float* __restrict__ in,
    const float* __restrict__ w, const float* __restrict__ bias,
    float* __restrict__ out) {
  __shared__ float ws[384];
  int tid = threadIdx.x;
  for (int i = tid; i < 384; i += 256) ws[i] = w[i];
  __syncthreads();
  int idx = blockIdx.x * 256 + tid;
  if (idx >= 26624) return;
  int b = idx / 104, r = idx % 104;
  int sh = r / 4, sw = r % 4;
  float acc = bias[0];
  for (int o = 0; o < 32; o++) {
    #pragma unroll
    for (int kh = 0; kh < 3; kh++) {
      int hs = sh - kh;
      if (hs >= 0 && hs < 24)
        acc += in[b * 768 + o * 24 + hs] * ws[o * 12 + kh * 4 + sw];
    }
  }
  out[idx] = acc;
}

// ======================= batchnorm =======================
__global__ __launch_bounds__(256) void bn2d_k(float* __restrict__ x,
    const float* __restrict__ g, const float* __restrict__ be,
    int C, int HW) {
  __shared__ float rs[256], rs2[256];
  int c = blockIdx.x, tid = threadIdx.x;
  int total = 256 * HW;
  float s = 0.f, s2 = 0.f;
  for (int i = tid; i < total; i += 256) {
    int b = i / HW, j = i - b * HW;
    float v = x[(b * C + c) * HW + j];
    s += v; s2 += v * v;
  }
  rs[tid] = s; rs2[tid] = s2;
  __syncthreads();
  for (int off = 128; off > 0; off >>= 1) {
    if (tid < off) { rs[tid] += rs[tid + off]; rs2[tid] += rs2[tid + off]; }
    __syncthreads();
  }
  float m = rs[0] / (float)total;
  float var = rs2[0] / (float)total - m * m;
  float rstd = rsqrtf(var + 1e-5f) * g[c];
  float bb = be[c];
  for (int i = tid; i < total; i += 256) {
    int b = i / HW, j = i - b * HW;
    size_t idx = (size_t)(b * C + c) * HW + j;
    float v = (x[idx] - m) * rstd + bb;
    x[idx] = v > 0.f ? v : 0.f;
  }
}

__global__ __launch_bounds__(256) void bn1d_k(float* __restrict__ x,
    const float* __restrict__ g, const float* __restrict__ be, int N) {
  __shared__ float p1[8][32], p2[8][32];
  int t = threadIdx.x;
  int cl = t & 31, rg = t >> 5;
  int c = blockIdx.x * 32 + cl;
  float s = 0.f, s2 = 0.f;
  if (c < N) {
    for (int r = rg * 32; r < rg * 32 + 32; r++) {
      float v = x[r * N + c];
      s += v; s2 += v * v;
    }
  }
  p1[rg][cl] = s; p2[rg][cl] = s2;
  __syncthreads();
  float ts = 0.f, ts2 = 0.f;
  #pragma unroll
  for (int i = 0; i < 8; i++) { ts += p1[i][cl]; ts2 += p2[i][cl]; }
  float m = ts * (1.f / 256.f);
  float var = ts2 * (1.f / 256.f) - m * m;
  float rstd = rsqrtf(var + 1e-5f) * ((c < N) ? g[c] : 1.f);
  float bb = (c < N) ? be[c] : 0.f;
  if (c < N) {
    for (int r = rg * 32; r < rg * 32 + 32; r++) {
      float v = (x[r * N + c] - m) * rstd + bb;
      x[r * N + c] = v > 0.f ? v : 0.f;
    }
  }
}

// ============== one-shot fp32 GEMM (K<=112, N multiple of 64) ===============
// v2: also accumulates per-column (sum, sumsq) of the raw output (incl bias)
// into stats[2n],[2n+1] via LDS reduce (reusing dead As) + 4 atomicAdds per
// column (one per mb block). Consumers apply bn+relu inline -> the separate
// bn1d dispatch for out1/dec1 is removed (dispatch-latency regime, R14).
__global__ __launch_bounds__(256) void gemm_os_k(const float* __restrict__ A,
    const float* __restrict__ W, const float* __restrict__ bias,
    float* __restrict__ C, float* __restrict__ stats, int K, int N) {
  __shared__ float As[112 * 68];
  __shared__ float Bs[112 * 68];
  int tid = threadIdx.x;
  int nb = blockIdx.x, mb = blockIdx.y;
  int K16 = K >> 4;
  {
    int row = tid >> 2;
    const float* Ar = A + (size_t)(mb * 64 + row) * K;
    for (int i = 0; i < K16; i++) {
      int j = (tid & 3) + 4 * i;
      float4 v = *(const float4*)(Ar + j * 4);
      int k = j * 4;
      As[k * 68 + row] = v.x;
      As[(k + 1) * 68 + row] = v.y;
      As[(k + 2) * 68 + row] = v.z;
      As[(k + 3) * 68 + row] = v.w;
    }
  }
  {
    int n4 = (tid & 15) * 4;
    for (int i = 0; i < K16; i++) {
      int k = (tid >> 4) + 16 * i;
      float4 v = *(const float4*)(W + (size_t)k * N + nb * 64 + n4);
      *(float4*)(Bs + k * 68 + n4) = v;
    }
  }
  __syncthreads();
  int tm = tid >> 4, tn = tid & 15;
  int m0 = tm * 4, n0 = tn * 4;
  float acc[4][4] = {{0.f}};
  #pragma unroll 8
  for (int kk = 0; kk < K; kk++) {
    float4 a = *(const float4*)(As + kk * 68 + m0);
    float4 b = *(const float4*)(Bs + kk * 68 + n0);
    acc[0][0] += a.x*b.x; acc[0][1] += a.x*b.y; acc[0][2] += a.x*b.z; acc[0][3] += a.x*b.w;
    acc[1][0] += a.y*b.x; acc[1][1] += a.y*b.y; acc[1][2] += a.y*b.z; acc[1][3] += a.y*b.w;
    acc[2][0] += a.z*b.x; acc[2][1] += a.z*b.y; acc[2][2] += a.z*b.z; acc[2][3] += a.z*b.w;
    acc[3][0] += a.w*b.x; acc[3][1] += a.w*b.y; acc[3][2] += a.w*b.z; acc[3][3] += a.w*b.w;
  }
  float s[4] = {0.f, 0.f, 0.f, 0.f}, s2[4] = {0.f, 0.f, 0.f, 0.f};
  #pragma unroll
  for (int i = 0; i < 4; i++) {
    int m = mb * 64 + m0 + i;
    #pragma unroll
    for (int j = 0; j < 4; j++) {
      int n = nb * 64 + n0 + j;
      float v = acc[i][j] + bias[n];
      C[(size_t)m * N + n] = v;
      s[j] += v; s2[j] += v * v;
    }
  }
  // ---- per-column stats reduce (As is dead) ----
  __syncthreads();
  float* ssum = As;          // [16 tm][64 col]
  float* ssq  = As + 1024;
  #pragma unroll
  for (int j = 0; j < 4; j++) {
    ssum[tid * 4 + j] = s[j];   // == [tm*64 + tn*4+j]
    ssq[tid * 4 + j]  = s2[j];
  }
  __syncthreads();
  if (tid < 64) {
    float ts = 0.f, ts2 = 0.f;
    #pragma unroll
    for (int t = 0; t < 16; t++) {
      ts  += ssum[t * 64 + tid];
      ts2 += ssq[t * 64 + tid];
    }
    int n = nb * 64 + tid;
    atomicAdd(&stats[2 * n],     ts);
    atomicAdd(&stats[2 * n + 1], ts2);
  }
}

// ============== K-split fp32 GEMM for d4: C(256,112) += A@W chunk ===========
// v2: applies bn3+relu (from stats3, computed by gemm_os d3) to A at load.
__global__ __launch_bounds__(256) void gemm_ks_k(const float* __restrict__ A,
    const float* __restrict__ stats, const float* __restrict__ bng,
    const float* __restrict__ bnb,
    const float* __restrict__ W, const float* __restrict__ bias,
    float* __restrict__ C) {
  __shared__ float As[64 * 68];
  __shared__ float Bs[64 * 68];
  int tid = threadIdx.x;
  int nb = blockIdx.x, mb = blockIdx.y, kc = blockIdx.z;
  int k0 = kc * 64;
  {
    int row = tid >> 2;
    const float* Ar = A + (size_t)(mb * 64 + row) * 1024 + k0;
    #pragma unroll
    for (int i = 0; i < 4; i++) {
      int j = (tid & 3) + 4 * i;
      float4 v = *(const float4*)(Ar + j * 4);
      int k = j * 4;
      float vv[4] = {v.x, v.y, v.z, v.w};
      #pragma unroll
      for (int e = 0; e < 4; e++) {
        int c = k0 + k + e;
        float m = stats[2 * c] * (1.f / 256.f);
        float var = stats[2 * c + 1] * (1.f / 256.f) - m * m;
        float rstd = rsqrtf(var + 1e-5f) * bng[c];
        float nv = (vv[e] - m) * rstd + bnb[c];
        vv[e] = nv > 0.f ? nv : 0.f;
      }
      As[k * 68 + row] = vv[0];
      As[(k + 1) * 68 + row] = vv[1];
      As[(k + 2) * 68 + row] = vv[2];
      As[(k + 3) * 68 + row] = vv[3];
    }
  }
  {
    int n4 = (tid & 15) * 4;
    int nbase = nb * 64 + n4;
    #pragma unroll
    for (int i = 0; i < 4; i++) {
      int k = (tid >> 4) + 16 * i;
      const float* Wr = W + (size_t)(k0 + k) * 112;
      float4 v;
      v.x = (nbase     < 112) ? Wr[nbase]     : 0.f;
      v.y = (nbase + 1 < 112) ? Wr[nbase + 1] : 0.f;
      v.z = (nbase + 2 < 112) ? Wr[nbase + 2] : 0.f;
      v.w = (nbase + 3 < 112) ? Wr[nbase + 3] : 0.f;
      *(float4*)(Bs + k * 68 + n4) = v;
    }
  }
  __syncthreads();
  int tm = tid >> 4, tn = tid & 15;
  int m0 = tm * 4, n0 = tn * 4;
  float acc[4][4] = {{0.f}};
  #pragma unroll 8
  for (int kk = 0; kk < 64; kk++) {
    float4 a = *(const float4*)(As + kk * 68 + m0);
    float4 b = *(const float4*)(Bs + kk * 68 + n0);
    acc[0][0] += a.x*b.x; acc[0][1] += a.x*b.y; acc[0][2] += a.x*b.z; acc[0][3] += a.x*b.w;
    acc[1][0] += a.y*b.x; acc[1][1] += a.y*b.y; acc[1][2] += a.y*b.z; acc[1][3] += a.y*b.w;
    acc[2][0] += a.z*b.x; acc[2][1] += a.z*b.y; acc[2][2] += a.z*b.z; acc[2][3] += a.z*b.w;
    acc[3][0] += a.w*b.x; acc[3][1] += a.w*b.y; acc[3][2] += a.w*b.z; acc[3][3] += a.w*b.w;
  }
  #pragma unroll
  for (int i = 0; i < 4; i++) {
    int m = mb * 64 + m0 + i;
    #pragma unroll
    for (int j = 0; j < 4; j++) {
      int n = nb * 64 + n0 + j;
      if (n < 112) {
        float v = acc[i][j] + (kc == 0 ? bias[n] : 0.f);
        atomicAdd(&C[m * 112 + n], v);
      }
    }
  }
}

// ======= A-fragment precompute: out1 raw -> bn1+relu -> bf16 hi/lo ==========
// v2: applies bn1+relu inline from stats1 (gemm_os d1), removing bn1d(out1).
__global__ __launch_bounds__(256) void prep_a_k(const float* __restrict__ A,
    const float* __restrict__ stats, const float* __restrict__ bng,
    const float* __restrict__ bnb,
    short* __restrict__ ahi, short* __restrict__ alo) {
  int gi = blockIdx.x * 256 + threadIdx.x;   // 0..32767
  int lane = gi & 63;
  int t = gi >> 6;
  int mt = t & 3; t >>= 2;
  int c = t & 31; int mb = t >> 5;
  int row = mb * 64 + mt * 16 + (lane & 15);
  int k0 = c * 32 + (lane >> 4) * 8;
  const float* src = A + (size_t)row * 1024 + k0;
  float4 v0 = *(const float4*)(src);
  float4 v1 = *(const float4*)(src + 4);
  float av[8] = {v0.x, v0.y, v0.z, v0.w, v1.x, v1.y, v1.z, v1.w};
  short8 h, lo;
  #pragma unroll
  for (int i = 0; i < 8; i++) {
    int col = k0 + i;
    float m = stats[2 * col] * (1.f / 256.f);
    float var = stats[2 * col + 1] * (1.f / 256.f) - m * m;
    float rstd = rsqrtf(var + 1e-5f) * bng[col];
    float v = (av[i] - m) * rstd + bnb[col];
    v = v > 0.f ? v : 0.f;
    unsigned short hh = f2bf(v);
    h[i] = (short)hh;
    lo[i] = (short)f2bf(v - bf2f(hh));
  }
  *(short8*)(ahi + (size_t)gi * 8) = h;
  *(short8*)(alo + (size_t)gi * 8) = lo;
}

// ================= fused head GEMMs, compensated-bf16 MFMA ==================
// v7 (unchanged): grid (200, 2), 512-thread blocks, lgkmcnt-only barrier.
struct HeadArgs {
  const float* W[7];
  const float* b[7];
  float* dst[7];
  int off[8];
  int ldw[7];
  int op[7];
};

__global__ __launch_bounds__(512) void heads_mfma_k(const short* __restrict__ ahi,
                                                    const short* __restrict__ alo,
                                                    HeadArgs ha) {
  __shared__ __align__(16) short Wsh[2][2][2048];  // [buf][hi/lo][64col x 32k frag]
  int tid = threadIdx.x;
  int nb = blockIdx.x;          // 64-col tile, 0..199
  int mqh = blockIdx.y;         // 128-row half, 0..1
  int gc = nb * 64;
  int r = 0;
  while (gc >= ha.off[r + 1]) r++;
  const float* Wp = ha.W[r];
  const float* bias = ha.b[r];
  float* dst = ha.dst[r];
  int ldw = ha.ldw[r];
  int op = ha.op[r];
  int nloc = gc - ha.off[r];

  int w = tid >> 6, l = tid & 63;
  int lane16 = l & 15, quad = l >> 4;

  int c64 = tid & 63, q8 = tid >> 6;
  const float* wcol = Wp + (size_t)(q8 * 4) * ldw + nloc + c64;
  int wg = ((c64 >> 4) * 64 + (q8 >> 1) * 16 + (c64 & 15)) * 8 + (q8 & 1) * 4;

  int mb = mqh * 2 + (w >> 2);
  int mt = w & 3;
  const short* agh = ahi + (size_t)mb * 65536 + mt * 512 + l * 8;
  const short* agl = alo + (size_t)mb * 65536 + mt * 512 + l * 8;

  const floatx4 zero4 = {0.f, 0.f, 0.f, 0.f};
  floatx4 acc[4] = {zero4, zero4, zero4, zero4};

  float wvN[4], wvF[4];
  short4v whiN, wloN;
  short8 aCh, aCl, aNh, aNl;

  {
    float wv0[4];
    #pragma unroll
    for (int j = 0; j < 4; j++) wv0[j] = wcol[(size_t)j * ldw];
    #pragma unroll
    for (int j = 0; j < 4; j++) wvN[j] = wcol[(size_t)(32 + j) * ldw];
    aCh = *(const short8*)(agh);
    aCl = *(const short8*)(agl);
    #pragma unroll
    for (int j = 0; j < 4; j++) wvF[j] = wcol[(size_t)(64 + j) * ldw];
    short4v t0h, t0l;
    #pragma unroll
    for (int j = 0; j < 4; j++) {
      unsigned short hh = f2bf(wv0[j]);
      t0h[j] = (short)hh;
      t0l[j] = (short)f2bf(wv0[j] - bf2f(hh));
    }
    *(short4v*)(&Wsh[0][0][wg]) = t0h;
    *(short4v*)(&Wsh[0][1][wg]) = t0l;
    #pragma unroll
    for (int j = 0; j < 4; j++) {
      unsigned short hh = f2bf(wvN[j]);
      whiN[j] = (short)hh;
      wloN[j] = (short)f2bf(wvN[j] - bf2f(hh));
    }
    #pragma unroll
    for (int j = 0; j < 4; j++) wvN[j] = wvF[j];
    asm volatile("s_waitcnt lgkmcnt(0)" ::: "memory");
    __builtin_amdgcn_s_barrier();
  }

  for (int ch = 0; ch < 32; ++ch) {
    int p = ch & 1;
    if (ch < 31) {
      *(short4v*)(&Wsh[p ^ 1][0][wg]) = whiN;
      *(short4v*)(&Wsh[p ^ 1][1][wg]) = wloN;
    }
    if (ch < 29) {
      #pragma unroll
      for (int j = 0; j < 4; j++)
        wvF[j] = wcol[(size_t)((ch + 3) * 32 + j) * ldw];
    }
    if (ch < 31) {
      aNh = *(const short8*)(agh + (size_t)(ch + 1) * 2048);
      aNl = *(const short8*)(agl + (size_t)(ch + 1) * 2048);
    }
    short8 bh0 = *(const short8*)(&Wsh[p][0][(0 * 64 + l) * 8]);
    short8 bl0 = *(const short8*)(&Wsh[p][1][(0 * 64 + l) * 8]);
    short8 bh1 = *(const short8*)(&Wsh[p][0][(1 * 64 + l) * 8]);
    short8 bl1 = *(const short8*)(&Wsh[p][1][(1 * 64 + l) * 8]);
    short8 bh2 = *(const short8*)(&Wsh[p][0][(2 * 64 + l) * 8]);
    short8 bl2 = *(const short8*)(&Wsh[p][1][(2 * 64 + l) * 8]);
    short8 bh3 = *(const short8*)(&Wsh[p][0][(3 * 64 + l) * 8]);
    short8 bl3 = *(const short8*)(&Wsh[p][1][(3 * 64 + l) * 8]);
    acc[0] = __builtin_amdgcn_mfma_f32_16x16x32_bf16(aCh, bh0, acc[0], 0, 0, 0);
    acc[0] = __builtin_amdgcn_mfma_f32_16x16x32_bf16(aCh, bl0, acc[0], 0, 0, 0);
    acc[0] = __builtin_amdgcn_mfma_f32_16x16x32_bf16(aCl, bh0, acc[0], 0, 0, 0);
    acc[1] = __builtin_amdgcn_mfma_f32_16x16x32_bf16(aCh, bh1, acc[1], 0, 0, 0);
    acc[1] = __builtin_amdgcn_mfma_f32_16x16x32_bf16(aCh, bl1, acc[1], 0, 0, 0);
    acc[1] = __builtin_amdgcn_mfma_f32_16x16x32_bf16(aCl, bh1, acc[1], 0, 0, 0);
    acc[2] = __builtin_amdgcn_mfma_f32_16x16x32_bf16(aCh, bh2, acc[2], 0, 0, 0);
    acc[2] = __builtin_amdgcn_mfma_f32_16x16x32_bf16(aCh, bl2, acc[2], 0, 0, 0);
    acc[2] = __builtin_amdgcn_mfma_f32_16x16x32_bf16(aCl, bh2, acc[2], 0, 0, 0);
    acc[3] = __builtin_amdgcn_mfma_f32_16x16x32_bf16(aCh, bh3, acc[3], 0, 0, 0);
    acc[3] = __builtin_amdgcn_mfma_f32_16x16x32_bf16(aCh, bl3, acc[3], 0, 0, 0);
    acc[3] = __builtin_amdgcn_mfma_f32_16x16x32_bf16(aCl, bh3, acc[3], 0, 0, 0);
    if (ch < 30) {
      #pragma unroll
      for (int j = 0; j < 4; j++) {
        unsigned short hh = f2bf(wvN[j]);
        whiN[j] = (short)hh;
        wloN[j] = (short)f2bf(wvN[j] - bf2f(hh));
      }
    }
    if (ch < 29) {
      #pragma unroll
      for (int j = 0; j < 4; j++) wvN[j] = wvF[j];
    }
    if (ch < 31) { aCh = aNh; aCl = aNl; }
    asm volatile("s_waitcnt lgkmcnt(0)" ::: "memory");
    __builtin_amdgcn_s_barrier();
  }

  #pragma unroll
  for (int nf = 0; nf < 4; nf++) {
    int n = nloc + nf * 16 + lane16;
    float bv = bias[n];
    #pragma unroll
    for (int i = 0; i < 4; i++) {
      int m = mqh * 128 + w * 16 + quad * 4 + i;
      float v = acc[nf][i] + bv;
      if (op == 1) v = tanhf(v);
      dst[(size_t)m * ldw + n] = v;
    }
  }
}

// ============ Newton-Schulz: fully compensated f16 MFMA =====================
// v3 structure (proven stable; do NOT re-derive fgh/fgl from registers —
// register-allocator cliff, see R6-R8). NS_STEPS=16 validated.
__global__ __launch_bounds__(128) void ns_f16split_k(const float* __restrict__ q,
                                                     float* __restrict__ amat) {
  __align__(16) __shared__ _Float16 arena[12288];
  int tid = threadIdx.x;
  int wid = tid >> 6;
  int l = tid & 63;
  int lane16 = l & 15, quad = l >> 4;
  _Float16* Ah_cm = arena;          // [32][72]
  _Float16* Al_cm = arena + 2304;   // [32][72]
  _Float16* Mh_cm = arena + 4608;   // [32][40]
  _Float16* Ml_cm = arena + 5888;   // [32][40]
  _Float16* Ah_rm = arena + 7168;   // [64][40]
  _Float16* Al_rm = arena + 9728;   // [64][40]
  float* Afin = (float*)arena;      // [64][36]

  const float* g = q + (size_t)blockIdx.x * 2048;
  float* o = amat + (size_t)blockIdx.x * 2048;

  if (wid == 0) {
    float vals[32];
    float ss = 0.f;
    #pragma unroll
    for (int j = 0; j < 8; j++) {
      float4 v = *(const float4*)(g + l * 32 + j * 4);
      vals[4*j] = v.x; vals[4*j+1] = v.y; vals[4*j+2] = v.z; vals[4*j+3] = v.w;
      ss += v.x*v.x + v.y*v.y + v.z*v.z + v.w*v.w;
    }
    #pragma unroll
    for (int off = 32; off > 0; off >>= 1) ss += __shfl_xor(ss, off);
    float rn = rsqrtf(ss);
    #pragma unroll
    for (int i = 0; i < 32; i++) vals[i] *= rn;
    #pragma unroll
    for (int j = 0; j < 8; j++) {
      half4v ph, pl;
      #pragma unroll
      for (int rr = 0; rr < 4; rr++) {
        float v = vals[4*j + rr];
        _Float16 h = (_Float16)v;
        _Float16 lo = (_Float16)(v - (float)h);
        ph[rr] = h; pl[rr] = lo;
      }
      *(half4v*)(Ah_rm + l * 40 + j * 4) = ph;
      *(half4v*)(Al_rm + l * 40 + j * 4) = pl;
    }
    #pragma unroll
    for (int i = 0; i < 32; i++) {
      float v = vals[i];
      _Float16 h = (_Float16)v;
      Ah_cm[i * 72 + l] = h;
      Al_cm[i * 72 + l] = (_Float16)(v - (float)h);
    }
  }
  __syncthreads();

  const floatx4 zero4 = {0.f, 0.f, 0.f, 0.f};
  for (int s = 0; s < NS_STEPS; s++) {
    bool last = (s == NS_STEPS - 1);
    half8 fgh[2], fgl[2];
    #pragma unroll
    for (int c = 0; c < 2; c++) {
      fgh[c] = *(half8*)(Ah_cm + (wid * 16 + lane16) * 72 + c * 32 + quad * 8);
      fgl[c] = *(half8*)(Al_cm + (wid * 16 + lane16) * 72 + c * 32 + quad * 8);
    }
    half8 fah[2][2], fal[2][2];
    #pragma unroll
    for (int ti = 0; ti < 2; ti++)
      #pragma unroll
      for (int c = 0; c < 2; c++) {
        fah[ti][c] = *(half8*)(Ah_cm + (ti * 16 + lane16) * 72 + c * 32 + quad * 8);
        fal[ti][c] = *(half8*)(Al_cm + (ti * 16 + lane16) * 72 + c * 32 + quad * 8);
      }
    floatx4 gf[2] = {zero4, zero4};
    #pragma unroll
    for (int ti = 0; ti < 2; ti++)
      #pragma unroll
      for (int c = 0; c < 2; c++) {
        gf[ti] = __builtin_amdgcn_mfma_f32_16x16x32_f16(
            fah[ti][c], fgh[c], gf[ti], 0, 0, 0);
        gf[ti] = __builtin_amdgcn_mfma_f32_16x16x32_f16(
            fah[ti][c], fgl[c], gf[ti], 0, 0, 0);
        gf[ti] = __builtin_amdgcn_mfma_f32_16x16x32_f16(
            fal[ti][c], fgh[c], gf[ti], 0, 0, 0);
      }
    #pragma unroll
    for (int ti = 0; ti < 2; ti++) {
      int col = wid * 16 + lane16;
      int row0 = ti * 16 + quad * 4;
      half4v ph, pl;
      #pragma unroll
      for (int rr = 0; rr < 4; rr++) {
        float m = ((row0 + rr) == col ? 1.5f : 0.f) - 0.5f * gf[ti][rr];
        _Float16 h = (_Float16)m;
        ph[rr] = h; pl[rr] = (_Float16)(m - (float)h);
      }
      *(half4v*)(Mh_cm + col * 40 + row0) = ph;
      *(half4v*)(Ml_cm + col * 40 + row0) = pl;
    }
    __syncthreads();
    half8 fmh[2], fml[2], fbh[2], fbl[2];
    #pragma unroll
    for (int ti = 0; ti < 2; ti++) {
      fmh[ti] = *(half8*)(Mh_cm + (ti * 16 + lane16) * 40 + quad * 8);
      fml[ti] = *(half8*)(Ml_cm + (ti * 16 + lane16) * 40 + quad * 8);
    }
    #pragma unroll
    for (int jj = 0; jj < 2; jj++) {
      int tj = 2 * wid + jj;
      fbh[jj] = *(half8*)(Ah_rm + (tj * 16 + lane16) * 40 + quad * 8);
      fbl[jj] = *(half8*)(Al_rm + (tj * 16 + lane16) * 40 + quad * 8);
    }
    floatx4 df[2][2];
    #pragma unroll
    for (int ti = 0; ti < 2; ti++)
      #pragma unroll
      for (int jj = 0; jj < 2; jj++) {
        df[ti][jj] = __builtin_amdgcn_mfma_f32_16x16x32_f16(
            fmh[ti], fbh[jj], zero4, 0, 0, 0);
        df[ti][jj] = __builtin_amdgcn_mfma_f32_16x16x32_f16(
            fmh[ti], fbl[jj], df[ti][jj], 0, 0, 0);
        df[ti][jj] = __builtin_amdgcn_mfma_f32_16x16x32_f16(
            fml[ti], fbh[jj], df[ti][jj], 0, 0, 0);
      }
    __syncthreads();   // WAR: all reads of Ah_rm/M done before overwrite
    if (!last) {
      #pragma unroll
      for (int ti = 0; ti < 2; ti++)
        #pragma unroll
        for (int jj = 0; jj < 2; jj++) {
          int tj = 2 * wid + jj;
          int z = tj * 16 + lane16;
          int d0 = ti * 16 + quad * 4;
          half4v ph, pl;
          #pragma unroll
          for (int rr = 0; rr < 4; rr++) {
            float v = df[ti][jj][rr];
            _Float16 h = (_Float16)v;
            ph[rr] = h; pl[rr] = (_Float16)(v - (float)h);
          }
          *(half4v*)(Ah_rm + z * 40 + d0) = ph;
          *(half4v*)(Al_rm + z * 40 + d0) = pl;
          #pragma unroll
          for (int rr = 0; rr < 4; rr++) {
            Ah_cm[(d0 + rr) * 72 + z] = ph[rr];
            Al_cm[(d0 + rr) * 72 + z] = pl[rr];
          }
        }
    } else {
      #pragma unroll
      for (int ti = 0; ti < 2; ti++)
        #pragma unroll
        for (int jj = 0; jj < 2; jj++) {
          int tj = 2 * wid + jj;
          int z = tj * 16 + lane16;
          int d0 = ti * 16 + quad * 4;
          float4 v;
          v.x = df[ti][jj][0]; v.y = df[ti][jj][1];
          v.z = df[ti][jj][2]; v.w = df[ti][jj][3];
          *(float4*)(Afin + z * 36 + d0) = v;
        }
    }
    __syncthreads();
  }
  #pragma unroll
  for (int j = 0; j < 4; j++) {
    int f = j * 512 + tid * 4;
    int z = f >> 5, d = f & 31;
    float4 v = *(const float4*)(Afin + z * 36 + d);
    *(float4*)(o + f) = v;
  }
}

// ======================= Sylvester flow (K=4 steps) =======================
__global__ __launch_bounds__(64) void flow_k(const float* __restrict__ amat,
    const float* __restrict__ fd, const float* __restrict__ dg1,
    const float* __restrict__ dg2, const float* __restrict__ ab,
    const float* __restrict__ eps, float* __restrict__ dout) {
  __shared__ float Ps[32][64];
  __shared__ float wsh[32], tsh[32], ush[32];
  int b = blockIdx.x, l = threadIdx.x;
  float mv  = dout[26624 + b * 64 + l];
  float lvv = dout[43008 + b * 64 + l];
  float z0 = mv + eps[b * 64 + l] * expf(0.5f * lvv);
  dout[59648 + b * 64 + l] = z0;
  float zv = z0;
  float ldj = 0.f;
  float q[32];
  for (int k = 0; k < 4; k++) {
    const float4* qrow = (const float4*)(amat + (size_t)(b * 4 + k) * 2048 + l * 32);
    #pragma unroll
    for (int j = 0; j < 8; j++) {
      float4 v = qrow[j];
      q[4*j] = v.x; q[4*j+1] = v.y; q[4*j+2] = v.z; q[4*j+3] = v.w;
    }
    #pragma unroll
    for (int d = 0; d < 32; d++) Ps[d][l] = zv * q[d];
    __syncthreads();
    if (l < 32) {
      const float4* pr = (const float4*)Ps[l];
      float s = 0.f;
      #pragma unroll
      for (int j = 0; j < 16; j++) {
        float4 v = pr[j];
        s += v.x + v.y + v.z + v.w;
      }
      wsh[l] = s;
    }
    __syncthreads();
    if (l < 32) {
      int e = l;
      float acc = ab[b * 128 + e * 4 + k] + wsh[e] * dg2[b * 128 + e * 4 + k];
      for (int d = e + 1; d < 32; d++)
        acc += wsh[d] * fd[b * 4096 + d * 128 + e * 4 + k];
      float tt = tanhf(acc);
      tsh[e] = tt;
      float dd = (1.f - tt * tt) * (dg1[b*128 + e*4 + k] * dg2[b*128 + e*4 + k]) + 1.f;
      ldj += logf(fabsf(dd));
    }
    __syncthreads();
    if (l < 32) {
      int d = l;
      float acc = tsh[d] * dg1[b * 128 + d * 4 + k];
      for (int e = d + 1; e < 32; e++)
        acc += fd[b * 4096 + d * 128 + e * 4 + k] * tsh[e];
      ush[d] = acc;
    }
    __syncthreads();
    #pragma unroll
    for (int d = 0; d < 32; d++) zv += q[d] * ush[d];
    __syncthreads();
  }
  dout[76032 + b * 64 + l] = zv;
  for (int off = 16; off > 0; off >>= 1) ldj += __shfl_down(ldj, off, 32);
  if (l == 0) dout[59392 + b] = ldj;
}

// ======================= host launch =======================
extern "C" void kernel_launch(void* const* d_in, const int* in_sizes, int n_in,
                              void* d_out, int out_size, void* d_ws, size_t ws_size,
                              hipStream_t stream) {
  (void)in_sizes; (void)n_in; (void)out_size; (void)ws_size;
  const float* x     = (const float*)d_in[0];
  const float* eps   = (const float*)d_in[1];
  const float* cw1   = (const float*)d_in[2];
  const float* cb1   = (const float*)d_in[3];
  const float* g1    = (const float*)d_in[4];
  const float* be1   = (const float*)d_in[5];
  const float* cw2   = (const float*)d_in[6];
  const float* cb2   = (const float*)d_in[7];
  const float* g2    = (const float*)d_in[8];
  const float* be2   = (const float*)d_in[9];
  const float* cw3   = (const float*)d_in[10];
  const float* cb3   = (const float*)d_in[11];
  const float* g3    = (const float*)d_in[12];
  const float* be3   = (const float*)d_in[13];
  const float* d1_w  = (const float*)d_in[14];
  const float* d1_b  = (const float*)d_in[15];
  const float* bn1_g = (const float*)d_in[16];
  const float* bn1_b = (const float*)d_in[17];
  const float* mu_w  = (const float*)d_in[18];
  const float* mu_b  = (const float*)d_in[19];
  const float* lv_w  = (const float*)d_in[20];
  const float* lv_b  = (const float*)d_in[21];
  const float* ad_w  = (const float*)d_in[22];
  const float* ad_b  = (const float*)d_in[23];
  const float* adg1_w= (const float*)d_in[24];
  const float* adg1_b= (const float*)d_in[25];
  const float* adg2_w= (const float*)d_in[26];
  const float* adg2_b= (const float*)d_in[27];
  const float* aq_w  = (const float*)d_in[28];
  const float* aq_b  = (const float*)d_in[29];
  const float* ab_w  = (const float*)d_in[30];
  const float* ab_b  = (const float*)d_in[31];
  const float* d3_w  = (const float*)d_in[32];
  const float* d3_b  = (const float*)d_in[33];
  const float* bn3_g = (const float*)d_in[34];
  const float* bn3_b = (const float*)d_in[35];
  const float* d4_w  = (const float*)d_in[36];
  const float* d4_b  = (const float*)d_in[37];
  const float* bn4_g = (const float*)d_in[38];
  const float* bn4_b = (const float*)d_in[39];
  const float* tw1   = (const float*)d_in[40];
  const float* tb1   = (const float*)d_in[41];
  const float* tg1   = (const float*)d_in[42];
  const float* tbe1  = (const float*)d_in[43];
  const float* tw2   = (const float*)d_in[44];
  const float* tb2   = (const float*)d_in[45];
  const float* tg2   = (const float*)d_in[46];
  const float* tbe2  = (const float*)d_in[47];
  const float* tw3   = (const float*)d_in[48];
  const float* tb3   = (const float*)d_in[49];

  float* out = (float*)d_out;
  float* wsf = (float*)d_ws;
  float* h1   = wsf;                 // 196608  (later: abuf, t2)
  float* h2   = wsf + 196608;        // 81920   (later: abuf tail, t1)
  float* h3   = wsf + 278528;        // 28672   (later: dec2)
  float* out1 = wsf + 307200;        // 262144  (later: dec1)
  float* fd   = wsf + 569344;        // 1048576
  float* dg1  = wsf + 1617920;       // 32768
  float* dg2  = wsf + 1650688;       // 32768
  float* qb   = wsf + 1683456;       // 2097152
  float* ab   = wsf + 3780608;       // 32768
  float* amat = wsf + 3813376;       // 2097152
  float* stats1 = wsf + 5910528;     // 2048 (bn1 col sums/sumsq)
  float* stats3 = wsf + 5912576;     // 2048 (bn3 col sums/sumsq)
  float* dec1 = out1;
  float* dec2 = h3;
  float* t1   = h2;
  float* t2   = h1;

  // A-fragment buffer: 524288 shorts = 262144 floats, reuses dead h1+h2
  short* ahi = (short*)wsf;
  short* alo = ahi + 262144;

  float* mean_o = out + 26624;
  float* lv_o   = out + 43008;
  float* z_o    = out + 76032;

  // zero the bn stats accumulators (both used later this launch)
  hipMemsetAsync(stats1, 0, 4096 * sizeof(float), stream);

  // ---------------- encoder ----------------
  conv1_k<<<768, 256, 0, stream>>>(x, cw1, cb1, h1);
  bn2d_k<<<32, 256, 0, stream>>>(h1, g1, be1, 32, 24);
  conv2_k<<<320, 256, 0, stream>>>(h1, cw2, cb2, h2);
  bn2d_k<<<16, 256, 0, stream>>>(h2, g2, be2, 16, 20);
  conv3_k<<<112, 256, 0, stream>>>(h2, cw3, cb3, h3);
  bn2d_k<<<8, 256, 0, stream>>>(h3, g3, be3, 8, 14);

  gemm_os_k<<<dim3(16, 4), 256, 0, stream>>>(h3, d1_w, d1_b, out1, stats1, 112, 1024);

  // ---------------- fused heads (MFMA) ----------------
  prep_a_k<<<128, 256, 0, stream>>>(out1, stats1, bn1_g, bn1_b, ahi, alo);

  HeadArgs ha;
  ha.W[0] = mu_w;   ha.b[0] = mu_b;   ha.dst[0] = mean_o; ha.ldw[0] = 64;   ha.op[0] = 0;
  ha.W[1] = lv_w;   ha.b[1] = lv_b;   ha.dst[1] = lv_o;   ha.ldw[1] = 64;   ha.op[1] = 0;
  ha.W[2] = ad_w;   ha.b[2] = ad_b;   ha.dst[2] = fd;     ha.ldw[2] = 4096; ha.op[2] = 0;
  ha.W[3] = adg1_w; ha.b[3] = adg1_b; ha.dst[3] = dg1;    ha.ldw[3] = 128;  ha.op[3] = 1;
  ha.W[4] = adg2_w; ha.b[4] = adg2_b; ha.dst[4] = dg2;    ha.ldw[4] = 128;  ha.op[4] = 1;
  ha.W[5] = aq_w;   ha.b[5] = aq_b;   ha.dst[5] = qb;     ha.ldw[5] = 8192; ha.op[5] = 0;
  ha.W[6] = ab_w;   ha.b[6] = ab_b;   ha.dst[6] = ab;     ha.ldw[6] = 128;  ha.op[6] = 0;
  ha.off[0] = 0;    ha.off[1] = 64;   ha.off[2] = 128;  ha.off[3] = 4224;
  ha.off[4] = 4352; ha.off[5] = 4480; ha.off[6] = 12672; ha.off[7] = 12800;
  heads_mfma_k<<<dim3(200, 2), 512, 0, stream>>>(ahi, alo, ha);

  // ---------------- orthogonalization + flow ----------------
  ns_f16split_k<<<1024, 128, 0, stream>>>(qb, amat);
  flow_k<<<256, 64, 0, stream>>>(amat, fd, dg1, dg2, ab, eps, out);

  // ---------------- decoder ----------------
  gemm_os_k<<<dim3(16, 4), 256, 0, stream>>>(z_o, d3_w, d3_b, dec1, stats3, 64, 1024);
  hipMemsetAsync(dec2, 0, 28672 * sizeof(float), stream);
  gemm_ks_k<<<dim3(2, 4, 16), 256, 0, stream>>>(dec1, stats3, bn3_g, bn3_b, d4_w, d4_b, dec2);
  bn1d_k<<<4, 256, 0, stream>>>(dec2, bn4_g, bn4_b, 112);

  tconv1_k<<<320, 256, 0, stream>>>(dec2, tw1, tb1, t1);
  bn2d_k<<<16, 256, 0, stream>>>(t1, tg1, tbe1, 16, 20);
  tconv2_k<<<768, 256, 0, stream>>>(t1, tw2, tb2, t2);
  bn2d_k<<<32, 256, 0, stream>>>(t2, tg2, tbe2, 32, 24);
  tconv3_k<<<104, 256, 0, stream>>>(t2, tw3, tb3, out);
}